// Round 8
// baseline (9339.315 us; speedup 1.0000x reference)
//
#include <hip/hip_runtime.h>

typedef unsigned short u16;
typedef unsigned int u32;
typedef unsigned long long u64;
using bf16x8 = __attribute__((ext_vector_type(8))) short;
using f32x4  = __attribute__((ext_vector_type(4))) float;
using u32x4  = __attribute__((ext_vector_type(4))) unsigned int;

#define TT   256
#define NB   64
#define XDI  256
#define HDI  512
#define ZDI  128
#define VV   10000

// ---- workspace byte offsets ----
#define OFF_WE1   512ull        // [512][768] bf16
#define OFF_WE2   786944ull     // [512][512] bf16
#define OFF_WMW   1311232ull    // [128][512] bf16
#define OFF_WSW   1442304ull    // [128][512] bf16
#define OFF_WD1   1573376ull    // [512][640] bf16
#define OFF_WD2   2228736ull    // [512][512] bf16
#define OFF_WDM   2753024ull    // [256][512] bf16
#define OFF_WIH   3015168ull    // [1536][384] bf16
#define OFF_WHH   4194816ull    // [1536][512] bf16
#define OFF_WGW   5767680ull    // [10000][256] bf16
#define OFF_XEMB  10887680ull   // [256][64][256] bf16
#define OFF_H     19276288ull   // [64][512] f32
#define OFF_ZALL  19997184ull   // [256*64][128] bf16
#define OFF_HALL  24191488ull   // [256*64][512] bf16 (h entering step t)
#define OFF_GPART 40968704ull   // [256] f32
#define OFF_GIX   41102848ull   // [256][1536][64] bf16 (x-part of gi + bih)
// tagged exchange buffers (u32 = tag<<16 | bf16), double-buffered by t&1
#define OFF_XC1   91434496ull   // [2][64][512] u32
#define OFF_XE    91696640ull   // [2][64][512] u32
#define OFF_XZ    91958784ull   // [2][64][128] u32
#define OFF_XH    92024320ull   // [2][64][512] u32
#define TAGBYTES  851968ull

__device__ __forceinline__ u16 f2b(float f) {
  union { float f; u32 u; } v; v.f = f;
  u32 r = v.u + 0x7fffu + ((v.u >> 16) & 1u);
  return (u16)(r >> 16);
}
__device__ __forceinline__ u32 f2b2(float a, float b) {
  return (u32)f2b(a) | ((u32)f2b(b) << 16);
}
__device__ __forceinline__ float b2f(u16 x) {
  union { u32 u; float f; } v; v.u = ((u32)x) << 16; return v.f;
}

#define MFMA16(a, b, c) __builtin_amdgcn_mfma_f32_16x16x32_bf16(a, b, c, 0, 0, 0)

// swizzled LDS frag pointer
__device__ __forceinline__ const bf16x8* ldsB(const u16* base, int r, int K, int k) {
  return (const bf16x8*)((const char*)base + (((r * K + k) << 1) ^ ((r & 7) << 4)));
}
__device__ __forceinline__ void ldsW(u16* base, int r, int K, int k, uint4 v) {
  *(uint4*)((char*)base + (((r * K + k) << 1) ^ ((r & 7) << 4))) = v;
}

__device__ __forceinline__ void fill_lds(u16* lds, int Ktot,
                                         const u16* s0, int K0,
                                         const u16* s1, int K1) {
  int kch = Ktot >> 3;
  int nch = 64 * kch;
  for (int i = threadIdx.x; i < nch; i += 256) {
    int row = i / kch;
    int k = (i - row * kch) << 3;
    const u16* src = (k < K0) ? (s0 + row * K0 + k) : (s1 + row * K1 + (k - K0));
    uint4 v = *(const uint4*)src;
    ldsW(lds, row, Ktot, k, v);
  }
}

__device__ __forceinline__ void mm_tile(f32x4 acc[4], const u16* lds, int ldsStride, int ldsK0,
                                        const u16* __restrict__ W, int Kw, int wcol0,
                                        int Klen, int lane) {
  const int kl = (lane >> 4) << 3;
  const int cl = lane & 15;
  const u16* wp = W + (size_t)(wcol0 + cl) * Kw;
  for (int kc = 0; kc < Klen; kc += 32) {
    int k = kc + kl;
    bf16x8 b = *(const bf16x8*)(wp + k);
#pragma unroll
    for (int m = 0; m < 4; ++m)
      acc[m] = MFMA16(*ldsB(lds, (m << 4) + cl, ldsStride, ldsK0 + k), b, acc[m]);
  }
}

// ---- tagged-exchange helpers: coherent (MALL) loads/stores ----
// consumer chunk loads: 8 chunks of 32B at 128B stride → 16 dwordx4
__device__ __forceinline__ void ld16p_c(const u32* p, u32x4* f) {
  asm volatile(
      "global_load_dwordx4 %0, %16, off sc0 sc1\n\t"
      "global_load_dwordx4 %1, %16, off offset:16 sc0 sc1\n\t"
      "global_load_dwordx4 %2, %16, off offset:128 sc0 sc1\n\t"
      "global_load_dwordx4 %3, %16, off offset:144 sc0 sc1\n\t"
      "global_load_dwordx4 %4, %16, off offset:256 sc0 sc1\n\t"
      "global_load_dwordx4 %5, %16, off offset:272 sc0 sc1\n\t"
      "global_load_dwordx4 %6, %16, off offset:384 sc0 sc1\n\t"
      "global_load_dwordx4 %7, %16, off offset:400 sc0 sc1\n\t"
      "global_load_dwordx4 %8, %16, off offset:512 sc0 sc1\n\t"
      "global_load_dwordx4 %9, %16, off offset:528 sc0 sc1\n\t"
      "global_load_dwordx4 %10, %16, off offset:640 sc0 sc1\n\t"
      "global_load_dwordx4 %11, %16, off offset:656 sc0 sc1\n\t"
      "global_load_dwordx4 %12, %16, off offset:768 sc0 sc1\n\t"
      "global_load_dwordx4 %13, %16, off offset:784 sc0 sc1\n\t"
      "global_load_dwordx4 %14, %16, off offset:896 sc0 sc1\n\t"
      "global_load_dwordx4 %15, %16, off offset:912 sc0 sc1\n\t"
      "s_waitcnt vmcnt(0)"
      : "=&v"(f[0]), "=&v"(f[1]), "=&v"(f[2]), "=&v"(f[3]),
        "=&v"(f[4]), "=&v"(f[5]), "=&v"(f[6]), "=&v"(f[7]),
        "=&v"(f[8]), "=&v"(f[9]), "=&v"(f[10]), "=&v"(f[11]),
        "=&v"(f[12]), "=&v"(f[13]), "=&v"(f[14]), "=&v"(f[15])
      : "v"(p) : "memory");
}
__device__ __forceinline__ void ld8p_c(const u32* p, u32x4* f) {
  asm volatile(
      "global_load_dwordx4 %0, %8, off sc0 sc1\n\t"
      "global_load_dwordx4 %1, %8, off offset:16 sc0 sc1\n\t"
      "global_load_dwordx4 %2, %8, off offset:128 sc0 sc1\n\t"
      "global_load_dwordx4 %3, %8, off offset:144 sc0 sc1\n\t"
      "global_load_dwordx4 %4, %8, off offset:256 sc0 sc1\n\t"
      "global_load_dwordx4 %5, %8, off offset:272 sc0 sc1\n\t"
      "global_load_dwordx4 %6, %8, off offset:384 sc0 sc1\n\t"
      "global_load_dwordx4 %7, %8, off offset:400 sc0 sc1\n\t"
      "s_waitcnt vmcnt(0)"
      : "=&v"(f[0]), "=&v"(f[1]), "=&v"(f[2]), "=&v"(f[3]),
        "=&v"(f[4]), "=&v"(f[5]), "=&v"(f[6]), "=&v"(f[7])
      : "v"(p) : "memory");
}
__device__ __forceinline__ void st32t(u32* p, u32 v) {  // write-through tagged store
  asm volatile("global_store_dword %0, %1, off sc0 sc1" :: "v"(p), "v"(v) : "memory");
}
__device__ __forceinline__ u32 chk(const u32x4& w, u32 T) {
  return (((w[0] ^ T) | (w[1] ^ T) | (w[2] ^ T) | (w[3] ^ T)) & 0xFFFF0000u);
}
__device__ __forceinline__ u32 pk2(u32 lo, u32 hi) { return (lo & 0xFFFFu) | (hi << 16); }
__device__ __forceinline__ bf16x8 mkfrag(const u32x4& A, const u32x4& B) {
  union { bf16x8 v; u32 a[4]; } f;
  f.a[0] = pk2(A[0], A[1]); f.a[1] = pk2(A[2], A[3]);
  f.a[2] = pk2(B[0], B[1]); f.a[3] = pk2(B[2], B[3]);
  return f.v;
}
__device__ __forceinline__ f32x4 unpk4(u64 g) {
  f32x4 a;
#pragma unroll
  for (int j = 0; j < 4; ++j) a[j] = b2f((u16)(g >> (16 * j)));
  return a;
}
__device__ __forceinline__ float sigm(float x) { return 1.f / (1.f + __expf(-x)); }

// ---------------- prep kernels ----------------
struct ConvArgs { const float* s[10]; unsigned long long doff[10]; int n[10]; };

__global__ __launch_bounds__(256) void wconv(char* ws, ConvArgs a) {
  int seg = blockIdx.y;
  const float* s = a.s[seg];
  u16* d = (u16*)(ws + a.doff[seg]);
  int n = a.n[seg];
  int i = (blockIdx.x * 256 + threadIdx.x) * 8;
  if (i < n) {
    float4 v0 = *(const float4*)(s + i);
    float4 v1 = *(const float4*)(s + i + 4);
    uint4 o;
    o.x = f2b2(v0.x, v0.y); o.y = f2b2(v0.z, v0.w);
    o.z = f2b2(v1.x, v1.y); o.w = f2b2(v1.z, v1.w);
    *(uint4*)(d + i) = o;
  }
}

__global__ __launch_bounds__(256) void gatherx(char* ws, const int* xs, const float* embed) {
  u16* xemb = (u16*)(ws + OFF_XEMB);
  int i = blockIdx.x * 256 + threadIdx.x;
  int t = i >> 11;
  int rr = i & 2047;
  int n = rr >> 5;
  int k = (rr & 31) << 3;
  int idx = xs[n * TT + t];
  const float* src = embed + (size_t)idx * XDI + k;
  float4 v0 = *(const float4*)src;
  float4 v1 = *(const float4*)(src + 4);
  uint4 o;
  o.x = f2b2(v0.x, v0.y); o.y = f2b2(v0.z, v0.w);
  o.z = f2b2(v1.x, v1.y); o.w = f2b2(v1.z, v1.w);
  *(uint4*)(xemb + ((size_t)t * NB + n) * XDI + k) = o;
}

__global__ __launch_bounds__(256) void h0init(char* ws, const int* labels, const int* wflag,
                                              const float* hnoise, const float* hw, const float* hb0) {
  int i = blockIdx.x * 256 + threadIdx.x;  // 32768
  int n = i >> 9, c = i & 511;
  float v = (float)labels[n] * hw[c] + hb0[c];
  if (wflag[0]) v += hnoise[i];
  ((float*)(ws + OFF_H))[i] = v;
  u16 b = f2b(v);
  ((u16*)(ws + OFF_HALL))[i] = b;                 // hall[0] = h0 (bf16, for phaseC)
  ((u32*)(ws + OFF_XH))[i] = 0x10000u | (u32)b;   // hex slot0, tag 1
}

// gi_x[t][c][n] = bih[c] + sum_k x_emb[t][n][k] * Wih[c][k], k<256
__global__ __launch_bounds__(256) void gixk(char* ws, const float* bih) {
  __shared__ u16 lA[64 * 256];
  int t = blockIdx.x;
  int tid = threadIdx.x, wave = tid >> 6, lane = tid & 63;
  const int cl = lane & 15, rb = (lane >> 4) << 2;
  const u16* xemb = (const u16*)(ws + OFF_XEMB);
  const u16* wih = (const u16*)(ws + OFF_WIH);
  u16* gix = (u16*)(ws + OFF_GIX);
  fill_lds(lA, 256, xemb + (size_t)t * NB * XDI, 256, xemb, 256);
  __syncthreads();
  for (int ct = wave; ct < 96; ct += 4) {
    f32x4 acc[4];
    acc[0] = acc[1] = acc[2] = acc[3] = (f32x4){0.f, 0.f, 0.f, 0.f};
    mm_tile(acc, lA, 256, 0, wih, 384, ct * 16, 256, lane);
    int col = ct * 16 + cl;
    float bv = bih[col];
    u16* dst = gix + ((size_t)t * 1536 + col) * 64;
#pragma unroll
    for (int m = 0; m < 4; ++m) {
      u64 o = (u64)f2b(acc[m][0] + bv) | ((u64)f2b(acc[m][1] + bv) << 16)
            | ((u64)f2b(acc[m][2] + bv) << 32) | ((u64)f2b(acc[m][3] + bv) << 48);
      *(u64*)(dst + (m << 4) + rb) = o;
    }
  }
}

// ---------------- phase B: weight-stationary recurrence, tag-in-data handoffs ----------------
// 32 WGs x 512 threads. WG = one weight slice (16 cols) x all 64 batch rows.
// Exchange words carry their own step tag: no flags, no drains, no detect slack.
__global__ __launch_bounds__(512, 1) void phaseB(
    char* ws, const float* __restrict__ eps,
    const float* __restrict__ b_e1, const float* __restrict__ b_e2,
    const float* __restrict__ b_mw, const float* __restrict__ b_sw,
    const float* __restrict__ bhh) {
  __shared__ u16 wsl[59392];         // 116KB weight slices (swizzled)
  __shared__ float ghb[3][64][16];   // 12KB gh tiles
  __shared__ float red[3][64][16];   // 12KB gi_z tiles
  __shared__ float musp[64][8];      // 2KB mu / pre-softplus std
  __shared__ float hold[64][16];     // 4KB own h slice (f32)

  u16* wWe1 = wsl;            // [16][768]
  u16* wWhh = wsl + 12288;    // [48][512]
  u16* wWe2 = wsl + 36864;    // [16][512]
  u16* wWms = wsl + 45056;    // [16][512] rows 0-3 mu, 4-7 std
  u16* wWihz = wsl + 53248;   // [48][128]

  const u16* we1 = (const u16*)(ws + OFF_WE1);
  const u16* we2 = (const u16*)(ws + OFF_WE2);
  const u16* wmw = (const u16*)(ws + OFF_WMW);
  const u16* wsw = (const u16*)(ws + OFF_WSW);
  const u16* wih = (const u16*)(ws + OFF_WIH);
  const u16* whh = (const u16*)(ws + OFF_WHH);
  const u16* xemb = (const u16*)(ws + OFF_XEMB);
  const u16* gix = (const u16*)(ws + OFF_GIX);
  float* hg = (float*)(ws + OFF_H);
  u16* zall = (u16*)(ws + OFF_ZALL);
  u16* hall = (u16*)(ws + OFF_HALL);
  u32* xc1b = (u32*)(ws + OFF_XC1);
  u32* xeb  = (u32*)(ws + OFF_XE);
  u32* xzb  = (u32*)(ws + OFF_XZ);
  u32* hexb = (u32*)(ws + OFF_XH);

  const int tid = threadIdx.x, wave = tid >> 6, lane = tid & 63;
  const int cl = lane & 15, kl = (lane >> 4) << 3, rb = (lane >> 4) << 2;
  const int sl = blockIdx.x;
  const int mt = wave & 3;
  const int arow = mt * 16 + cl;       // activation row handled by this lane

  // ---- preload weight slices into LDS ----
  for (int c = tid; c < 1536; c += 512) {
    int r = c / 96, k = (c % 96) << 3;
    ldsW(wWe1, r, 768, k, *(const uint4*)(we1 + (size_t)(sl * 16 + r) * 768 + k));
  }
  for (int c = tid; c < 3072; c += 512) {
    int r = c >> 6, k = (c & 63) << 3;
    int gr = (r >> 4) * 512 + sl * 16 + (r & 15);
    ldsW(wWhh, r, 512, k, *(const uint4*)(whh + (size_t)gr * 512 + k));
  }
  for (int c = tid; c < 1024; c += 512) {
    int r = c >> 6, k = (c & 63) << 3;
    ldsW(wWe2, r, 512, k, *(const uint4*)(we2 + (size_t)(sl * 16 + r) * 512 + k));
  }
  for (int c = tid; c < 1024; c += 512) {
    int r = c >> 6, k = (c & 63) << 3;
    uint4 v = {0, 0, 0, 0};
    if (r < 4)      v = *(const uint4*)(wmw + (size_t)(sl * 4 + r) * 512 + k);
    else if (r < 8) v = *(const uint4*)(wsw + (size_t)(sl * 4 + r - 4) * 512 + k);
    ldsW(wWms, r, 512, k, v);
  }
  for (int c = tid; c < 768; c += 512) {
    int r = c >> 4, k = (c & 15) << 3;
    int gr = (r >> 4) * 512 + sl * 16 + (r & 15);
    ldsW(wWihz, r, 128, k, *(const uint4*)(wih + (size_t)gr * 384 + 256 + k));
  }
  for (int i = tid << 1; i < 1024; i += 1024) {
    int r = i >> 4, c = i & 15;
    *(float2*)&hold[r][c] = *(const float2*)(hg + (size_t)r * 512 + sl * 16 + c);
  }
  // biases
  const float be1 = b_e1[sl * 16 + cl];
  const float be2 = b_e2[sl * 16 + cl];
  const float bms = (cl < 4) ? b_mw[sl * 4 + cl] : ((cl < 8) ? b_sw[sl * 4 + cl - 4] : 0.f);
  const float bh0 = bhh[sl * 16 + cl];
  const float bh1 = bhh[512 + sl * 16 + cl];
  const float bh2 = bhh[1024 + sl * 16 + cl];
  __syncthreads();

  const f32x4 z4 = {0.f, 0.f, 0.f, 0.f};
  for (int t = 0; t < TT; ++t) {
    const u32 TG = (u32)(t + 1) << 16;
    const int slot = t & 1;
    // ---- S0: prefetch h-independent operands (plain cached) ----
    u32x4 xf[8];
    u64 gx0 = 0, gx1 = 0;
    float2 ev = {0.f, 0.f};
    if (wave < 4) {
      const u16* xr = xemb + ((size_t)t * NB + arow) * XDI + kl;
#pragma unroll
      for (int i = 0; i < 8; ++i) xf[i] = *(const u32x4*)(xr + i * 32);
      gx0 = *(const u64*)(gix + ((size_t)t * 1536 + sl * 16 + cl) * 64 + mt * 16 + rb);
    } else {
      gx0 = *(const u64*)(gix + ((size_t)t * 1536 + 512 + sl * 16 + cl) * 64 + mt * 16 + rb);
      gx1 = *(const u64*)(gix + ((size_t)t * 1536 + 1024 + sl * 16 + cl) * 64 + mt * 16 + rb);
    }
    if (tid < 128)
      ev = *(const float2*)(eps + (size_t)(tid >> 1) * (TT * ZDI) + (size_t)t * ZDI + sl * 4 + ((tid & 1) << 1));

    // ---- S1: poll h(t); c1 slice (w0-3) / gh tiles (w4-7) ----
    {
      const u32* hb_ = hexb + ((size_t)(slot * NB + arow)) * 512 + kl;
      u32x4 hw[32];
      for (;;) {
        ld16p_c(hb_, hw);
        ld16p_c(hb_ + 256, hw + 16);
        u32 bad = 0;
#pragma unroll
        for (int i = 0; i < 32; ++i) bad |= chk(hw[i], TG);
        if (!__any((int)(bad != 0))) break;
      }
      if (wave < 4) {
        f32x4 a = z4;
#pragma unroll
        for (int i = 0; i < 8; ++i)
          a = MFMA16(*(const bf16x8*)&xf[i], *ldsB(wWe1, cl, 768, i * 32 + kl), a);
#pragma unroll
        for (int c = 0; c < 16; ++c)
          a = MFMA16(mkfrag(hw[2 * c], hw[2 * c + 1]), *ldsB(wWe1, cl, 768, 256 + c * 32 + kl), a);
#pragma unroll
        for (int j = 0; j < 4; ++j)
          st32t(xc1b + ((size_t)(slot * NB + mt * 16 + rb + j)) * 512 + sl * 16 + cl,
                TG | (u32)f2b(fmaxf(a[j] + be1, 0.f)));
      } else {
        f32x4 g0 = z4, g1 = z4, g2 = z4;
#pragma unroll
        for (int c = 0; c < 16; ++c) {
          bf16x8 af = mkfrag(hw[2 * c], hw[2 * c + 1]);
          g0 = MFMA16(af, *ldsB(wWhh, cl, 512, c * 32 + kl), g0);
          g1 = MFMA16(af, *ldsB(wWhh, 16 + cl, 512, c * 32 + kl), g1);
          g2 = MFMA16(af, *ldsB(wWhh, 32 + cl, 512, c * 32 + kl), g2);
        }
#pragma unroll
        for (int j = 0; j < 4; ++j) {
          ghb[0][mt * 16 + rb + j][cl] = g0[j] + bh0;
          ghb[1][mt * 16 + rb + j][cl] = g1[j] + bh1;
          ghb[2][mt * 16 + rb + j][cl] = g2[j] + bh2;
        }
      }
    }

    // ---- S2 + S3a: e slice, then mu/std slice (w0-3 only) ----
    if (wave < 4) {
      {
        const u32* cb_ = xc1b + ((size_t)(slot * NB + arow)) * 512 + kl;
        u32x4 cw[32];
        for (;;) {
          ld16p_c(cb_, cw);
          ld16p_c(cb_ + 256, cw + 16);
          u32 bad = 0;
#pragma unroll
          for (int i = 0; i < 32; ++i) bad |= chk(cw[i], TG);
          if (!__any((int)(bad != 0))) break;
        }
        f32x4 a = z4;
#pragma unroll
        for (int c = 0; c < 16; ++c)
          a = MFMA16(mkfrag(cw[2 * c], cw[2 * c + 1]), *ldsB(wWe2, cl, 512, c * 32 + kl), a);
#pragma unroll
        for (int j = 0; j < 4; ++j)
          st32t(xeb + ((size_t)(slot * NB + mt * 16 + rb + j)) * 512 + sl * 16 + cl,
                TG | (u32)f2b(fmaxf(a[j] + be2, 0.f)));
      }
      {
        const u32* eb_ = xeb + ((size_t)(slot * NB + arow)) * 512 + kl;
        u32x4 ew[32];
        for (;;) {
          ld16p_c(eb_, ew);
          ld16p_c(eb_ + 256, ew + 16);
          u32 bad = 0;
#pragma unroll
        for (int i = 0; i < 32; ++i) bad |= chk(ew[i], TG);
          if (!__any((int)(bad != 0))) break;
        }
        f32x4 a = z4;
#pragma unroll
        for (int c = 0; c < 16; ++c)
          a = MFMA16(mkfrag(ew[2 * c], ew[2 * c + 1]), *ldsB(wWms, cl, 512, c * 32 + kl), a);
        if (cl < 8) {
#pragma unroll
          for (int j = 0; j < 4; ++j) musp[mt * 16 + rb + j][cl] = a[j] + bms;
        }
      }
    }
    __syncthreads();  // BARRIER(1): musp ready; all 8 waves aligned

    // ---- S3b: z = eps*softplus(std) + mu (tid<128) ----
    if (tid < 128) {
      int r = tid >> 1, c0 = (tid & 1) << 1;
      float sx0 = musp[r][4 + c0], sx1 = musp[r][5 + c0];
      float sp0 = fmaxf(sx0, 0.f) + log1pf(__expf(-fabsf(sx0)));
      float sp1 = fmaxf(sx1, 0.f) + log1pf(__expf(-fabsf(sx1)));
      float z0 = ev.x * sp0 + musp[r][c0];
      float z1 = ev.y * sp1 + musp[r][c0 + 1];
      u32* zp = xzb + ((size_t)(slot * NB + r)) * 128 + sl * 4 + c0;
      st32t(zp, TG | (u32)f2b(z0));
      st32t(zp + 1, TG | (u32)f2b(z1));
      *(u32*)(zall + ((size_t)t * NB + r) * ZDI + sl * 4 + c0) = f2b2(z0, z1);
    }

    // ---- S4: poll z; gi_z tiles ----
    {
      const u32* zb_ = xzb + ((size_t)(slot * NB + arow)) * 128 + kl;
      u32x4 zw[8];
      for (;;) {
        ld8p_c(zb_, zw);
        u32 bad = 0;
#pragma unroll
        for (int i = 0; i < 8; ++i) bad |= chk(zw[i], TG);
        if (!__any((int)(bad != 0))) break;
      }
      if (wave < 4) {
        f32x4 a = unpk4(gx0);
#pragma unroll
        for (int c = 0; c < 4; ++c)
          a = MFMA16(mkfrag(zw[2 * c], zw[2 * c + 1]), *ldsB(wWihz, cl, 128, c * 32 + kl), a);
#pragma unroll
        for (int j = 0; j < 4; ++j) red[0][mt * 16 + rb + j][cl] = a[j];
      } else {
        f32x4 a0 = unpk4(gx0), a1 = unpk4(gx1);
#pragma unroll
        for (int c = 0; c < 4; ++c) {
          bf16x8 af = mkfrag(zw[2 * c], zw[2 * c + 1]);
          a0 = MFMA16(af, *ldsB(wWihz, 16 + cl, 128, c * 32 + kl), a0);
          a1 = MFMA16(af, *ldsB(wWihz, 32 + cl, 128, c * 32 + kl), a1);
        }
#pragma unroll
        for (int j = 0; j < 4; ++j) {
          red[1][mt * 16 + rb + j][cl] = a0[j];
          red[2][mt * 16 + rb + j][cl] = a1[j];
        }
      }
    }
    __syncthreads();  // BARRIER(2): red + ghb ready

    // ---- gates + h' (all 512 threads) ----
    {
      int r = tid >> 3, c0 = (tid & 7) << 1;
      float rg0 = sigm(red[0][r][c0] + ghb[0][r][c0]);
      float rg1 = sigm(red[0][r][c0 + 1] + ghb[0][r][c0 + 1]);
      float zg0 = sigm(red[1][r][c0] + ghb[1][r][c0]);
      float zg1 = sigm(red[1][r][c0 + 1] + ghb[1][r][c0 + 1]);
      float ng0 = tanhf(red[2][r][c0] + rg0 * ghb[2][r][c0]);
      float ng1 = tanhf(red[2][r][c0 + 1] + rg1 * ghb[2][r][c0 + 1]);
      float h0n = (1.f - zg0) * ng0 + zg0 * hold[r][c0];
      float h1n = (1.f - zg1) * ng1 + zg1 * hold[r][c0 + 1];
      hold[r][c0] = h0n;
      hold[r][c0 + 1] = h1n;
      if (t < TT - 1) {
        const u32 TG2 = (u32)(t + 2) << 16;
        u32* hp = hexb + ((size_t)(((t + 1) & 1) * NB + r)) * 512 + sl * 16 + c0;
        st32t(hp, TG2 | (u32)f2b(h0n));
        st32t(hp + 1, TG2 | (u32)f2b(h1n));
        *(u32*)(hall + ((size_t)(t + 1) * NB + r) * HDI + sl * 16 + c0) = f2b2(h0n, h1n);
      } else {
        float2 o = {h0n, h1n};
        *(float2*)(hg + (size_t)r * 512 + sl * 16 + c0) = o;
      }
    }
  }
}

// ---------------- phase C: decoder chain + generation loss ----------------
__global__ __launch_bounds__(256, 1) void phaseC(
    char* ws, const float* db1, const float* db2, const float* dmbias,
    const float* genb, const int* ts, float* gpart) {
  __shared__ u16 lA[64 * 640];
  __shared__ u16 lB[64 * 512];
  int rb = blockIdx.x;
  int tid = threadIdx.x, wave = tid >> 6, lane = tid & 63;
  const u16* zall = (const u16*)(ws + OFF_ZALL);
  const u16* hall = (const u16*)(ws + OFF_HALL);
  const u16* wd1 = (const u16*)(ws + OFF_WD1);
  const u16* wd2 = (const u16*)(ws + OFF_WD2);
  const u16* wdm = (const u16*)(ws + OFF_WDM);
  const u16* wgw = (const u16*)(ws + OFF_WGW);

  fill_lds(lA, 640, zall + (size_t)rb * NB * ZDI, 128, hall + (size_t)rb * NB * HDI, 512);
  __syncthreads();
  for (int tile = wave; tile < 32; tile += 4) {
    f32x4 acc[4];
    acc[0] = acc[1] = acc[2] = acc[3] = (f32x4){0.f, 0.f, 0.f, 0.f};
    mm_tile(acc, lA, 640, 0, wd1, 640, tile * 16, 640, lane);
    int col = tile * 16 + (lane & 15);
    float bias = db1[col];
#pragma unroll
    for (int m = 0; m < 4; ++m)
#pragma unroll
      for (int j = 0; j < 4; ++j) {
        int row = (m << 4) + ((lane >> 4) << 2) + j;
        int byte = ((row * 512 + col) << 1) ^ ((row & 7) << 4);
        *(u16*)((char*)lB + byte) = f2b(fmaxf(acc[m][j] + bias, 0.f));
      }
  }
  __syncthreads();
  for (int tile = wave; tile < 32; tile += 4) {
    f32x4 acc[4];
    acc[0] = acc[1] = acc[2] = acc[3] = (f32x4){0.f, 0.f, 0.f, 0.f};
    mm_tile(acc, lB, 512, 0, wd2, 512, tile * 16, 512, lane);
    int col = tile * 16 + (lane & 15);
    float bias = db2[col];
#pragma unroll
    for (int m = 0; m < 4; ++m)
#pragma unroll
      for (int j = 0; j < 4; ++j) {
        int row = (m << 4) + ((lane >> 4) << 2) + j;
        int byte = ((row * 512 + col) << 1) ^ ((row & 7) << 4);
        *(u16*)((char*)lA + byte) = f2b(fmaxf(acc[m][j] + bias, 0.f));
      }
  }
  __syncthreads();
  for (int tile = wave; tile < 16; tile += 4) {
    f32x4 acc[4];
    acc[0] = acc[1] = acc[2] = acc[3] = (f32x4){0.f, 0.f, 0.f, 0.f};
    mm_tile(acc, lA, 512, 0, wdm, 512, tile * 16, 512, lane);
    int col = tile * 16 + (lane & 15);
    float bias = dmbias[col];
#pragma unroll
    for (int m = 0; m < 4; ++m)
#pragma unroll
      for (int j = 0; j < 4; ++j) {
        int row = (m << 4) + ((lane >> 4) << 2) + j;
        float v = 1.f / (1.f + __expf(-(acc[m][j] + bias)));
        int byte = ((row * 256 + col) << 1) ^ ((row & 7) << 4);
        *(u16*)((char*)lB + byte) = f2b(v);
      }
  }
  __syncthreads();
  float mr[16], sr[16], cap[16];
  int tg[16];
#pragma unroll
  for (int q = 0; q < 16; ++q) {
    int r = ((q >> 2) << 4) + ((lane >> 4) << 2) + (q & 3);
    tg[q] = ts[r * TT + rb];
    mr[q] = -1e30f; sr[q] = 0.f; cap[q] = -1e30f;
  }
  for (int ct = wave; ct < 625; ct += 4) {
    f32x4 acc[4];
    acc[0] = acc[1] = acc[2] = acc[3] = (f32x4){0.f, 0.f, 0.f, 0.f};
    mm_tile(acc, lB, 256, 0, wgw, 256, ct * 16, 256, lane);
    int colw = ct * 16 + (lane & 15);
    float gbv = genb[colw];
#pragma unroll
    for (int mi = 0; mi < 4; ++mi)
#pragma unroll
      for (int j = 0; j < 4; ++j) {
        int q = (mi << 2) + j;
        float v = acc[mi][j] + gbv;
        if (colw == tg[q]) cap[q] = v;
        float mn = fmaxf(mr[q], v);
        sr[q] = sr[q] * __expf(mr[q] - mn) + __expf(v - mn);
        mr[q] = mn;
      }
  }
#pragma unroll
  for (int d = 1; d < 16; d <<= 1) {
#pragma unroll
    for (int q = 0; q < 16; ++q) {
      float mo = __shfl_xor(mr[q], d);
      float so = __shfl_xor(sr[q], d);
      float co = __shfl_xor(cap[q], d);
      float mn = fmaxf(mr[q], mo);
      sr[q] = sr[q] * __expf(mr[q] - mn) + so * __expf(mo - mn);
      mr[q] = mn;
      cap[q] = fmaxf(cap[q], co);
    }
  }
  float* sc = (float*)lA;
  if ((lane & 15) == 0) {
    int g = lane >> 4;
#pragma unroll
    for (int q = 0; q < 16; ++q) {
      int r = ((q >> 2) << 4) + (g << 2) + (q & 3);
      sc[wave * 64 + r] = mr[q];
      sc[256 + wave * 64 + r] = sr[q];
      sc[512 + wave * 64 + r] = cap[q];
    }
  }
  __syncthreads();
  if (tid < 64) {
    float M = -1e30f, S = 0.f, C = -1e30f;
#pragma unroll
    for (int w = 0; w < 4; ++w) {
      float m = sc[w * 64 + tid], s = sc[256 + w * 64 + tid], c = sc[512 + w * 64 + tid];
      float mn = fmaxf(M, m);
      S = S * __expf(M - mn) + s * __expf(m - mn);
      M = mn;
      C = fmaxf(C, c);
    }
    float lossr = M + __logf(S) - C;
    for (int d = 1; d < 64; d <<= 1) lossr += __shfl_xor(lossr, d);
    if (tid == 0) gpart[rb] = lossr;
  }
}

// ---------------- final reduce + classifier ----------------
__global__ __launch_bounds__(256) void finalk(char* ws, const int* labels,
                                              const float* cw, const float* cb,
                                              const float* gpart, float* out) {
  __shared__ float sred[256];
  __shared__ float cred[64];
  int tid = threadIdx.x;
  sred[tid] = gpart[tid];
  __syncthreads();
  for (int s2 = 128; s2 > 0; s2 >>= 1) {
    if (tid < s2) sred[tid] += sred[tid + s2];
    __syncthreads();
  }
  const float* h = (const float*)(ws + OFF_H);
  if (tid < 64) {
    const float* hrow = h + tid * 512;
    float a0 = cb[0], a1 = cb[1], a2 = cb[2], a3 = cb[3];
    for (int k = 0; k < 512; k += 4) {
      float4 hv = *(const float4*)(hrow + k);
      float4 w0 = *(const float4*)(cw + 0 * 512 + k);
      float4 w1 = *(const float4*)(cw + 1 * 512 + k);
      float4 w2 = *(const float4*)(cw + 2 * 512 + k);
      float4 w3 = *(const float4*)(cw + 3 * 512 + k);
      a0 += hv.x * w0.x + hv.y * w0.y + hv.z * w0.z + hv.w * w0.w;
      a1 += hv.x * w1.x + hv.y * w1.y + hv.z * w1.z + hv.w * w1.w;
      a2 += hv.x * w2.x + hv.y * w2.y + hv.z * w2.z + hv.w * w2.w;
      a3 += hv.x * w3.x + hv.y * w3.y + hv.z * w3.z + hv.w * w3.w;
    }
    float M = fmaxf(fmaxf(a0, a1), fmaxf(a2, a3));
    float S = __expf(a0 - M) + __expf(a1 - M) + __expf(a2 - M) + __expf(a3 - M);
    int lb = labels[tid];
    float lg = (lb == 0) ? a0 : (lb == 1) ? a1 : (lb == 2) ? a2 : a3;
    cred[tid] = M + __logf(S) - lg;
  }
  __syncthreads();
  if (tid == 0) {
    float cs = 0.f;
    for (int i = 0; i < 64; ++i) cs += cred[i];
    out[0] = sred[0] / 16384.f;
    out[1] = cs / 64.f;
  }
}

extern "C" void kernel_launch(void* const* d_in, const int* in_sizes, int n_in,
                              void* d_out, int out_size, void* d_ws, size_t ws_size,
                              hipStream_t stream) {
  (void)in_sizes; (void)n_in; (void)out_size; (void)ws_size;
  char* ws = (char*)d_ws;
  const int* xs = (const int*)d_in[0];
  const int* ts = (const int*)d_in[1];
  const int* labels = (const int*)d_in[2];
  const int* wflag = (const int*)d_in[3];
  const float* eps = (const float*)d_in[4];
  const float* hnoise = (const float*)d_in[5];
  const float* embed = (const float*)d_in[6];
  const float* e_w1 = (const float*)d_in[7];
  const float* e_b1 = (const float*)d_in[8];
  const float* e_w2 = (const float*)d_in[9];
  const float* e_b2 = (const float*)d_in[10];
  const float* m_w = (const float*)d_in[11];
  const float* m_b = (const float*)d_in[12];
  const float* s_w = (const float*)d_in[13];
  const float* s_b = (const float*)d_in[14];
  const float* d_w1 = (const float*)d_in[15];
  const float* d_b1 = (const float*)d_in[16];
  const float* d_w2 = (const float*)d_in[17];
  const float* d_b2 = (const float*)d_in[18];
  const float* dm_w = (const float*)d_in[19];
  const float* dm_b = (const float*)d_in[20];
  const float* g_ih = (const float*)d_in[21];
  const float* g_hh = (const float*)d_in[22];
  const float* g_bih = (const float*)d_in[23];
  const float* g_bhh = (const float*)d_in[24];
  const float* gw = (const float*)d_in[25];
  const float* gb = (const float*)d_in[26];
  const float* cw = (const float*)d_in[27];
  const float* cb = (const float*)d_in[28];
  const float* hw = (const float*)d_in[29];
  const float* hb0 = (const float*)d_in[30];

  hipMemsetAsync(ws + OFF_XC1, 0, TAGBYTES, stream);   // zero all exchange tags

  ConvArgs ca;
  const float* srcs[10] = {e_w1, e_w2, m_w, s_w, d_w1, d_w2, dm_w, g_ih, g_hh, gw};
  unsigned long long doffs[10] = {OFF_WE1, OFF_WE2, OFF_WMW, OFF_WSW, OFF_WD1,
                                  OFF_WD2, OFF_WDM, OFF_WIH, OFF_WHH, OFF_WGW};
  int ns[10] = {393216, 262144, 65536, 65536, 327680, 262144, 131072, 589824, 786432, 2560000};
  for (int i = 0; i < 10; ++i) { ca.s[i] = srcs[i]; ca.doff[i] = doffs[i]; ca.n[i] = ns[i]; }

  wconv<<<dim3(1250, 10), 256, 0, stream>>>(ws, ca);
  gatherx<<<2048, 256, 0, stream>>>(ws, xs, embed);
  h0init<<<128, 256, 0, stream>>>(ws, labels, wflag, hnoise, hw, hb0);
  gixk<<<256, 256, 0, stream>>>(ws, g_bih);
  phaseB<<<32, 512, 0, stream>>>(ws, eps, e_b1, e_b2, m_b, s_b, g_bhh);
  phaseC<<<256, 256, 0, stream>>>(ws, d_b1, d_b2, dm_b, gb, ts, (float*)(ws + OFF_GPART));
  finalk<<<1, 256, 0, stream>>>(ws, labels, cw, cb, (const float*)(ws + OFF_GPART), (float*)d_out);
}

// Round 9
// 8231.477 us; speedup vs baseline: 1.1346x; 1.1346x over previous
//
#include <hip/hip_runtime.h>

typedef unsigned short u16;
typedef unsigned int u32;
typedef unsigned long long u64;
using bf16x8 = __attribute__((ext_vector_type(8))) short;
using f32x4  = __attribute__((ext_vector_type(4))) float;
using u32x4  = __attribute__((ext_vector_type(4))) unsigned int;

#define TT   256
#define NB   64
#define XDI  256
#define HDI  512
#define ZDI  128
#define VV   10000

// ---- workspace byte offsets ----
#define OFF_WE1   512ull        // [512][768] bf16
#define OFF_WE2   786944ull     // [512][512] bf16
#define OFF_WMW   1311232ull    // [128][512] bf16
#define OFF_WSW   1442304ull    // [128][512] bf16
#define OFF_WD1   1573376ull    // [512][640] bf16
#define OFF_WD2   2228736ull    // [512][512] bf16
#define OFF_WDM   2753024ull    // [256][512] bf16
#define OFF_WIH   3015168ull    // [1536][384] bf16
#define OFF_WHH   4194816ull    // [1536][512] bf16
#define OFF_WGW   5767680ull    // [10000][256] bf16
#define OFF_XEMB  10887680ull   // [256][64][256] bf16
#define OFF_H     19276288ull   // [64][512] f32
#define OFF_ZALL  19997184ull   // [256*64][128] bf16
#define OFF_HALL  24191488ull   // [256*64][512] bf16 (h entering step t)
#define OFF_GPART 40968704ull   // [256] f32
#define OFF_GIX   41102848ull   // [256][1536][64] bf16 (x-part of gi + bih)
// bf16 exchange buffers
#define OFF_XC1   91434496ull   // [64][512] bf16
#define OFF_XE    91500032ull   // [64][512] bf16
#define OFF_XZ    91565568ull   // [2][64][128] bf16
#define OFF_XH    91631104ull   // [2][64][512] bf16
#define OFF_FLAG  91762688ull   // 4 counters, 256B apart

__device__ __forceinline__ u16 f2b(float f) {
  union { float f; u32 u; } v; v.f = f;
  u32 r = v.u + 0x7fffu + ((v.u >> 16) & 1u);
  return (u16)(r >> 16);
}
__device__ __forceinline__ u32 f2b2(float a, float b) {
  return (u32)f2b(a) | ((u32)f2b(b) << 16);
}
__device__ __forceinline__ float b2f(u16 x) {
  union { u32 u; float f; } v; v.u = ((u32)x) << 16; return v.f;
}

#define MFMA16(a, b, c) __builtin_amdgcn_mfma_f32_16x16x32_bf16(a, b, c, 0, 0, 0)

__device__ __forceinline__ const bf16x8* ldsB(const u16* base, int r, int K, int k) {
  return (const bf16x8*)((const char*)base + (((r * K + k) << 1) ^ ((r & 7) << 4)));
}
__device__ __forceinline__ void ldsW(u16* base, int r, int K, int k, uint4 v) {
  *(uint4*)((char*)base + (((r * K + k) << 1) ^ ((r & 7) << 4))) = v;
}

__device__ __forceinline__ void fill_lds(u16* lds, int Ktot,
                                         const u16* s0, int K0,
                                         const u16* s1, int K1) {
  int kch = Ktot >> 3;
  int nch = 64 * kch;
  for (int i = threadIdx.x; i < nch; i += 256) {
    int row = i / kch;
    int k = (i - row * kch) << 3;
    const u16* src = (k < K0) ? (s0 + row * K0 + k) : (s1 + row * K1 + (k - K0));
    uint4 v = *(const uint4*)src;
    ldsW(lds, row, Ktot, k, v);
  }
}

__device__ __forceinline__ void mm_tile(f32x4 acc[4], const u16* lds, int ldsStride, int ldsK0,
                                        const u16* __restrict__ W, int Kw, int wcol0,
                                        int Klen, int lane) {
  const int kl = (lane >> 4) << 3;
  const int cl = lane & 15;
  const u16* wp = W + (size_t)(wcol0 + cl) * Kw;
  for (int kc = 0; kc < Klen; kc += 32) {
    int k = kc + kl;
    bf16x8 b = *(const bf16x8*)(wp + k);
#pragma unroll
    for (int m = 0; m < 4; ++m)
      acc[m] = MFMA16(*ldsB(lds, (m << 4) + cl, ldsStride, ldsK0 + k), b, acc[m]);
  }
}

// ---- MALL-coherent consumer loads (R4/R7-proven) ----
__device__ __forceinline__ void ld16_c(const void* p, u32x4* f) {
  asm volatile(
      "global_load_dwordx4 %0, %16, off sc0 sc1\n\t"
      "global_load_dwordx4 %1, %16, off offset:64 sc0 sc1\n\t"
      "global_load_dwordx4 %2, %16, off offset:128 sc0 sc1\n\t"
      "global_load_dwordx4 %3, %16, off offset:192 sc0 sc1\n\t"
      "global_load_dwordx4 %4, %16, off offset:256 sc0 sc1\n\t"
      "global_load_dwordx4 %5, %16, off offset:320 sc0 sc1\n\t"
      "global_load_dwordx4 %6, %16, off offset:384 sc0 sc1\n\t"
      "global_load_dwordx4 %7, %16, off offset:448 sc0 sc1\n\t"
      "global_load_dwordx4 %8, %16, off offset:512 sc0 sc1\n\t"
      "global_load_dwordx4 %9, %16, off offset:576 sc0 sc1\n\t"
      "global_load_dwordx4 %10, %16, off offset:640 sc0 sc1\n\t"
      "global_load_dwordx4 %11, %16, off offset:704 sc0 sc1\n\t"
      "global_load_dwordx4 %12, %16, off offset:768 sc0 sc1\n\t"
      "global_load_dwordx4 %13, %16, off offset:832 sc0 sc1\n\t"
      "global_load_dwordx4 %14, %16, off offset:896 sc0 sc1\n\t"
      "global_load_dwordx4 %15, %16, off offset:960 sc0 sc1\n\t"
      "s_waitcnt vmcnt(0)"
      : "=&v"(f[0]), "=&v"(f[1]), "=&v"(f[2]), "=&v"(f[3]),
        "=&v"(f[4]), "=&v"(f[5]), "=&v"(f[6]), "=&v"(f[7]),
        "=&v"(f[8]), "=&v"(f[9]), "=&v"(f[10]), "=&v"(f[11]),
        "=&v"(f[12]), "=&v"(f[13]), "=&v"(f[14]), "=&v"(f[15])
      : "v"(p) : "memory");
}
__device__ __forceinline__ void ld4_c(const void* p, u32x4* f) {
  asm volatile(
      "global_load_dwordx4 %0, %4, off sc0 sc1\n\t"
      "global_load_dwordx4 %1, %4, off offset:64 sc0 sc1\n\t"
      "global_load_dwordx4 %2, %4, off offset:128 sc0 sc1\n\t"
      "global_load_dwordx4 %3, %4, off offset:192 sc0 sc1\n\t"
      "s_waitcnt vmcnt(0)"
      : "=&v"(f[0]), "=&v"(f[1]), "=&v"(f[2]), "=&v"(f[3])
      : "v"(p) : "memory");
}
__device__ __forceinline__ void st16B_c(void* p, u32x4 v) {
  asm volatile("global_store_dwordx4 %0, %1, off sc0 sc1" :: "v"(p), "v"(v) : "memory");
}
__device__ __forceinline__ void st8B_c(void* p, u64 v) {
  asm volatile("global_store_dwordx2 %0, %1, off sc0 sc1" :: "v"(p), "v"(v) : "memory");
}
__device__ __forceinline__ void drain_vm() {
  asm volatile("s_waitcnt vmcnt(0)" ::: "memory");
}
// counter sync (compiler-emitted agent-scope atomics; R7-proven)
__device__ __forceinline__ void postc(u32* cnt) {
  __hip_atomic_fetch_add(cnt, 1u, __ATOMIC_RELAXED, __HIP_MEMORY_SCOPE_AGENT);
}
__device__ __forceinline__ void wavespin(u32* cnt, u32 target) {
  while (__hip_atomic_load(cnt, __ATOMIC_RELAXED, __HIP_MEMORY_SCOPE_AGENT) < target) {}
}
__device__ __forceinline__ f32x4 unpk4(u64 g) {
  f32x4 a;
#pragma unroll
  for (int j = 0; j < 4; ++j) a[j] = b2f((u16)(g >> (16 * j)));
  return a;
}
__device__ __forceinline__ float sigm(float x) { return 1.f / (1.f + __expf(-x)); }

// ---------------- prep kernels ----------------
struct ConvArgs { const float* s[10]; unsigned long long doff[10]; int n[10]; };

__global__ __launch_bounds__(256) void wconv(char* ws, ConvArgs a) {
  int seg = blockIdx.y;
  const float* s = a.s[seg];
  u16* d = (u16*)(ws + a.doff[seg]);
  int n = a.n[seg];
  int i = (blockIdx.x * 256 + threadIdx.x) * 8;
  if (i < n) {
    float4 v0 = *(const float4*)(s + i);
    float4 v1 = *(const float4*)(s + i + 4);
    uint4 o;
    o.x = f2b2(v0.x, v0.y); o.y = f2b2(v0.z, v0.w);
    o.z = f2b2(v1.x, v1.y); o.w = f2b2(v1.z, v1.w);
    *(uint4*)(d + i) = o;
  }
}

__global__ __launch_bounds__(256) void gatherx(char* ws, const int* xs, const float* embed) {
  u16* xemb = (u16*)(ws + OFF_XEMB);
  int i = blockIdx.x * 256 + threadIdx.x;
  int t = i >> 11;
  int rr = i & 2047;
  int n = rr >> 5;
  int k = (rr & 31) << 3;
  int idx = xs[n * TT + t];
  const float* src = embed + (size_t)idx * XDI + k;
  float4 v0 = *(const float4*)src;
  float4 v1 = *(const float4*)(src + 4);
  uint4 o;
  o.x = f2b2(v0.x, v0.y); o.y = f2b2(v0.z, v0.w);
  o.z = f2b2(v1.x, v1.y); o.w = f2b2(v1.z, v1.w);
  *(uint4*)(xemb + ((size_t)t * NB + n) * XDI + k) = o;
}

__global__ __launch_bounds__(256) void h0init(char* ws, const int* labels, const int* wflag,
                                              const float* hnoise, const float* hw, const float* hb0) {
  int i = blockIdx.x * 256 + threadIdx.x;  // 32768
  int n = i >> 9, c = i & 511;
  float v = (float)labels[n] * hw[c] + hb0[c];
  if (wflag[0]) v += hnoise[i];
  ((float*)(ws + OFF_H))[i] = v;
  u16 b = f2b(v);
  ((u16*)(ws + OFF_HALL))[i] = b;   // hall[0] = h0 (for phaseC)
  ((u16*)(ws + OFF_XH))[i] = b;     // hexb slot0
}

// gi_x[t][c][n] = bih[c] + sum_k x_emb[t][n][k] * Wih[c][k], k<256
__global__ __launch_bounds__(256) void gixk(char* ws, const float* bih) {
  __shared__ u16 lA[64 * 256];
  int t = blockIdx.x;
  int tid = threadIdx.x, wave = tid >> 6, lane = tid & 63;
  const int cl = lane & 15, rb = (lane >> 4) << 2;
  const u16* xemb = (const u16*)(ws + OFF_XEMB);
  const u16* wih = (const u16*)(ws + OFF_WIH);
  u16* gix = (u16*)(ws + OFF_GIX);
  fill_lds(lA, 256, xemb + (size_t)t * NB * XDI, 256, xemb, 256);
  __syncthreads();
  for (int ct = wave; ct < 96; ct += 4) {
    f32x4 acc[4];
    acc[0] = acc[1] = acc[2] = acc[3] = (f32x4){0.f, 0.f, 0.f, 0.f};
    mm_tile(acc, lA, 256, 0, wih, 384, ct * 16, 256, lane);
    int col = ct * 16 + cl;
    float bv = bih[col];
    u16* dst = gix + ((size_t)t * 1536 + col) * 64;
#pragma unroll
    for (int m = 0; m < 4; ++m) {
      u64 o = (u64)f2b(acc[m][0] + bv) | ((u64)f2b(acc[m][1] + bv) << 16)
            | ((u64)f2b(acc[m][2] + bv) << 32) | ((u64)f2b(acc[m][3] + bv) << 48);
      *(u64*)(dst + (m << 4) + rb) = o;
    }
  }
}

// ---------------- phase B: weight-stationary recurrence, coalesced handoffs ----------------
// 32 WGs x 512 threads. Producer stores coalesced via wave-local LDS transpose;
// wave-level counter spins; only 2 full barriers per step.
__global__ __launch_bounds__(512, 1) void phaseB(
    char* ws, const float* __restrict__ eps,
    const float* __restrict__ b_e1, const float* __restrict__ b_e2,
    const float* __restrict__ b_mw, const float* __restrict__ b_sw,
    const float* __restrict__ bhh) {
  __shared__ u16 wsl[59392];               // 116KB weight slices (swizzled)
  __shared__ float ghb[3][64][16];         // gh tiles
  __shared__ float red[3][64][16];         // gi_z tiles
  __shared__ float musp[64][8];            // mu / pre-softplus std
  __shared__ float hold[64][16];           // own h slice (f32)
  __shared__ __align__(16) u16 stg[64][16]; // store-coalescing stage
  __shared__ u32 mbE;                      // LDS mini-barrier for musp

  u16* wWe1 = wsl;            // [16][768]
  u16* wWhh = wsl + 12288;    // [48][512]
  u16* wWe2 = wsl + 36864;    // [16][512]
  u16* wWms = wsl + 45056;    // [16][512] rows 0-3 mu, 4-7 std
  u16* wWihz = wsl + 53248;   // [48][128]

  const u16* we1 = (const u16*)(ws + OFF_WE1);
  const u16* we2 = (const u16*)(ws + OFF_WE2);
  const u16* wmw = (const u16*)(ws + OFF_WMW);
  const u16* wsw = (const u16*)(ws + OFF_WSW);
  const u16* wih = (const u16*)(ws + OFF_WIH);
  const u16* whh = (const u16*)(ws + OFF_WHH);
  const u16* xemb = (const u16*)(ws + OFF_XEMB);
  const u16* gix = (const u16*)(ws + OFF_GIX);
  float* hg = (float*)(ws + OFF_H);
  u16* zall = (u16*)(ws + OFF_ZALL);
  u16* hall = (u16*)(ws + OFF_HALL);
  u16* c1ex = (u16*)(ws + OFF_XC1);
  u16* eex  = (u16*)(ws + OFF_XE);
  u16* xzb  = (u16*)(ws + OFF_XZ);
  u16* hexb = (u16*)(ws + OFF_XH);
  u32* cC1 = (u32*)(ws + OFF_FLAG);
  u32* cE  = (u32*)(ws + OFF_FLAG + 256);
  u32* cZ  = (u32*)(ws + OFF_FLAG + 512);
  u32* cH  = (u32*)(ws + OFF_FLAG + 768);

  const int tid = threadIdx.x, wave = tid >> 6, lane = tid & 63;
  const int cl = lane & 15, kl = (lane >> 4) << 3, rb = (lane >> 4) << 2;
  const int sl = blockIdx.x;
  const int mt = wave & 3;
  const int arow = mt * 16 + cl;

  // ---- preload weight slices into LDS ----
  for (int c = tid; c < 1536; c += 512) {
    int r = c / 96, k = (c % 96) << 3;
    ldsW(wWe1, r, 768, k, *(const uint4*)(we1 + (size_t)(sl * 16 + r) * 768 + k));
  }
  for (int c = tid; c < 3072; c += 512) {
    int r = c >> 6, k = (c & 63) << 3;
    int gr = (r >> 4) * 512 + sl * 16 + (r & 15);
    ldsW(wWhh, r, 512, k, *(const uint4*)(whh + (size_t)gr * 512 + k));
  }
  for (int c = tid; c < 1024; c += 512) {
    int r = c >> 6, k = (c & 63) << 3;
    ldsW(wWe2, r, 512, k, *(const uint4*)(we2 + (size_t)(sl * 16 + r) * 512 + k));
  }
  for (int c = tid; c < 1024; c += 512) {
    int r = c >> 6, k = (c & 63) << 3;
    uint4 v = {0, 0, 0, 0};
    if (r < 4)      v = *(const uint4*)(wmw + (size_t)(sl * 4 + r) * 512 + k);
    else if (r < 8) v = *(const uint4*)(wsw + (size_t)(sl * 4 + r - 4) * 512 + k);
    ldsW(wWms, r, 512, k, v);
  }
  for (int c = tid; c < 768; c += 512) {
    int r = c >> 4, k = (c & 15) << 3;
    int gr = (r >> 4) * 512 + sl * 16 + (r & 15);
    ldsW(wWihz, r, 128, k, *(const uint4*)(wih + (size_t)gr * 384 + 256 + k));
  }
  for (int i = tid << 1; i < 1024; i += 1024) {
    int r = i >> 4, c = i & 15;
    *(float2*)&hold[r][c] = *(const float2*)(hg + (size_t)r * 512 + sl * 16 + c);
  }
  if (tid == 0) mbE = 0;
  // biases
  const float be1 = b_e1[sl * 16 + cl];
  const float be2 = b_e2[sl * 16 + cl];
  const float bms = (cl < 4) ? b_mw[sl * 4 + cl] : ((cl < 8) ? b_sw[sl * 4 + cl - 4] : 0.f);
  const float bh0 = bhh[sl * 16 + cl];
  const float bh1 = bhh[512 + sl * 16 + cl];
  const float bh2 = bhh[1024 + sl * 16 + cl];
  __syncthreads();

  const f32x4 z4 = {0.f, 0.f, 0.f, 0.f};
  for (int t = 0; t < TT; ++t) {
    const int slot = t & 1;
    // ---- S0: prefetch h-independent operands (plain cached) ----
    u32x4 xf[8];
    u64 gx0 = 0, gx1 = 0;
    float4 ev4 = {0.f, 0.f, 0.f, 0.f};
    if (wave < 4) {
      const u16* xr = xemb + ((size_t)t * NB + arow) * XDI + kl;
#pragma unroll
      for (int i = 0; i < 8; ++i) xf[i] = *(const u32x4*)(xr + i * 32);
      gx0 = *(const u64*)(gix + ((size_t)t * 1536 + sl * 16 + cl) * 64 + mt * 16 + rb);
    } else {
      gx0 = *(const u64*)(gix + ((size_t)t * 1536 + 512 + sl * 16 + cl) * 64 + mt * 16 + rb);
      gx1 = *(const u64*)(gix + ((size_t)t * 1536 + 1024 + sl * 16 + cl) * 64 + mt * 16 + rb);
    }
    if (wave == 0)
      ev4 = *(const float4*)(eps + (size_t)lane * (TT * ZDI) + (size_t)t * ZDI + sl * 4);

    // x-part of c1 BEFORE h arrives
    f32x4 ax = z4;
    if (wave < 4) {
#pragma unroll
      for (int i = 0; i < 8; ++i)
        ax = MFMA16(*(const bf16x8*)&xf[i], *ldsB(wWe1, cl, 768, i * 32 + kl), ax);
    }

    // ---- S1: wave-spin h(t); c1 slice (w0-3) / gh tiles (w4-7) ----
    wavespin(cH, 32u * (u32)t);
    u32x4 hf[16];
    ld16_c(hexb + ((size_t)(slot * NB + arow)) * HDI + kl, hf);
    if (wave < 4) {
      f32x4 a = ax;
#pragma unroll
      for (int c = 0; c < 16; ++c)
        a = MFMA16(*(const bf16x8*)&hf[c], *ldsB(wWe1, cl, 768, 256 + c * 32 + kl), a);
#pragma unroll
      for (int j = 0; j < 4; ++j)
        stg[mt * 16 + rb + j][cl] = f2b(fmaxf(a[j] + be1, 0.f));
      if (lane < 32) {
        int row = mt * 16 + (lane >> 1), half = lane & 1;
        u32x4 v = *(const u32x4*)&stg[row][half * 8];
        st16B_c(c1ex + (size_t)row * 512 + sl * 16 + half * 8, v);
      }
      drain_vm();
      if (lane == 0) postc(cC1);
    } else {
      f32x4 g0 = z4, g1 = z4, g2 = z4;
#pragma unroll
      for (int c = 0; c < 16; ++c) {
        bf16x8 af = *(const bf16x8*)&hf[c];
        g0 = MFMA16(af, *ldsB(wWhh, cl, 512, c * 32 + kl), g0);
        g1 = MFMA16(af, *ldsB(wWhh, 16 + cl, 512, c * 32 + kl), g1);
        g2 = MFMA16(af, *ldsB(wWhh, 32 + cl, 512, c * 32 + kl), g2);
      }
#pragma unroll
      for (int j = 0; j < 4; ++j) {
        ghb[0][mt * 16 + rb + j][cl] = g0[j] + bh0;
        ghb[1][mt * 16 + rb + j][cl] = g1[j] + bh1;
        ghb[2][mt * 16 + rb + j][cl] = g2[j] + bh2;
      }
    }

    if (wave < 4) {
      // ---- S2: e = relu(c1 @ We2^T + b2) ----
      wavespin(cC1, 128u * (u32)(t + 1));
      {
        u32x4 cf[16];
        ld16_c(c1ex + (size_t)arow * 512 + kl, cf);
        f32x4 a = z4;
#pragma unroll
        for (int c = 0; c < 16; ++c)
          a = MFMA16(*(const bf16x8*)&cf[c], *ldsB(wWe2, cl, 512, c * 32 + kl), a);
#pragma unroll
        for (int j = 0; j < 4; ++j)
          stg[mt * 16 + rb + j][cl] = f2b(fmaxf(a[j] + be2, 0.f));
        if (lane < 32) {
          int row = mt * 16 + (lane >> 1), half = lane & 1;
          u32x4 v = *(const u32x4*)&stg[row][half * 8];
          st16B_c(eex + (size_t)row * 512 + sl * 16 + half * 8, v);
        }
        drain_vm();
        if (lane == 0) postc(cE);
      }
      // ---- S3: mu/std slice ----
      wavespin(cE, 128u * (u32)(t + 1));
      {
        u32x4 ef[16];
        ld16_c(eex + (size_t)arow * 512 + kl, ef);
        f32x4 a = z4;
#pragma unroll
        for (int c = 0; c < 16; ++c)
          a = MFMA16(*(const bf16x8*)&ef[c], *ldsB(wWms, cl, 512, c * 32 + kl), a);
        if (cl < 8) {
#pragma unroll
          for (int j = 0; j < 4; ++j) musp[mt * 16 + rb + j][cl] = a[j] + bms;
        }
        if (lane == 0)
          __hip_atomic_fetch_add(&mbE, 1u, __ATOMIC_RELAXED, __HIP_MEMORY_SCOPE_WORKGROUP);
      }
    }

    // ---- S3b: z by wave 0 only (lane == row) ----
    if (wave == 0) {
      while (__hip_atomic_load(&mbE, __ATOMIC_RELAXED, __HIP_MEMORY_SCOPE_WORKGROUP) < 4u * (u32)(t + 1)) {}
      int r = lane;
      float m0 = musp[r][0], m1 = musp[r][1], m2 = musp[r][2], m3 = musp[r][3];
      float s0 = musp[r][4], s1 = musp[r][5], s2 = musp[r][6], s3 = musp[r][7];
      float p0 = fmaxf(s0, 0.f) + log1pf(__expf(-fabsf(s0)));
      float p1 = fmaxf(s1, 0.f) + log1pf(__expf(-fabsf(s1)));
      float p2 = fmaxf(s2, 0.f) + log1pf(__expf(-fabsf(s2)));
      float p3 = fmaxf(s3, 0.f) + log1pf(__expf(-fabsf(s3)));
      float z0 = ev4.x * p0 + m0, z1 = ev4.y * p1 + m1;
      float z2 = ev4.z * p2 + m2, z3 = ev4.w * p3 + m3;
      u64 pk = (u64)f2b2(z0, z1) | ((u64)f2b2(z2, z3) << 32);
      st8B_c(xzb + ((size_t)(slot * NB + r)) * ZDI + sl * 4, pk);
      *(u64*)(zall + ((size_t)t * NB + r) * ZDI + sl * 4) = pk;
      drain_vm();
      if (lane == 0) postc(cZ);
    }

    // ---- S4: z -> gi_z tiles (all 8 waves) ----
    wavespin(cZ, 32u * (u32)(t + 1));
    {
      u32x4 zf[4];
      ld4_c(xzb + ((size_t)(slot * NB + arow)) * ZDI + kl, zf);
      if (wave < 4) {
        f32x4 a = unpk4(gx0);
#pragma unroll
        for (int c = 0; c < 4; ++c)
          a = MFMA16(*(const bf16x8*)&zf[c], *ldsB(wWihz, cl, 128, c * 32 + kl), a);
#pragma unroll
        for (int j = 0; j < 4; ++j) red[0][mt * 16 + rb + j][cl] = a[j];
      } else {
        f32x4 a0 = unpk4(gx0), a1 = unpk4(gx1);
#pragma unroll
        for (int c = 0; c < 4; ++c) {
          bf16x8 af = *(const bf16x8*)&zf[c];
          a0 = MFMA16(af, *ldsB(wWihz, 16 + cl, 128, c * 32 + kl), a0);
          a1 = MFMA16(af, *ldsB(wWihz, 32 + cl, 128, c * 32 + kl), a1);
        }
#pragma unroll
        for (int j = 0; j < 4; ++j) {
          red[1][mt * 16 + rb + j][cl] = a0[j];
          red[2][mt * 16 + rb + j][cl] = a1[j];
        }
      }
    }
    __syncthreads();   // red + ghb ready

    // ---- gates + h' (all 512 threads -> hold LDS) ----
    {
      int r = tid >> 3, c0 = (tid & 7) << 1;
      float rg0 = sigm(red[0][r][c0] + ghb[0][r][c0]);
      float rg1 = sigm(red[0][r][c0 + 1] + ghb[0][r][c0 + 1]);
      float zg0 = sigm(red[1][r][c0] + ghb[1][r][c0]);
      float zg1 = sigm(red[1][r][c0 + 1] + ghb[1][r][c0 + 1]);
      float ng0 = tanhf(red[2][r][c0] + rg0 * ghb[2][r][c0]);
      float ng1 = tanhf(red[2][r][c0 + 1] + rg1 * ghb[2][r][c0 + 1]);
      hold[r][c0]     = (1.f - zg0) * ng0 + zg0 * hold[r][c0];
      hold[r][c0 + 1] = (1.f - zg1) * ng1 + zg1 * hold[r][c0 + 1];
    }
    __syncthreads();   // hold ready

    // ---- h' export: wave0 -> hexb (critical), wave1 -> hall/hg (off-path) ----
    if (t < TT - 1) {
      if (wave == 0) {
        int r = lane;
        const float* hp = &hold[r][0];
        u32x4 w0, w1;
        w0[0] = f2b2(hp[0], hp[1]);  w0[1] = f2b2(hp[2], hp[3]);
        w0[2] = f2b2(hp[4], hp[5]);  w0[3] = f2b2(hp[6], hp[7]);
        w1[0] = f2b2(hp[8], hp[9]);  w1[1] = f2b2(hp[10], hp[11]);
        w1[2] = f2b2(hp[12], hp[13]); w1[3] = f2b2(hp[14], hp[15]);
        u16* dst = hexb + ((size_t)(((t + 1) & 1) * NB + r)) * HDI + sl * 16;
        st16B_c(dst, w0);
        st16B_c(dst + 8, w1);
        drain_vm();
        if (lane == 0) postc(cH);
      } else if (wave == 1) {
        int r = lane;
        const float* hp = &hold[r][0];
        uint4 w0, w1;
        w0.x = f2b2(hp[0], hp[1]);  w0.y = f2b2(hp[2], hp[3]);
        w0.z = f2b2(hp[4], hp[5]);  w0.w = f2b2(hp[6], hp[7]);
        w1.x = f2b2(hp[8], hp[9]);  w1.y = f2b2(hp[10], hp[11]);
        w1.z = f2b2(hp[12], hp[13]); w1.w = f2b2(hp[14], hp[15]);
        u16* dst = hall + ((size_t)(t + 1) * NB + r) * HDI + sl * 16;
        *(uint4*)dst = w0;
        *(uint4*)(dst + 8) = w1;
      }
    } else {
      if (wave == 1) {
        int r = lane;
        float* dst = hg + (size_t)r * 512 + sl * 16;
#pragma unroll
        for (int k = 0; k < 16; k += 4)
          *(float4*)(dst + k) = *(const float4*)&hold[r][k];
      }
    }
  }
}

// ---------------- phase C: decoder chain + generation loss ----------------
__global__ __launch_bounds__(256, 1) void phaseC(
    char* ws, const float* db1, const float* db2, const float* dmbias,
    const float* genb, const int* ts, float* gpart) {
  __shared__ u16 lA[64 * 640];
  __shared__ u16 lB[64 * 512];
  int rb = blockIdx.x;
  int tid = threadIdx.x, wave = tid >> 6, lane = tid & 63;
  const u16* zall = (const u16*)(ws + OFF_ZALL);
  const u16* hall = (const u16*)(ws + OFF_HALL);
  const u16* wd1 = (const u16*)(ws + OFF_WD1);
  const u16* wd2 = (const u16*)(ws + OFF_WD2);
  const u16* wdm = (const u16*)(ws + OFF_WDM);
  const u16* wgw = (const u16*)(ws + OFF_WGW);

  fill_lds(lA, 640, zall + (size_t)rb * NB * ZDI, 128, hall + (size_t)rb * NB * HDI, 512);
  __syncthreads();
  for (int tile = wave; tile < 32; tile += 4) {
    f32x4 acc[4];
    acc[0] = acc[1] = acc[2] = acc[3] = (f32x4){0.f, 0.f, 0.f, 0.f};
    mm_tile(acc, lA, 640, 0, wd1, 640, tile * 16, 640, lane);
    int col = tile * 16 + (lane & 15);
    float bias = db1[col];
#pragma unroll
    for (int m = 0; m < 4; ++m)
#pragma unroll
      for (int j = 0; j < 4; ++j) {
        int row = (m << 4) + ((lane >> 4) << 2) + j;
        int byte = ((row * 512 + col) << 1) ^ ((row & 7) << 4);
        *(u16*)((char*)lB + byte) = f2b(fmaxf(acc[m][j] + bias, 0.f));
      }
  }
  __syncthreads();
  for (int tile = wave; tile < 32; tile += 4) {
    f32x4 acc[4];
    acc[0] = acc[1] = acc[2] = acc[3] = (f32x4){0.f, 0.f, 0.f, 0.f};
    mm_tile(acc, lB, 512, 0, wd2, 512, tile * 16, 512, lane);
    int col = tile * 16 + (lane & 15);
    float bias = db2[col];
#pragma unroll
    for (int m = 0; m < 4; ++m)
#pragma unroll
      for (int j = 0; j < 4; ++j) {
        int row = (m << 4) + ((lane >> 4) << 2) + j;
        int byte = ((row * 512 + col) << 1) ^ ((row & 7) << 4);
        *(u16*)((char*)lA + byte) = f2b(fmaxf(acc[m][j] + bias, 0.f));
      }
  }
  __syncthreads();
  for (int tile = wave; tile < 16; tile += 4) {
    f32x4 acc[4];
    acc[0] = acc[1] = acc[2] = acc[3] = (f32x4){0.f, 0.f, 0.f, 0.f};
    mm_tile(acc, lA, 512, 0, wdm, 512, tile * 16, 512, lane);
    int col = tile * 16 + (lane & 15);
    float bias = dmbias[col];
#pragma unroll
    for (int m = 0; m < 4; ++m)
#pragma unroll
      for (int j = 0; j < 4; ++j) {
        int row = (m << 4) + ((lane >> 4) << 2) + j;
        float v = 1.f / (1.f + __expf(-(acc[m][j] + bias)));
        int byte = ((row * 256 + col) << 1) ^ ((row & 7) << 4);
        *(u16*)((char*)lB + byte) = f2b(v);
      }
  }
  __syncthreads();
  float mr[16], sr[16], cap[16];
  int tg[16];
#pragma unroll
  for (int q = 0; q < 16; ++q) {
    int r = ((q >> 2) << 4) + ((lane >> 4) << 2) + (q & 3);
    tg[q] = ts[r * TT + rb];
    mr[q] = -1e30f; sr[q] = 0.f; cap[q] = -1e30f;
  }
  for (int ct = wave; ct < 625; ct += 4) {
    f32x4 acc[4];
    acc[0] = acc[1] = acc[2] = acc[3] = (f32x4){0.f, 0.f, 0.f, 0.f};
    mm_tile(acc, lB, 256, 0, wgw, 256, ct * 16, 256, lane);
    int colw = ct * 16 + (lane & 15);
    float gbv = genb[colw];
#pragma unroll
    for (int mi = 0; mi < 4; ++mi)
#pragma unroll
      for (int j = 0; j < 4; ++j) {
        int q = (mi << 2) + j;
        float v = acc[mi][j] + gbv;
        if (colw == tg[q]) cap[q] = v;
        float mn = fmaxf(mr[q], v);
        sr[q] = sr[q] * __expf(mr[q] - mn) + __expf(v - mn);
        mr[q] = mn;
      }
  }
#pragma unroll
  for (int d = 1; d < 16; d <<= 1) {
#pragma unroll
    for (int q = 0; q < 16; ++q) {
      float mo = __shfl_xor(mr[q], d);
      float so = __shfl_xor(sr[q], d);
      float co = __shfl_xor(cap[q], d);
      float mn = fmaxf(mr[q], mo);
      sr[q] = sr[q] * __expf(mr[q] - mn) + so * __expf(mo - mn);
      mr[q] = mn;
      cap[q] = fmaxf(cap[q], co);
    }
  }
  float* sc = (float*)lA;
  if ((lane & 15) == 0) {
    int g = lane >> 4;
#pragma unroll
    for (int q = 0; q < 16; ++q) {
      int r = ((q >> 2) << 4) + (g << 2) + (q & 3);
      sc[wave * 64 + r] = mr[q];
      sc[256 + wave * 64 + r] = sr[q];
      sc[512 + wave * 64 + r] = cap[q];
    }
  }
  __syncthreads();
  if (tid < 64) {
    float M = -1e30f, S = 0.f, C = -1e30f;
#pragma unroll
    for (int w = 0; w < 4; ++w) {
      float m = sc[w * 64 + tid], s = sc[256 + w * 64 + tid], c = sc[512 + w * 64 + tid];
      float mn = fmaxf(M, m);
      S = S * __expf(M - mn) + s * __expf(m - mn);
      M = mn;
      C = fmaxf(C, c);
    }
    float lossr = M + __logf(S) - C;
    for (int d = 1; d < 64; d <<= 1) lossr += __shfl_xor(lossr, d);
    if (tid == 0) gpart[rb] = lossr;
  }
}

// ---------------- final reduce + classifier ----------------
__global__ __launch_bounds__(256) void finalk(char* ws, const int* labels,
                                              const float* cw, const float* cb,
                                              const float* gpart, float* out) {
  __shared__ float sred[256];
  __shared__ float cred[64];
  int tid = threadIdx.x;
  sred[tid] = gpart[tid];
  __syncthreads();
  for (int s2 = 128; s2 > 0; s2 >>= 1) {
    if (tid < s2) sred[tid] += sred[tid + s2];
    __syncthreads();
  }
  const float* h = (const float*)(ws + OFF_H);
  if (tid < 64) {
    const float* hrow = h + tid * 512;
    float a0 = cb[0], a1 = cb[1], a2 = cb[2], a3 = cb[3];
    for (int k = 0; k < 512; k += 4) {
      float4 hv = *(const float4*)(hrow + k);
      float4 w0 = *(const float4*)(cw + 0 * 512 + k);
      float4 w1 = *(const float4*)(cw + 1 * 512 + k);
      float4 w2 = *(const float4*)(cw + 2 * 512 + k);
      float4 w3 = *(const float4*)(cw + 3 * 512 + k);
      a0 += hv.x * w0.x + hv.y * w0.y + hv.z * w0.z + hv.w * w0.w;
      a1 += hv.x * w1.x + hv.y * w1.y + hv.z * w1.z + hv.w * w1.w;
      a2 += hv.x * w2.x + hv.y * w2.y + hv.z * w2.z + hv.w * w2.w;
      a3 += hv.x * w3.x + hv.y * w3.y + hv.z * w3.z + hv.w * w3.w;
    }
    float M = fmaxf(fmaxf(a0, a1), fmaxf(a2, a3));
    float S = __expf(a0 - M) + __expf(a1 - M) + __expf(a2 - M) + __expf(a3 - M);
    int lb = labels[tid];
    float lg = (lb == 0) ? a0 : (lb == 1) ? a1 : (lb == 2) ? a2 : a3;
    cred[tid] = M + __logf(S) - lg;
  }
  __syncthreads();
  if (tid == 0) {
    float cs = 0.f;
    for (int i = 0; i < 64; ++i) cs += cred[i];
    out[0] = sred[0] / 16384.f;
    out[1] = cs / 64.f;
  }
}

extern "C" void kernel_launch(void* const* d_in, const int* in_sizes, int n_in,
                              void* d_out, int out_size, void* d_ws, size_t ws_size,
                              hipStream_t stream) {
  (void)in_sizes; (void)n_in; (void)out_size; (void)ws_size;
  char* ws = (char*)d_ws;
  const int* xs = (const int*)d_in[0];
  const int* ts = (const int*)d_in[1];
  const int* labels = (const int*)d_in[2];
  const int* wflag = (const int*)d_in[3];
  const float* eps = (const float*)d_in[4];
  const float* hnoise = (const float*)d_in[5];
  const float* embed = (const float*)d_in[6];
  const float* e_w1 = (const float*)d_in[7];
  const float* e_b1 = (const float*)d_in[8];
  const float* e_w2 = (const float*)d_in[9];
  const float* e_b2 = (const float*)d_in[10];
  const float* m_w = (const float*)d_in[11];
  const float* m_b = (const float*)d_in[12];
  const float* s_w = (const float*)d_in[13];
  const float* s_b = (const float*)d_in[14];
  const float* d_w1 = (const float*)d_in[15];
  const float* d_b1 = (const float*)d_in[16];
  const float* d_w2 = (const float*)d_in[17];
  const float* d_b2 = (const float*)d_in[18];
  const float* dm_w = (const float*)d_in[19];
  const float* dm_b = (const float*)d_in[20];
  const float* g_ih = (const float*)d_in[21];
  const float* g_hh = (const float*)d_in[22];
  const float* g_bih = (const float*)d_in[23];
  const float* g_bhh = (const float*)d_in[24];
  const float* gw = (const float*)d_in[25];
  const float* gb = (const float*)d_in[26];
  const float* cw = (const float*)d_in[27];
  const float* cb = (const float*)d_in[28];
  const float* hw = (const float*)d_in[29];
  const float* hb0 = (const float*)d_in[30];

  hipMemsetAsync(ws + OFF_FLAG, 0, 1024, stream);

  ConvArgs ca;
  const float* srcs[10] = {e_w1, e_w2, m_w, s_w, d_w1, d_w2, dm_w, g_ih, g_hh, gw};
  unsigned long long doffs[10] = {OFF_WE1, OFF_WE2, OFF_WMW, OFF_WSW, OFF_WD1,
                                  OFF_WD2, OFF_WDM, OFF_WIH, OFF_WHH, OFF_WGW};
  int ns[10] = {393216, 262144, 65536, 65536, 327680, 262144, 131072, 589824, 786432, 2560000};
  for (int i = 0; i < 10; ++i) { ca.s[i] = srcs[i]; ca.doff[i] = doffs[i]; ca.n[i] = ns[i]; }

  wconv<<<dim3(1250, 10), 256, 0, stream>>>(ws, ca);
  gatherx<<<2048, 256, 0, stream>>>(ws, xs, embed);
  h0init<<<128, 256, 0, stream>>>(ws, labels, wflag, hnoise, hw, hb0);
  gixk<<<256, 256, 0, stream>>>(ws, g_bih);
  phaseB<<<32, 512, 0, stream>>>(ws, eps, e_b1, e_b2, m_b, s_b, g_bhh);
  phaseC<<<256, 256, 0, stream>>>(ws, d_b1, d_b2, dm_b, gb, ts, (float*)(ws + OFF_GPART));
  finalk<<<1, 256, 0, stream>>>(ws, labels, cw, cb, (const float*)(ws + OFF_GPART), (float*)d_out);
}

// Round 10
// 7079.809 us; speedup vs baseline: 1.3191x; 1.1627x over previous
//
#include <hip/hip_runtime.h>

typedef unsigned short u16;
typedef unsigned int u32;
typedef unsigned long long u64;
using bf16x8 = __attribute__((ext_vector_type(8))) short;
using f32x4  = __attribute__((ext_vector_type(4))) float;
using u32x4  = __attribute__((ext_vector_type(4))) unsigned int;

#define TT   256
#define NB   64
#define XDI  256
#define HDI  512
#define ZDI  128
#define VV   10000

// ---- workspace byte offsets ----
#define OFF_WE1   512ull        // [512][768] bf16
#define OFF_WE2   786944ull     // [512][512] bf16
#define OFF_WMW   1311232ull    // [128][512] bf16
#define OFF_WSW   1442304ull    // [128][512] bf16
#define OFF_WD1   1573376ull    // [512][640] bf16
#define OFF_WD2   2228736ull    // [512][512] bf16
#define OFF_WDM   2753024ull    // [256][512] bf16
#define OFF_WIH   3015168ull    // [1536][384] bf16
#define OFF_WHH   4194816ull    // [1536][512] bf16
#define OFF_WGW   5767680ull    // [10000][256] bf16
#define OFF_XEMB  10887680ull   // [256][64][256] bf16
#define OFF_H     19276288ull   // [64][512] f32
#define OFF_ZALL  19997184ull   // [256*64][128] bf16
#define OFF_HALL  24191488ull   // [256*64][512] bf16 (h entering step t)
#define OFF_GPART 40968704ull   // [256] f32
#define OFF_GIX   41102848ull   // [256][1536][64] bf16 (x-part of gi + bih)
// bf16 exchange buffers
#define OFF_XC1   91434496ull   // [64][512] bf16
#define OFF_XE    91500032ull   // [64][512] bf16
#define OFF_XZ    91565568ull   // [2][64][128] bf16
#define OFF_XH    91631104ull   // [2][64][512] bf16
#define OFF_FLAG  91762688ull   // 4 counters, 256B apart

__device__ __forceinline__ u16 f2b(float f) {
  union { float f; u32 u; } v; v.f = f;
  u32 r = v.u + 0x7fffu + ((v.u >> 16) & 1u);
  return (u16)(r >> 16);
}
__device__ __forceinline__ u32 f2b2(float a, float b) {
  return (u32)f2b(a) | ((u32)f2b(b) << 16);
}
__device__ __forceinline__ float b2f(u16 x) {
  union { u32 u; float f; } v; v.u = ((u32)x) << 16; return v.f;
}

#define MFMA16(a, b, c) __builtin_amdgcn_mfma_f32_16x16x32_bf16(a, b, c, 0, 0, 0)

__device__ __forceinline__ const bf16x8* ldsB(const u16* base, int r, int K, int k) {
  return (const bf16x8*)((const char*)base + (((r * K + k) << 1) ^ ((r & 7) << 4)));
}
__device__ __forceinline__ void ldsW(u16* base, int r, int K, int k, uint4 v) {
  *(uint4*)((char*)base + (((r * K + k) << 1) ^ ((r & 7) << 4))) = v;
}

__device__ __forceinline__ void fill_lds(u16* lds, int Ktot,
                                         const u16* s0, int K0,
                                         const u16* s1, int K1) {
  int kch = Ktot >> 3;
  int nch = 64 * kch;
  for (int i = threadIdx.x; i < nch; i += 256) {
    int row = i / kch;
    int k = (i - row * kch) << 3;
    const u16* src = (k < K0) ? (s0 + row * K0 + k) : (s1 + row * K1 + (k - K0));
    uint4 v = *(const uint4*)src;
    ldsW(lds, row, Ktot, k, v);
  }
}

__device__ __forceinline__ void mm_tile(f32x4 acc[4], const u16* lds, int ldsStride, int ldsK0,
                                        const u16* __restrict__ W, int Kw, int wcol0,
                                        int Klen, int lane) {
  const int kl = (lane >> 4) << 3;
  const int cl = lane & 15;
  const u16* wp = W + (size_t)(wcol0 + cl) * Kw;
  for (int kc = 0; kc < Klen; kc += 32) {
    int k = kc + kl;
    bf16x8 b = *(const bf16x8*)(wp + k);
#pragma unroll
    for (int m = 0; m < 4; ++m)
      acc[m] = MFMA16(*ldsB(lds, (m << 4) + cl, ldsStride, ldsK0 + k), b, acc[m]);
  }
}

// ---- MALL-coherent consumer loads (R4/R7-proven) ----
__device__ __forceinline__ void ld16_c(const void* p, u32x4* f) {
  asm volatile(
      "global_load_dwordx4 %0, %16, off sc0 sc1\n\t"
      "global_load_dwordx4 %1, %16, off offset:64 sc0 sc1\n\t"
      "global_load_dwordx4 %2, %16, off offset:128 sc0 sc1\n\t"
      "global_load_dwordx4 %3, %16, off offset:192 sc0 sc1\n\t"
      "global_load_dwordx4 %4, %16, off offset:256 sc0 sc1\n\t"
      "global_load_dwordx4 %5, %16, off offset:320 sc0 sc1\n\t"
      "global_load_dwordx4 %6, %16, off offset:384 sc0 sc1\n\t"
      "global_load_dwordx4 %7, %16, off offset:448 sc0 sc1\n\t"
      "global_load_dwordx4 %8, %16, off offset:512 sc0 sc1\n\t"
      "global_load_dwordx4 %9, %16, off offset:576 sc0 sc1\n\t"
      "global_load_dwordx4 %10, %16, off offset:640 sc0 sc1\n\t"
      "global_load_dwordx4 %11, %16, off offset:704 sc0 sc1\n\t"
      "global_load_dwordx4 %12, %16, off offset:768 sc0 sc1\n\t"
      "global_load_dwordx4 %13, %16, off offset:832 sc0 sc1\n\t"
      "global_load_dwordx4 %14, %16, off offset:896 sc0 sc1\n\t"
      "global_load_dwordx4 %15, %16, off offset:960 sc0 sc1\n\t"
      "s_waitcnt vmcnt(0)"
      : "=&v"(f[0]), "=&v"(f[1]), "=&v"(f[2]), "=&v"(f[3]),
        "=&v"(f[4]), "=&v"(f[5]), "=&v"(f[6]), "=&v"(f[7]),
        "=&v"(f[8]), "=&v"(f[9]), "=&v"(f[10]), "=&v"(f[11]),
        "=&v"(f[12]), "=&v"(f[13]), "=&v"(f[14]), "=&v"(f[15])
      : "v"(p) : "memory");
}
__device__ __forceinline__ void ld4_c(const void* p, u32x4* f) {
  asm volatile(
      "global_load_dwordx4 %0, %4, off sc0 sc1\n\t"
      "global_load_dwordx4 %1, %4, off offset:64 sc0 sc1\n\t"
      "global_load_dwordx4 %2, %4, off offset:128 sc0 sc1\n\t"
      "global_load_dwordx4 %3, %4, off offset:192 sc0 sc1\n\t"
      "s_waitcnt vmcnt(0)"
      : "=&v"(f[0]), "=&v"(f[1]), "=&v"(f[2]), "=&v"(f[3])
      : "v"(p) : "memory");
}
__device__ __forceinline__ void st16B_c(void* p, u32x4 v) {
  asm volatile("global_store_dwordx4 %0, %1, off sc0 sc1" :: "v"(p), "v"(v) : "memory");
}
__device__ __forceinline__ void st8B_c(void* p, u64 v) {
  asm volatile("global_store_dwordx2 %0, %1, off sc0 sc1" :: "v"(p), "v"(v) : "memory");
}
__device__ __forceinline__ void drain_vm() {
  asm volatile("s_waitcnt vmcnt(0)" ::: "memory");
}
// global counters: compiler-emitted agent-scope atomics (R7-proven)
__device__ __forceinline__ void postc(u32* cnt) {
  __hip_atomic_fetch_add(cnt, 1u, __ATOMIC_RELAXED, __HIP_MEMORY_SCOPE_AGENT);
}
// per-wave poll: lane0 spins with backoff, wave reconverges
__device__ __forceinline__ void wpoll(u32* cnt, int lane, u32 target) {
  if (lane == 0) {
    while (__hip_atomic_load(cnt, __ATOMIC_RELAXED, __HIP_MEMORY_SCOPE_AGENT) < target)
      __builtin_amdgcn_s_sleep(1);
  }
  __builtin_amdgcn_sched_barrier(0);
}
__device__ __forceinline__ f32x4 unpk4(u64 g) {
  f32x4 a;
#pragma unroll
  for (int j = 0; j < 4; ++j) a[j] = b2f((u16)(g >> (16 * j)));
  return a;
}
__device__ __forceinline__ float sigm(float x) { return 1.f / (1.f + __expf(-x)); }

// ---------------- prep kernels ----------------
struct ConvArgs { const float* s[10]; unsigned long long doff[10]; int n[10]; };

__global__ __launch_bounds__(256) void wconv(char* ws, ConvArgs a) {
  int seg = blockIdx.y;
  const float* s = a.s[seg];
  u16* d = (u16*)(ws + a.doff[seg]);
  int n = a.n[seg];
  int i = (blockIdx.x * 256 + threadIdx.x) * 8;
  if (i < n) {
    float4 v0 = *(const float4*)(s + i);
    float4 v1 = *(const float4*)(s + i + 4);
    uint4 o;
    o.x = f2b2(v0.x, v0.y); o.y = f2b2(v0.z, v0.w);
    o.z = f2b2(v1.x, v1.y); o.w = f2b2(v1.z, v1.w);
    *(uint4*)(d + i) = o;
  }
}

__global__ __launch_bounds__(256) void gatherx(char* ws, const int* xs, const float* embed) {
  u16* xemb = (u16*)(ws + OFF_XEMB);
  int i = blockIdx.x * 256 + threadIdx.x;
  int t = i >> 11;
  int rr = i & 2047;
  int n = rr >> 5;
  int k = (rr & 31) << 3;
  int idx = xs[n * TT + t];
  const float* src = embed + (size_t)idx * XDI + k;
  float4 v0 = *(const float4*)src;
  float4 v1 = *(const float4*)(src + 4);
  uint4 o;
  o.x = f2b2(v0.x, v0.y); o.y = f2b2(v0.z, v0.w);
  o.z = f2b2(v1.x, v1.y); o.w = f2b2(v1.z, v1.w);
  *(uint4*)(xemb + ((size_t)t * NB + n) * XDI + k) = o;
}

__global__ __launch_bounds__(256) void h0init(char* ws, const int* labels, const int* wflag,
                                              const float* hnoise, const float* hw, const float* hb0) {
  int i = blockIdx.x * 256 + threadIdx.x;  // 32768
  int n = i >> 9, c = i & 511;
  float v = (float)labels[n] * hw[c] + hb0[c];
  if (wflag[0]) v += hnoise[i];
  ((float*)(ws + OFF_H))[i] = v;
  u16 b = f2b(v);
  ((u16*)(ws + OFF_HALL))[i] = b;   // hall[0] = h0 (for phaseC)
  ((u16*)(ws + OFF_XH))[i] = b;     // hexb slot0
}

// gi_x[t][c][n] = bih[c] + sum_k x_emb[t][n][k] * Wih[c][k], k<256
__global__ __launch_bounds__(256) void gixk(char* ws, const float* bih) {
  __shared__ u16 lA[64 * 256];
  int t = blockIdx.x;
  int tid = threadIdx.x, wave = tid >> 6, lane = tid & 63;
  const int cl = lane & 15, rb = (lane >> 4) << 2;
  const u16* xemb = (const u16*)(ws + OFF_XEMB);
  const u16* wih = (const u16*)(ws + OFF_WIH);
  u16* gix = (u16*)(ws + OFF_GIX);
  fill_lds(lA, 256, xemb + (size_t)t * NB * XDI, 256, xemb, 256);
  __syncthreads();
  for (int ct = wave; ct < 96; ct += 4) {
    f32x4 acc[4];
    acc[0] = acc[1] = acc[2] = acc[3] = (f32x4){0.f, 0.f, 0.f, 0.f};
    mm_tile(acc, lA, 256, 0, wih, 384, ct * 16, 256, lane);
    int col = ct * 16 + cl;
    float bv = bih[col];
    u16* dst = gix + ((size_t)t * 1536 + col) * 64;
#pragma unroll
    for (int m = 0; m < 4; ++m) {
      u64 o = (u64)f2b(acc[m][0] + bv) | ((u64)f2b(acc[m][1] + bv) << 16)
            | ((u64)f2b(acc[m][2] + bv) << 32) | ((u64)f2b(acc[m][3] + bv) << 48);
      *(u64*)(dst + (m << 4) + rb) = o;
    }
  }
}

// ---------------- phase B: weight-stationary recurrence ----------------
// 32 WGs x 512 threads. Per-wave polls (lane0+sleep), LDS completion counters,
// coalesced exchange stores. Waves 0-3: c1->e->ms chain; waves 4-7: gh + gi_z.
__global__ __launch_bounds__(512, 1) void phaseB(
    char* ws, const float* __restrict__ eps,
    const float* __restrict__ b_e1, const float* __restrict__ b_e2,
    const float* __restrict__ b_mw, const float* __restrict__ b_sw,
    const float* __restrict__ bhh) {
  __shared__ u16 wsl[59392];                // 116KB weight slices (swizzled)
  __shared__ float ghb[3][64][16];          // gh tiles
  __shared__ float red[3][64][16];          // gi_z tiles
  __shared__ float musp[64][8];             // mu / pre-softplus std
  __shared__ float hold[64][16];            // own h slice (f32)
  __shared__ __align__(16) u16 stg[64][16]; // store-coalescing stage
  __shared__ u32 wgc[4];                    // LDS completion counters [C1,E,MS,-]

  u16* wWe1 = wsl;            // [16][768]
  u16* wWhh = wsl + 12288;    // [48][512]
  u16* wWe2 = wsl + 36864;    // [16][512]
  u16* wWms = wsl + 45056;    // [16][512] rows 0-3 mu, 4-7 std
  u16* wWihz = wsl + 53248;   // [48][128]

  const u16* we1 = (const u16*)(ws + OFF_WE1);
  const u16* we2 = (const u16*)(ws + OFF_WE2);
  const u16* wmw = (const u16*)(ws + OFF_WMW);
  const u16* wsw = (const u16*)(ws + OFF_WSW);
  const u16* wih = (const u16*)(ws + OFF_WIH);
  const u16* whh = (const u16*)(ws + OFF_WHH);
  const u16* xemb = (const u16*)(ws + OFF_XEMB);
  const u16* gix = (const u16*)(ws + OFF_GIX);
  float* hg = (float*)(ws + OFF_H);
  u16* zall = (u16*)(ws + OFF_ZALL);
  u16* hall = (u16*)(ws + OFF_HALL);
  u16* c1ex = (u16*)(ws + OFF_XC1);
  u16* eex  = (u16*)(ws + OFF_XE);
  u16* xzb  = (u16*)(ws + OFF_XZ);
  u16* hexb = (u16*)(ws + OFF_XH);
  u32* cC1 = (u32*)(ws + OFF_FLAG);
  u32* cE  = (u32*)(ws + OFF_FLAG + 256);
  u32* cZ  = (u32*)(ws + OFF_FLAG + 512);
  u32* cH  = (u32*)(ws + OFF_FLAG + 768);

  const int tid = threadIdx.x, wave = tid >> 6, lane = tid & 63;
  const int cl = lane & 15, kl = (lane >> 4) << 3, rb = (lane >> 4) << 2;
  const int sl = blockIdx.x;
  const int mt = wave & 3;
  const int arow = mt * 16 + cl;

  // ---- preload weight slices into LDS ----
  for (int c = tid; c < 1536; c += 512) {
    int r = c / 96, k = (c % 96) << 3;
    ldsW(wWe1, r, 768, k, *(const uint4*)(we1 + (size_t)(sl * 16 + r) * 768 + k));
  }
  for (int c = tid; c < 3072; c += 512) {
    int r = c >> 6, k = (c & 63) << 3;
    int gr = (r >> 4) * 512 + sl * 16 + (r & 15);
    ldsW(wWhh, r, 512, k, *(const uint4*)(whh + (size_t)gr * 512 + k));
  }
  for (int c = tid; c < 1024; c += 512) {
    int r = c >> 6, k = (c & 63) << 3;
    ldsW(wWe2, r, 512, k, *(const uint4*)(we2 + (size_t)(sl * 16 + r) * 512 + k));
  }
  for (int c = tid; c < 1024; c += 512) {
    int r = c >> 6, k = (c & 63) << 3;
    uint4 v = {0, 0, 0, 0};
    if (r < 4)      v = *(const uint4*)(wmw + (size_t)(sl * 4 + r) * 512 + k);
    else if (r < 8) v = *(const uint4*)(wsw + (size_t)(sl * 4 + r - 4) * 512 + k);
    ldsW(wWms, r, 512, k, v);
  }
  for (int c = tid; c < 768; c += 512) {
    int r = c >> 4, k = (c & 15) << 3;
    int gr = (r >> 4) * 512 + sl * 16 + (r & 15);
    ldsW(wWihz, r, 128, k, *(const uint4*)(wih + (size_t)gr * 384 + 256 + k));
  }
  for (int i = tid << 1; i < 1024; i += 1024) {
    int r = i >> 4, c = i & 15;
    *(float2*)&hold[r][c] = *(const float2*)(hg + (size_t)r * 512 + sl * 16 + c);
  }
  if (tid < 4) wgc[tid] = 0;
  // biases
  const float be1 = b_e1[sl * 16 + cl];
  const float be2 = b_e2[sl * 16 + cl];
  const float bms = (cl < 4) ? b_mw[sl * 4 + cl] : ((cl < 8) ? b_sw[sl * 4 + cl - 4] : 0.f);
  const float bh0 = bhh[sl * 16 + cl];
  const float bh1 = bhh[512 + sl * 16 + cl];
  const float bh2 = bhh[1024 + sl * 16 + cl];
  __syncthreads();

  const f32x4 z4 = {0.f, 0.f, 0.f, 0.f};
  for (int t = 0; t < TT; ++t) {
    const int slot = t & 1;
    // ---- S0: prefetch h-independent operands (plain cached) ----
    u32x4 xf[8];
    u64 gx0 = 0, gx1 = 0;
    float4 ev4 = {0.f, 0.f, 0.f, 0.f};
    if (wave < 4) {
      const u16* xr = xemb + ((size_t)t * NB + arow) * XDI + kl;
#pragma unroll
      for (int i = 0; i < 8; ++i) xf[i] = *(const u32x4*)(xr + i * 32);
      gx0 = *(const u64*)(gix + ((size_t)t * 1536 + sl * 16 + cl) * 64 + mt * 16 + rb);
    } else {
      gx0 = *(const u64*)(gix + ((size_t)t * 1536 + 512 + sl * 16 + cl) * 64 + mt * 16 + rb);
      gx1 = *(const u64*)(gix + ((size_t)t * 1536 + 1024 + sl * 16 + cl) * 64 + mt * 16 + rb);
    }
    if (wave == 0)
      ev4 = *(const float4*)(eps + (size_t)lane * (TT * ZDI) + (size_t)t * ZDI + sl * 4);

    // x-part of c1 BEFORE h arrives
    f32x4 ax = z4;
    if (wave < 4) {
#pragma unroll
      for (int i = 0; i < 8; ++i)
        ax = MFMA16(*(const bf16x8*)&xf[i], *ldsB(wWe1, cl, 768, i * 32 + kl), ax);
    }

    // ---- S1: per-wave poll h(t); c1 (w0-3) / gh (w4-7) ----
    wpoll(cH, lane, 32u * (u32)t);
    u32x4 hf[16];
    ld16_c(hexb + ((size_t)(slot * NB + arow)) * HDI + kl, hf);
    if (wave < 4) {
      f32x4 a = ax;
#pragma unroll
      for (int c = 0; c < 16; ++c)
        a = MFMA16(*(const bf16x8*)&hf[c], *ldsB(wWe1, cl, 768, 256 + c * 32 + kl), a);
#pragma unroll
      for (int j = 0; j < 4; ++j)
        stg[mt * 16 + rb + j][cl] = f2b(fmaxf(a[j] + be1, 0.f));
      if (lane < 32) {
        int row = mt * 16 + (lane >> 1), half = lane & 1;
        u32x4 v = *(const u32x4*)&stg[row][half * 8];
        st16B_c(c1ex + (size_t)row * 512 + sl * 16 + half * 8, v);
      }
      drain_vm();
      if (lane == 0) {
        u32 o = __hip_atomic_fetch_add(&wgc[0], 1u, __ATOMIC_RELAXED, __HIP_MEMORY_SCOPE_WORKGROUP);
        if (o == 4u * (u32)t + 3u) postc(cC1);
      }
    } else {
      f32x4 g0 = z4, g1 = z4, g2 = z4;
#pragma unroll
      for (int c = 0; c < 16; ++c) {
        bf16x8 af = *(const bf16x8*)&hf[c];
        g0 = MFMA16(af, *ldsB(wWhh, cl, 512, c * 32 + kl), g0);
        g1 = MFMA16(af, *ldsB(wWhh, 16 + cl, 512, c * 32 + kl), g1);
        g2 = MFMA16(af, *ldsB(wWhh, 32 + cl, 512, c * 32 + kl), g2);
      }
#pragma unroll
      for (int j = 0; j < 4; ++j) {
        ghb[0][mt * 16 + rb + j][cl] = g0[j] + bh0;
        ghb[1][mt * 16 + rb + j][cl] = g1[j] + bh1;
        ghb[2][mt * 16 + rb + j][cl] = g2[j] + bh2;
      }
    }

    if (wave < 4) {
      // ---- S2: e = relu(c1 @ We2^T + b2) ----
      wpoll(cC1, lane, 32u * (u32)(t + 1));
      {
        u32x4 cf[16];
        ld16_c(c1ex + (size_t)arow * 512 + kl, cf);
        f32x4 a = z4;
#pragma unroll
        for (int c = 0; c < 16; ++c)
          a = MFMA16(*(const bf16x8*)&cf[c], *ldsB(wWe2, cl, 512, c * 32 + kl), a);
#pragma unroll
        for (int j = 0; j < 4; ++j)
          stg[mt * 16 + rb + j][cl] = f2b(fmaxf(a[j] + be2, 0.f));
        if (lane < 32) {
          int row = mt * 16 + (lane >> 1), half = lane & 1;
          u32x4 v = *(const u32x4*)&stg[row][half * 8];
          st16B_c(eex + (size_t)row * 512 + sl * 16 + half * 8, v);
        }
        drain_vm();
        if (lane == 0) {
          u32 o = __hip_atomic_fetch_add(&wgc[1], 1u, __ATOMIC_RELAXED, __HIP_MEMORY_SCOPE_WORKGROUP);
          if (o == 4u * (u32)t + 3u) postc(cE);
        }
      }
      // ---- S3: mu/std slice ----
      wpoll(cE, lane, 32u * (u32)(t + 1));
      {
        u32x4 ef[16];
        ld16_c(eex + (size_t)arow * 512 + kl, ef);
        f32x4 a = z4;
#pragma unroll
        for (int c = 0; c < 16; ++c)
          a = MFMA16(*(const bf16x8*)&ef[c], *ldsB(wWms, cl, 512, c * 32 + kl), a);
        if (cl < 8) {
#pragma unroll
          for (int j = 0; j < 4; ++j) musp[mt * 16 + rb + j][cl] = a[j] + bms;
        }
        if (lane == 0)
          __hip_atomic_fetch_add(&wgc[2], 1u, __ATOMIC_RELEASE, __HIP_MEMORY_SCOPE_WORKGROUP);
      }
    }

    // ---- S3b: z by wave 0 (after its own S3) ----
    if (wave == 0) {
      if (lane == 0) {
        while (__hip_atomic_load(&wgc[2], __ATOMIC_ACQUIRE, __HIP_MEMORY_SCOPE_WORKGROUP) < 4u * (u32)(t + 1)) {}
      }
      __builtin_amdgcn_sched_barrier(0);
      int r = lane;
      float m0 = musp[r][0], m1 = musp[r][1], m2 = musp[r][2], m3 = musp[r][3];
      float s0 = musp[r][4], s1 = musp[r][5], s2 = musp[r][6], s3 = musp[r][7];
      float p0 = fmaxf(s0, 0.f) + log1pf(__expf(-fabsf(s0)));
      float p1 = fmaxf(s1, 0.f) + log1pf(__expf(-fabsf(s1)));
      float p2 = fmaxf(s2, 0.f) + log1pf(__expf(-fabsf(s2)));
      float p3 = fmaxf(s3, 0.f) + log1pf(__expf(-fabsf(s3)));
      float z0 = ev4.x * p0 + m0, z1 = ev4.y * p1 + m1;
      float z2 = ev4.z * p2 + m2, z3 = ev4.w * p3 + m3;
      u64 pk = (u64)f2b2(z0, z1) | ((u64)f2b2(z2, z3) << 32);
      st8B_c(xzb + ((size_t)(slot * NB + r)) * ZDI + sl * 4, pk);
      *(u64*)(zall + ((size_t)t * NB + r) * ZDI + sl * 4) = pk;
      drain_vm();
      if (lane == 0) postc(cZ);
    }

    // ---- S4: z -> gi_z tiles (all 8 waves) ----
    wpoll(cZ, lane, 32u * (u32)(t + 1));
    {
      u32x4 zf[4];
      ld4_c(xzb + ((size_t)(slot * NB + arow)) * ZDI + kl, zf);
      if (wave < 4) {
        f32x4 a = unpk4(gx0);
#pragma unroll
        for (int c = 0; c < 4; ++c)
          a = MFMA16(*(const bf16x8*)&zf[c], *ldsB(wWihz, cl, 128, c * 32 + kl), a);
#pragma unroll
        for (int j = 0; j < 4; ++j) red[0][mt * 16 + rb + j][cl] = a[j];
      } else {
        f32x4 a0 = unpk4(gx0), a1 = unpk4(gx1);
#pragma unroll
        for (int c = 0; c < 4; ++c) {
          bf16x8 af = *(const bf16x8*)&zf[c];
          a0 = MFMA16(af, *ldsB(wWihz, 16 + cl, 128, c * 32 + kl), a0);
          a1 = MFMA16(af, *ldsB(wWihz, 32 + cl, 128, c * 32 + kl), a1);
        }
#pragma unroll
        for (int j = 0; j < 4; ++j) {
          red[1][mt * 16 + rb + j][cl] = a0[j];
          red[2][mt * 16 + rb + j][cl] = a1[j];
        }
      }
    }
    __syncthreads();   // red + ghb + musp consumed

    // ---- gates + h' (all 512 threads -> hold LDS) ----
    {
      int r = tid >> 3, c0 = (tid & 7) << 1;
      float rg0 = sigm(red[0][r][c0] + ghb[0][r][c0]);
      float rg1 = sigm(red[0][r][c0 + 1] + ghb[0][r][c0 + 1]);
      float zg0 = sigm(red[1][r][c0] + ghb[1][r][c0]);
      float zg1 = sigm(red[1][r][c0 + 1] + ghb[1][r][c0 + 1]);
      float ng0 = tanhf(red[2][r][c0] + rg0 * ghb[2][r][c0]);
      float ng1 = tanhf(red[2][r][c0 + 1] + rg1 * ghb[2][r][c0 + 1]);
      hold[r][c0]     = (1.f - zg0) * ng0 + zg0 * hold[r][c0];
      hold[r][c0 + 1] = (1.f - zg1) * ng1 + zg1 * hold[r][c0 + 1];
    }
    __syncthreads();   // hold ready

    // ---- h' export: wave0 -> hexb (critical), wave1 -> hall/hg (off-path) ----
    if (t < TT - 1) {
      if (wave == 0) {
        int r = lane;
        const float* hp = &hold[r][0];
        u32x4 w0, w1;
        w0[0] = f2b2(hp[0], hp[1]);  w0[1] = f2b2(hp[2], hp[3]);
        w0[2] = f2b2(hp[4], hp[5]);  w0[3] = f2b2(hp[6], hp[7]);
        w1[0] = f2b2(hp[8], hp[9]);  w1[1] = f2b2(hp[10], hp[11]);
        w1[2] = f2b2(hp[12], hp[13]); w1[3] = f2b2(hp[14], hp[15]);
        u16* dst = hexb + ((size_t)(((t + 1) & 1) * NB + r)) * HDI + sl * 16;
        st16B_c(dst, w0);
        st16B_c(dst + 8, w1);
        drain_vm();
        if (lane == 0) postc(cH);
      } else if (wave == 1) {
        int r = lane;
        const float* hp = &hold[r][0];
        uint4 w0, w1;
        w0.x = f2b2(hp[0], hp[1]);  w0.y = f2b2(hp[2], hp[3]);
        w0.z = f2b2(hp[4], hp[5]);  w0.w = f2b2(hp[6], hp[7]);
        w1.x = f2b2(hp[8], hp[9]);  w1.y = f2b2(hp[10], hp[11]);
        w1.z = f2b2(hp[12], hp[13]); w1.w = f2b2(hp[14], hp[15]);
        u16* dst = hall + ((size_t)(t + 1) * NB + r) * HDI + sl * 16;
        *(uint4*)dst = w0;
        *(uint4*)(dst + 8) = w1;
      }
    } else {
      if (wave == 1) {
        int r = lane;
        float* dst = hg + (size_t)r * 512 + sl * 16;
#pragma unroll
        for (int k = 0; k < 16; k += 4)
          *(float4*)(dst + k) = *(const float4*)&hold[r][k];
      }
    }
  }
}

// ---------------- phase C: decoder chain + generation loss ----------------
__global__ __launch_bounds__(256, 1) void phaseC(
    char* ws, const float* db1, const float* db2, const float* dmbias,
    const float* genb, const int* ts, float* gpart) {
  __shared__ u16 lA[64 * 640];
  __shared__ u16 lB[64 * 512];
  int rb = blockIdx.x;
  int tid = threadIdx.x, wave = tid >> 6, lane = tid & 63;
  const u16* zall = (const u16*)(ws + OFF_ZALL);
  const u16* hall = (const u16*)(ws + OFF_HALL);
  const u16* wd1 = (const u16*)(ws + OFF_WD1);
  const u16* wd2 = (const u16*)(ws + OFF_WD2);
  const u16* wdm = (const u16*)(ws + OFF_WDM);
  const u16* wgw = (const u16*)(ws + OFF_WGW);

  fill_lds(lA, 640, zall + (size_t)rb * NB * ZDI, 128, hall + (size_t)rb * NB * HDI, 512);
  __syncthreads();
  for (int tile = wave; tile < 32; tile += 4) {
    f32x4 acc[4];
    acc[0] = acc[1] = acc[2] = acc[3] = (f32x4){0.f, 0.f, 0.f, 0.f};
    mm_tile(acc, lA, 640, 0, wd1, 640, tile * 16, 640, lane);
    int col = tile * 16 + (lane & 15);
    float bias = db1[col];
#pragma unroll
    for (int m = 0; m < 4; ++m)
#pragma unroll
      for (int j = 0; j < 4; ++j) {
        int row = (m << 4) + ((lane >> 4) << 2) + j;
        int byte = ((row * 512 + col) << 1) ^ ((row & 7) << 4);
        *(u16*)((char*)lB + byte) = f2b(fmaxf(acc[m][j] + bias, 0.f));
      }
  }
  __syncthreads();
  for (int tile = wave; tile < 32; tile += 4) {
    f32x4 acc[4];
    acc[0] = acc[1] = acc[2] = acc[3] = (f32x4){0.f, 0.f, 0.f, 0.f};
    mm_tile(acc, lB, 512, 0, wd2, 512, tile * 16, 512, lane);
    int col = tile * 16 + (lane & 15);
    float bias = db2[col];
#pragma unroll
    for (int m = 0; m < 4; ++m)
#pragma unroll
      for (int j = 0; j < 4; ++j) {
        int row = (m << 4) + ((lane >> 4) << 2) + j;
        int byte = ((row * 512 + col) << 1) ^ ((row & 7) << 4);
        *(u16*)((char*)lA + byte) = f2b(fmaxf(acc[m][j] + bias, 0.f));
      }
  }
  __syncthreads();
  for (int tile = wave; tile < 16; tile += 4) {
    f32x4 acc[4];
    acc[0] = acc[1] = acc[2] = acc[3] = (f32x4){0.f, 0.f, 0.f, 0.f};
    mm_tile(acc, lA, 512, 0, wdm, 512, tile * 16, 512, lane);
    int col = tile * 16 + (lane & 15);
    float bias = dmbias[col];
#pragma unroll
    for (int m = 0; m < 4; ++m)
#pragma unroll
      for (int j = 0; j < 4; ++j) {
        int row = (m << 4) + ((lane >> 4) << 2) + j;
        float v = 1.f / (1.f + __expf(-(acc[m][j] + bias)));
        int byte = ((row * 256 + col) << 1) ^ ((row & 7) << 4);
        *(u16*)((char*)lB + byte) = f2b(v);
      }
  }
  __syncthreads();
  float mr[16], sr[16], cap[16];
  int tg[16];
#pragma unroll
  for (int q = 0; q < 16; ++q) {
    int r = ((q >> 2) << 4) + ((lane >> 4) << 2) + (q & 3);
    tg[q] = ts[r * TT + rb];
    mr[q] = -1e30f; sr[q] = 0.f; cap[q] = -1e30f;
  }
  for (int ct = wave; ct < 625; ct += 4) {
    f32x4 acc[4];
    acc[0] = acc[1] = acc[2] = acc[3] = (f32x4){0.f, 0.f, 0.f, 0.f};
    mm_tile(acc, lB, 256, 0, wgw, 256, ct * 16, 256, lane);
    int colw = ct * 16 + (lane & 15);
    float gbv = genb[colw];
#pragma unroll
    for (int mi = 0; mi < 4; ++mi)
#pragma unroll
      for (int j = 0; j < 4; ++j) {
        int q = (mi << 2) + j;
        float v = acc[mi][j] + gbv;
        if (colw == tg[q]) cap[q] = v;
        float mn = fmaxf(mr[q], v);
        sr[q] = sr[q] * __expf(mr[q] - mn) + __expf(v - mn);
        mr[q] = mn;
      }
  }
#pragma unroll
  for (int d = 1; d < 16; d <<= 1) {
#pragma unroll
    for (int q = 0; q < 16; ++q) {
      float mo = __shfl_xor(mr[q], d);
      float so = __shfl_xor(sr[q], d);
      float co = __shfl_xor(cap[q], d);
      float mn = fmaxf(mr[q], mo);
      sr[q] = sr[q] * __expf(mr[q] - mn) + so * __expf(mo - mn);
      mr[q] = mn;
      cap[q] = fmaxf(cap[q], co);
    }
  }
  float* sc = (float*)lA;
  if ((lane & 15) == 0) {
    int g = lane >> 4;
#pragma unroll
    for (int q = 0; q < 16; ++q) {
      int r = ((q >> 2) << 4) + (g << 2) + (q & 3);
      sc[wave * 64 + r] = mr[q];
      sc[256 + wave * 64 + r] = sr[q];
      sc[512 + wave * 64 + r] = cap[q];
    }
  }
  __syncthreads();
  if (tid < 64) {
    float M = -1e30f, S = 0.f, C = -1e30f;
#pragma unroll
    for (int w = 0; w < 4; ++w) {
      float m = sc[w * 64 + tid], s = sc[256 + w * 64 + tid], c = sc[512 + w * 64 + tid];
      float mn = fmaxf(M, m);
      S = S * __expf(M - mn) + s * __expf(m - mn);
      M = mn;
      C = fmaxf(C, c);
    }
    float lossr = M + __logf(S) - C;
    for (int d = 1; d < 64; d <<= 1) lossr += __shfl_xor(lossr, d);
    if (tid == 0) gpart[rb] = lossr;
  }
}

// ---------------- final reduce + classifier ----------------
__global__ __launch_bounds__(256) void finalk(char* ws, const int* labels,
                                              const float* cw, const float* cb,
                                              const float* gpart, float* out) {
  __shared__ float sred[256];
  __shared__ float cred[64];
  int tid = threadIdx.x;
  sred[tid] = gpart[tid];
  __syncthreads();
  for (int s2 = 128; s2 > 0; s2 >>= 1) {
    if (tid < s2) sred[tid] += sred[tid + s2];
    __syncthreads();
  }
  const float* h = (const float*)(ws + OFF_H);
  if (tid < 64) {
    const float* hrow = h + tid * 512;
    float a0 = cb[0], a1 = cb[1], a2 = cb[2], a3 = cb[3];
    for (int k = 0; k < 512; k += 4) {
      float4 hv = *(const float4*)(hrow + k);
      float4 w0 = *(const float4*)(cw + 0 * 512 + k);
      float4 w1 = *(const float4*)(cw + 1 * 512 + k);
      float4 w2 = *(const float4*)(cw + 2 * 512 + k);
      float4 w3 = *(const float4*)(cw + 3 * 512 + k);
      a0 += hv.x * w0.x + hv.y * w0.y + hv.z * w0.z + hv.w * w0.w;
      a1 += hv.x * w1.x + hv.y * w1.y + hv.z * w1.z + hv.w * w1.w;
      a2 += hv.x * w2.x + hv.y * w2.y + hv.z * w2.z + hv.w * w2.w;
      a3 += hv.x * w3.x + hv.y * w3.y + hv.z * w3.z + hv.w * w3.w;
    }
    float M = fmaxf(fmaxf(a0, a1), fmaxf(a2, a3));
    float S = __expf(a0 - M) + __expf(a1 - M) + __expf(a2 - M) + __expf(a3 - M);
    int lb = labels[tid];
    float lg = (lb == 0) ? a0 : (lb == 1) ? a1 : (lb == 2) ? a2 : a3;
    cred[tid] = M + __logf(S) - lg;
  }
  __syncthreads();
  if (tid == 0) {
    float cs = 0.f;
    for (int i = 0; i < 64; ++i) cs += cred[i];
    out[0] = sred[0] / 16384.f;
    out[1] = cs / 64.f;
  }
}

extern "C" void kernel_launch(void* const* d_in, const int* in_sizes, int n_in,
                              void* d_out, int out_size, void* d_ws, size_t ws_size,
                              hipStream_t stream) {
  (void)in_sizes; (void)n_in; (void)out_size; (void)ws_size;
  char* ws = (char*)d_ws;
  const int* xs = (const int*)d_in[0];
  const int* ts = (const int*)d_in[1];
  const int* labels = (const int*)d_in[2];
  const int* wflag = (const int*)d_in[3];
  const float* eps = (const float*)d_in[4];
  const float* hnoise = (const float*)d_in[5];
  const float* embed = (const float*)d_in[6];
  const float* e_w1 = (const float*)d_in[7];
  const float* e_b1 = (const float*)d_in[8];
  const float* e_w2 = (const float*)d_in[9];
  const float* e_b2 = (const float*)d_in[10];
  const float* m_w = (const float*)d_in[11];
  const float* m_b = (const float*)d_in[12];
  const float* s_w = (const float*)d_in[13];
  const float* s_b = (const float*)d_in[14];
  const float* d_w1 = (const float*)d_in[15];
  const float* d_b1 = (const float*)d_in[16];
  const float* d_w2 = (const float*)d_in[17];
  const float* d_b2 = (const float*)d_in[18];
  const float* dm_w = (const float*)d_in[19];
  const float* dm_b = (const float*)d_in[20];
  const float* g_ih = (const float*)d_in[21];
  const float* g_hh = (const float*)d_in[22];
  const float* g_bih = (const float*)d_in[23];
  const float* g_bhh = (const float*)d_in[24];
  const float* gw = (const float*)d_in[25];
  const float* gb = (const float*)d_in[26];
  const float* cw = (const float*)d_in[27];
  const float* cb = (const float*)d_in[28];
  const float* hw = (const float*)d_in[29];
  const float* hb0 = (const float*)d_in[30];

  hipMemsetAsync(ws + OFF_FLAG, 0, 1024, stream);

  ConvArgs ca;
  const float* srcs[10] = {e_w1, e_w2, m_w, s_w, d_w1, d_w2, dm_w, g_ih, g_hh, gw};
  unsigned long long doffs[10] = {OFF_WE1, OFF_WE2, OFF_WMW, OFF_WSW, OFF_WD1,
                                  OFF_WD2, OFF_WDM, OFF_WIH, OFF_WHH, OFF_WGW};
  int ns[10] = {393216, 262144, 65536, 65536, 327680, 262144, 131072, 589824, 786432, 2560000};
  for (int i = 0; i < 10; ++i) { ca.s[i] = srcs[i]; ca.doff[i] = doffs[i]; ca.n[i] = ns[i]; }

  wconv<<<dim3(1250, 10), 256, 0, stream>>>(ws, ca);
  gatherx<<<2048, 256, 0, stream>>>(ws, xs, embed);
  h0init<<<128, 256, 0, stream>>>(ws, labels, wflag, hnoise, hw, hb0);
  gixk<<<256, 256, 0, stream>>>(ws, g_bih);
  phaseB<<<32, 512, 0, stream>>>(ws, eps, e_b1, e_b2, m_b, s_b, g_bhh);
  phaseC<<<256, 256, 0, stream>>>(ws, d_b1, d_b2, dm_b, gb, ts, (float*)(ws + OFF_GPART));
  finalk<<<1, 256, 0, stream>>>(ws, labels, cw, cb, (const float*)(ws + OFF_GPART), (float*)d_out);
}

// Round 11
// 5346.299 us; speedup vs baseline: 1.7469x; 1.3242x over previous
//
#include <hip/hip_runtime.h>

typedef unsigned short u16;
typedef unsigned int u32;
typedef unsigned long long u64;
using bf16x8 = __attribute__((ext_vector_type(8))) short;
using f32x4  = __attribute__((ext_vector_type(4))) float;
using u32x4  = __attribute__((ext_vector_type(4))) unsigned int;

#define TT   256
#define NB   64
#define XDI  256
#define HDI  512
#define ZDI  128
#define VV   10000

// ---- workspace byte offsets ----
#define OFF_WE1   512ull        // [512][768] bf16
#define OFF_WE2   786944ull     // [512][512] bf16
#define OFF_WMW   1311232ull    // [128][512] bf16
#define OFF_WSW   1442304ull    // [128][512] bf16
#define OFF_WD1   1573376ull    // [512][640] bf16
#define OFF_WD2   2228736ull    // [512][512] bf16
#define OFF_WDM   2753024ull    // [256][512] bf16
#define OFF_WIH   3015168ull    // [1536][384] bf16
#define OFF_WHH   4194816ull    // [1536][512] bf16
#define OFF_WGW   5767680ull    // [10000][256] bf16
#define OFF_XEMB  10887680ull   // [256][64][256] bf16
#define OFF_H     19276288ull   // [64][512] f32
#define OFF_ZALL  19997184ull   // [256*64][128] bf16 (also the z exchange, per-t buffer)
#define OFF_HALL  24191488ull   // [256*64][512] bf16 (h entering step t; also the h exchange)
#define OFF_GPART 40968704ull   // [256] f32
#define OFF_EXC   40969728ull   // [64][512] bf16 c1 exchange
#define OFF_EXE   41035264ull   // [64][512] bf16 e exchange
#define OFF_FLAG  41100800ull   // 4 stage counters, 256B apart
#define OFF_GIX   41102848ull   // [256][1536][64] bf16 (x-part of gi + bih)

__device__ __forceinline__ u16 f2b(float f) {
  union { float f; u32 u; } v; v.f = f;
  u32 r = v.u + 0x7fffu + ((v.u >> 16) & 1u);
  return (u16)(r >> 16);
}
__device__ __forceinline__ u32 f2b2(float a, float b) {
  return (u32)f2b(a) | ((u32)f2b(b) << 16);
}
__device__ __forceinline__ float b2f(u16 x) {
  union { u32 u; float f; } v; v.u = ((u32)x) << 16; return v.f;
}

#define MFMA16(a, b, c) __builtin_amdgcn_mfma_f32_16x16x32_bf16(a, b, c, 0, 0, 0)

__device__ __forceinline__ const bf16x8* ldsB(const u16* base, int r, int K, int k) {
  return (const bf16x8*)((const char*)base + (((r * K + k) << 1) ^ ((r & 7) << 4)));
}
__device__ __forceinline__ void ldsW(u16* base, int r, int K, int k, uint4 v) {
  *(uint4*)((char*)base + (((r * K + k) << 1) ^ ((r & 7) << 4))) = v;
}

__device__ __forceinline__ void fill_lds(u16* lds, int Ktot,
                                         const u16* s0, int K0,
                                         const u16* s1, int K1) {
  int kch = Ktot >> 3;
  int nch = 64 * kch;
  for (int i = threadIdx.x; i < nch; i += 256) {
    int row = i / kch;
    int k = (i - row * kch) << 3;
    const u16* src = (k < K0) ? (s0 + row * K0 + k) : (s1 + row * K1 + (k - K0));
    uint4 v = *(const uint4*)src;
    ldsW(lds, row, Ktot, k, v);
  }
}

__device__ __forceinline__ void mm_tile(f32x4 acc[4], const u16* lds, int ldsStride, int ldsK0,
                                        const u16* __restrict__ W, int Kw, int wcol0,
                                        int Klen, int lane) {
  const int kl = (lane >> 4) << 3;
  const int cl = lane & 15;
  const u16* wp = W + (size_t)(wcol0 + cl) * Kw;
  for (int kc = 0; kc < Klen; kc += 32) {
    int k = kc + kl;
    bf16x8 b = *(const bf16x8*)(wp + k);
#pragma unroll
    for (int m = 0; m < 4; ++m)
      acc[m] = MFMA16(*ldsB(lds, (m << 4) + cl, ldsStride, ldsK0 + k), b, acc[m]);
  }
}

// ---- MALL-coherent consumer loads (R4/R7-proven) ----
__device__ __forceinline__ void ld16_c(const void* p, u32x4* f) {
  asm volatile(
      "global_load_dwordx4 %0, %16, off sc0 sc1\n\t"
      "global_load_dwordx4 %1, %16, off offset:64 sc0 sc1\n\t"
      "global_load_dwordx4 %2, %16, off offset:128 sc0 sc1\n\t"
      "global_load_dwordx4 %3, %16, off offset:192 sc0 sc1\n\t"
      "global_load_dwordx4 %4, %16, off offset:256 sc0 sc1\n\t"
      "global_load_dwordx4 %5, %16, off offset:320 sc0 sc1\n\t"
      "global_load_dwordx4 %6, %16, off offset:384 sc0 sc1\n\t"
      "global_load_dwordx4 %7, %16, off offset:448 sc0 sc1\n\t"
      "global_load_dwordx4 %8, %16, off offset:512 sc0 sc1\n\t"
      "global_load_dwordx4 %9, %16, off offset:576 sc0 sc1\n\t"
      "global_load_dwordx4 %10, %16, off offset:640 sc0 sc1\n\t"
      "global_load_dwordx4 %11, %16, off offset:704 sc0 sc1\n\t"
      "global_load_dwordx4 %12, %16, off offset:768 sc0 sc1\n\t"
      "global_load_dwordx4 %13, %16, off offset:832 sc0 sc1\n\t"
      "global_load_dwordx4 %14, %16, off offset:896 sc0 sc1\n\t"
      "global_load_dwordx4 %15, %16, off offset:960 sc0 sc1\n\t"
      "s_waitcnt vmcnt(0)"
      : "=&v"(f[0]), "=&v"(f[1]), "=&v"(f[2]), "=&v"(f[3]),
        "=&v"(f[4]), "=&v"(f[5]), "=&v"(f[6]), "=&v"(f[7]),
        "=&v"(f[8]), "=&v"(f[9]), "=&v"(f[10]), "=&v"(f[11]),
        "=&v"(f[12]), "=&v"(f[13]), "=&v"(f[14]), "=&v"(f[15])
      : "v"(p) : "memory");
}
__device__ __forceinline__ void ld4_c(const void* p, u32x4* f) {
  asm volatile(
      "global_load_dwordx4 %0, %4, off sc0 sc1\n\t"
      "global_load_dwordx4 %1, %4, off offset:64 sc0 sc1\n\t"
      "global_load_dwordx4 %2, %4, off offset:128 sc0 sc1\n\t"
      "global_load_dwordx4 %3, %4, off offset:192 sc0 sc1\n\t"
      "s_waitcnt vmcnt(0)"
      : "=&v"(f[0]), "=&v"(f[1]), "=&v"(f[2]), "=&v"(f[3])
      : "v"(p) : "memory");
}
__device__ __forceinline__ void st16B_c(void* p, u32x4 v) {
  asm volatile("global_store_dwordx4 %0, %1, off sc0 sc1" :: "v"(p), "v"(v) : "memory");
}
__device__ __forceinline__ void st8B_c(void* p, u64 v) {
  asm volatile("global_store_dwordx2 %0, %1, off sc0 sc1" :: "v"(p), "v"(v) : "memory");
}
__device__ __forceinline__ void drain_vm() {
  asm volatile("s_waitcnt vmcnt(0)" ::: "memory");
}
// contention-free sync: one atomicAdd per WG per stage; one poller lane per WG (R7-proven).
__device__ __forceinline__ void postc(u32* cnt, int tid) {
  if (tid == 0)
    __hip_atomic_fetch_add(cnt, 1u, __ATOMIC_RELAXED, __HIP_MEMORY_SCOPE_AGENT);
}
__device__ __forceinline__ void pollc(u32* cnt, int tid, u32 target) {
  if (tid == 0) {
    while (__hip_atomic_load(cnt, __ATOMIC_RELAXED, __HIP_MEMORY_SCOPE_AGENT) < target)
      __builtin_amdgcn_s_sleep(1);
  }
  __syncthreads();
}
__device__ __forceinline__ f32x4 unpk4(u64 g) {
  f32x4 a;
#pragma unroll
  for (int j = 0; j < 4; ++j) a[j] = b2f((u16)(g >> (16 * j)));
  return a;
}
__device__ __forceinline__ float sigm(float x) { return 1.f / (1.f + __expf(-x)); }

// ---------------- prep kernels ----------------
struct ConvArgs { const float* s[10]; unsigned long long doff[10]; int n[10]; };

__global__ __launch_bounds__(256) void wconv(char* ws, ConvArgs a) {
  int seg = blockIdx.y;
  const float* s = a.s[seg];
  u16* d = (u16*)(ws + a.doff[seg]);
  int n = a.n[seg];
  int i = (blockIdx.x * 256 + threadIdx.x) * 8;
  if (i < n) {
    float4 v0 = *(const float4*)(s + i);
    float4 v1 = *(const float4*)(s + i + 4);
    uint4 o;
    o.x = f2b2(v0.x, v0.y); o.y = f2b2(v0.z, v0.w);
    o.z = f2b2(v1.x, v1.y); o.w = f2b2(v1.z, v1.w);
    *(uint4*)(d + i) = o;
  }
}

__global__ __launch_bounds__(256) void gatherx(char* ws, const int* xs, const float* embed) {
  u16* xemb = (u16*)(ws + OFF_XEMB);
  int i = blockIdx.x * 256 + threadIdx.x;
  int t = i >> 11;
  int rr = i & 2047;
  int n = rr >> 5;
  int k = (rr & 31) << 3;
  int idx = xs[n * TT + t];
  const float* src = embed + (size_t)idx * XDI + k;
  float4 v0 = *(const float4*)src;
  float4 v1 = *(const float4*)(src + 4);
  uint4 o;
  o.x = f2b2(v0.x, v0.y); o.y = f2b2(v0.z, v0.w);
  o.z = f2b2(v1.x, v1.y); o.w = f2b2(v1.z, v1.w);
  *(uint4*)(xemb + ((size_t)t * NB + n) * XDI + k) = o;
}

__global__ __launch_bounds__(256) void h0init(char* ws, const int* labels, const int* wflag,
                                              const float* hnoise, const float* hw, const float* hb0) {
  int i = blockIdx.x * 256 + threadIdx.x;  // 32768
  int n = i >> 9, c = i & 511;
  float v = (float)labels[n] * hw[c] + hb0[c];
  if (wflag[0]) v += hnoise[i];
  ((float*)(ws + OFF_H))[i] = v;
  ((u16*)(ws + OFF_HALL))[i] = f2b(v);   // hall[0] = h0 (bf16)
}

// gi_x[t][c][n] = bih[c] + sum_k x_emb[t][n][k] * Wih[c][k], k<256
__global__ __launch_bounds__(256) void gixk(char* ws, const float* bih) {
  __shared__ u16 lA[64 * 256];
  int t = blockIdx.x;
  int tid = threadIdx.x, wave = tid >> 6, lane = tid & 63;
  const int cl = lane & 15, rb = (lane >> 4) << 2;
  const u16* xemb = (const u16*)(ws + OFF_XEMB);
  const u16* wih = (const u16*)(ws + OFF_WIH);
  u16* gix = (u16*)(ws + OFF_GIX);
  fill_lds(lA, 256, xemb + (size_t)t * NB * XDI, 256, xemb, 256);
  __syncthreads();
  for (int ct = wave; ct < 96; ct += 4) {
    f32x4 acc[4];
    acc[0] = acc[1] = acc[2] = acc[3] = (f32x4){0.f, 0.f, 0.f, 0.f};
    mm_tile(acc, lA, 256, 0, wih, 384, ct * 16, 256, lane);
    int col = ct * 16 + cl;
    float bv = bih[col];
    u16* dst = gix + ((size_t)t * 1536 + col) * 64;
#pragma unroll
    for (int m = 0; m < 4; ++m) {
      u64 o = (u64)f2b(acc[m][0] + bv) | ((u64)f2b(acc[m][1] + bv) << 16)
            | ((u64)f2b(acc[m][2] + bv) << 32) | ((u64)f2b(acc[m][3] + bv) << 48);
      *(u64*)(dst + (m << 4) + rb) = o;
    }
  }
}

// ---------------- phase B: weight-stationary recurrence, counter handoffs ----------------
// 32 WGs x 512 threads. R7 protocol (aggregated counters, tid0 poll + barrier) with
// coalesced producer stores staged through LDS (single isolated change vs R7).
__global__ __launch_bounds__(512, 1) void phaseB(
    char* ws, const float* __restrict__ eps,
    const float* __restrict__ b_e1, const float* __restrict__ b_e2,
    const float* __restrict__ b_mw, const float* __restrict__ b_sw,
    const float* __restrict__ bhh) {
  __shared__ u16 wsl[59392];                // 116KB weight slices (swizzled)
  __shared__ float ghb[3][64][16];          // gh tiles
  __shared__ float red[3][64][16];          // gi_z tiles
  __shared__ float musp[64][8];             // mu / pre-softplus std
  __shared__ float hold[64][17];            // own h slice (f32, padded)
  __shared__ __align__(16) u16 stg[64][16]; // store-coalescing stage

  u16* wWe1 = wsl;            // [16][768]
  u16* wWhh = wsl + 12288;    // [48][512]
  u16* wWe2 = wsl + 36864;    // [16][512]
  u16* wWms = wsl + 45056;    // [16][512] rows 0-3 mu, 4-7 std
  u16* wWihz = wsl + 53248;   // [48][128]

  const u16* we1 = (const u16*)(ws + OFF_WE1);
  const u16* we2 = (const u16*)(ws + OFF_WE2);
  const u16* wmw = (const u16*)(ws + OFF_WMW);
  const u16* wsw = (const u16*)(ws + OFF_WSW);
  const u16* wih = (const u16*)(ws + OFF_WIH);
  const u16* whh = (const u16*)(ws + OFF_WHH);
  const u16* xemb = (const u16*)(ws + OFF_XEMB);
  const u16* gix = (const u16*)(ws + OFF_GIX);
  float* hg = (float*)(ws + OFF_H);
  u16* zall = (u16*)(ws + OFF_ZALL);
  u16* hall = (u16*)(ws + OFF_HALL);
  u16* c1ex = (u16*)(ws + OFF_EXC);
  u16* eex  = (u16*)(ws + OFF_EXE);
  u32* cC1 = (u32*)(ws + OFF_FLAG);
  u32* cE  = (u32*)(ws + OFF_FLAG + 256);
  u32* cZ  = (u32*)(ws + OFF_FLAG + 512);
  u32* cH  = (u32*)(ws + OFF_FLAG + 768);

  const int tid = threadIdx.x, wave = tid >> 6, lane = tid & 63;
  const int cl = lane & 15, kl = (lane >> 4) << 3, rb = (lane >> 4) << 2;
  const int sl = blockIdx.x;
  const int mt = wave & 3;
  const int arow = mt * 16 + cl;

  // ---- preload weight slices into LDS ----
  for (int c = tid; c < 1536; c += 512) {
    int r = c / 96, k = (c % 96) << 3;
    ldsW(wWe1, r, 768, k, *(const uint4*)(we1 + (size_t)(sl * 16 + r) * 768 + k));
  }
  for (int c = tid; c < 3072; c += 512) {
    int r = c >> 6, k = (c & 63) << 3;
    int gr = (r >> 4) * 512 + sl * 16 + (r & 15);
    ldsW(wWhh, r, 512, k, *(const uint4*)(whh + (size_t)gr * 512 + k));
  }
  for (int c = tid; c < 1024; c += 512) {
    int r = c >> 6, k = (c & 63) << 3;
    ldsW(wWe2, r, 512, k, *(const uint4*)(we2 + (size_t)(sl * 16 + r) * 512 + k));
  }
  for (int c = tid; c < 1024; c += 512) {
    int r = c >> 6, k = (c & 63) << 3;
    uint4 v = {0, 0, 0, 0};
    if (r < 4)      v = *(const uint4*)(wmw + (size_t)(sl * 4 + r) * 512 + k);
    else if (r < 8) v = *(const uint4*)(wsw + (size_t)(sl * 4 + r - 4) * 512 + k);
    ldsW(wWms, r, 512, k, v);
  }
  for (int c = tid; c < 768; c += 512) {
    int r = c >> 4, k = (c & 15) << 3;
    int gr = (r >> 4) * 512 + sl * 16 + (r & 15);
    ldsW(wWihz, r, 128, k, *(const uint4*)(wih + (size_t)gr * 384 + 256 + k));
  }
  for (int i = tid << 1; i < 1024; i += 1024) {
    int r = i >> 4, c = i & 15;
    float2 hv = *(const float2*)(hg + (size_t)r * 512 + sl * 16 + c);
    hold[r][c] = hv.x;
    hold[r][c + 1] = hv.y;
  }
  // biases
  const float be1 = b_e1[sl * 16 + cl];
  const float be2 = b_e2[sl * 16 + cl];
  const float bms = (cl < 4) ? b_mw[sl * 4 + cl] : ((cl < 8) ? b_sw[sl * 4 + cl - 4] : 0.f);
  const float bh0 = bhh[sl * 16 + cl];
  const float bh1 = bhh[512 + sl * 16 + cl];
  const float bh2 = bhh[1024 + sl * 16 + cl];
  __syncthreads();

  const f32x4 z4 = {0.f, 0.f, 0.f, 0.f};
  for (int t = 0; t < TT; ++t) {
    // ---- S0: prefetch h-independent operands (plain cached) ----
    u32x4 xf[8];
    u64 gx0 = 0, gx1 = 0;
    float4 ev4 = {0.f, 0.f, 0.f, 0.f};
    if (wave < 4) {
      const u16* xr = xemb + ((size_t)t * NB + arow) * XDI + kl;
#pragma unroll
      for (int i = 0; i < 8; ++i) xf[i] = *(const u32x4*)(xr + i * 32);
      gx0 = *(const u64*)(gix + ((size_t)t * 1536 + sl * 16 + cl) * 64 + mt * 16 + rb);
    } else {
      gx0 = *(const u64*)(gix + ((size_t)t * 1536 + 512 + sl * 16 + cl) * 64 + mt * 16 + rb);
      gx1 = *(const u64*)(gix + ((size_t)t * 1536 + 1024 + sl * 16 + cl) * 64 + mt * 16 + rb);
    }
    if (wave == 0)
      ev4 = *(const float4*)(eps + (size_t)lane * (TT * ZDI) + (size_t)t * ZDI + sl * 4);

    // x-part of c1 BEFORE the h poll (off critical path)
    f32x4 ax = z4;
    if (wave < 4) {
#pragma unroll
      for (int i = 0; i < 8; ++i)
        ax = MFMA16(*(const bf16x8*)&xf[i], *ldsB(wWe1, cl, 768, i * 32 + kl), ax);
    }

    // ---- S1: wait h(t); c1 slice (w0-3) / gh tiles (w4-7) ----
    pollc(cH, tid, 32u * (u32)t);
    u32x4 hf[16];
    ld16_c(hall + ((size_t)t * NB + arow) * HDI + kl, hf);
    if (wave < 4) {
      f32x4 a = ax;
#pragma unroll
      for (int c = 0; c < 16; ++c)
        a = MFMA16(*(const bf16x8*)&hf[c], *ldsB(wWe1, cl, 768, 256 + c * 32 + kl), a);
#pragma unroll
      for (int j = 0; j < 4; ++j)
        stg[mt * 16 + rb + j][cl] = f2b(fmaxf(a[j] + be1, 0.f));
      if (lane < 32) {
        int row = mt * 16 + (lane >> 1), half = lane & 1;
        u32x4 v = *(const u32x4*)&stg[row][half * 8];
        st16B_c(c1ex + (size_t)row * 512 + sl * 16 + half * 8, v);
      }
    }
    drain_vm();
    __syncthreads();
    postc(cC1, tid);
    if (wave >= 4) {  // gh overlaps other WGs' detect latency
      f32x4 g0 = z4, g1 = z4, g2 = z4;
#pragma unroll
      for (int c = 0; c < 16; ++c) {
        bf16x8 af = *(const bf16x8*)&hf[c];
        g0 = MFMA16(af, *ldsB(wWhh, cl, 512, c * 32 + kl), g0);
        g1 = MFMA16(af, *ldsB(wWhh, 16 + cl, 512, c * 32 + kl), g1);
        g2 = MFMA16(af, *ldsB(wWhh, 32 + cl, 512, c * 32 + kl), g2);
      }
#pragma unroll
      for (int j = 0; j < 4; ++j) {
        ghb[0][mt * 16 + rb + j][cl] = g0[j] + bh0;
        ghb[1][mt * 16 + rb + j][cl] = g1[j] + bh1;
        ghb[2][mt * 16 + rb + j][cl] = g2[j] + bh2;
      }
    }

    // ---- S2: e = relu(c1 @ We2^T + b2) ----
    pollc(cC1, tid, 32u * (u32)(t + 1));
    if (wave < 4) {
      u32x4 cf[16];
      ld16_c(c1ex + (size_t)arow * 512 + kl, cf);
      f32x4 a = z4;
#pragma unroll
      for (int c = 0; c < 16; ++c)
        a = MFMA16(*(const bf16x8*)&cf[c], *ldsB(wWe2, cl, 512, c * 32 + kl), a);
#pragma unroll
      for (int j = 0; j < 4; ++j)
        stg[mt * 16 + rb + j][cl] = f2b(fmaxf(a[j] + be2, 0.f));
      if (lane < 32) {
        int row = mt * 16 + (lane >> 1), half = lane & 1;
        u32x4 v = *(const u32x4*)&stg[row][half * 8];
        st16B_c(eex + (size_t)row * 512 + sl * 16 + half * 8, v);
      }
    }
    drain_vm();
    __syncthreads();
    postc(cE, tid);

    // ---- S3: mu/std -> z ----
    pollc(cE, tid, 32u * (u32)(t + 1));
    if (wave < 4) {
      u32x4 ef[16];
      ld16_c(eex + (size_t)arow * 512 + kl, ef);
      f32x4 a = z4;
#pragma unroll
      for (int c = 0; c < 16; ++c)
        a = MFMA16(*(const bf16x8*)&ef[c], *ldsB(wWms, cl, 512, c * 32 + kl), a);
      if (cl < 8) {
#pragma unroll
        for (int j = 0; j < 4; ++j) musp[mt * 16 + rb + j][cl] = a[j] + bms;
      }
    }
    __syncthreads();
    if (wave == 0) {  // one 8B store per row
      int r = lane;
      float m0 = musp[r][0], m1 = musp[r][1], m2 = musp[r][2], m3 = musp[r][3];
      float s0 = musp[r][4], s1 = musp[r][5], s2 = musp[r][6], s3 = musp[r][7];
      float p0 = fmaxf(s0, 0.f) + log1pf(__expf(-fabsf(s0)));
      float p1 = fmaxf(s1, 0.f) + log1pf(__expf(-fabsf(s1)));
      float p2 = fmaxf(s2, 0.f) + log1pf(__expf(-fabsf(s2)));
      float p3 = fmaxf(s3, 0.f) + log1pf(__expf(-fabsf(s3)));
      float z0 = ev4.x * p0 + m0, z1 = ev4.y * p1 + m1;
      float z2 = ev4.z * p2 + m2, z3 = ev4.w * p3 + m3;
      u64 pk = (u64)f2b2(z0, z1) | ((u64)f2b2(z2, z3) << 32);
      st8B_c(zall + ((size_t)t * NB + r) * ZDI + sl * 4, pk);
    }
    drain_vm();
    __syncthreads();
    postc(cZ, tid);

    // ---- S4: gi_z + gates + h' ----
    pollc(cZ, tid, 32u * (u32)(t + 1));
    u32x4 zf[4];
    ld4_c(zall + ((size_t)t * NB + arow) * ZDI + kl, zf);
    if (wave < 4) {
      f32x4 a = unpk4(gx0);
#pragma unroll
      for (int c = 0; c < 4; ++c)
        a = MFMA16(*(const bf16x8*)&zf[c], *ldsB(wWihz, cl, 128, c * 32 + kl), a);
#pragma unroll
      for (int j = 0; j < 4; ++j) red[0][mt * 16 + rb + j][cl] = a[j];
    } else {
      f32x4 a0 = unpk4(gx0), a1 = unpk4(gx1);
#pragma unroll
      for (int c = 0; c < 4; ++c) {
        bf16x8 af = *(const bf16x8*)&zf[c];
        a0 = MFMA16(af, *ldsB(wWihz, 16 + cl, 128, c * 32 + kl), a0);
        a1 = MFMA16(af, *ldsB(wWihz, 32 + cl, 128, c * 32 + kl), a1);
      }
#pragma unroll
      for (int j = 0; j < 4; ++j) {
        red[1][mt * 16 + rb + j][cl] = a0[j];
        red[2][mt * 16 + rb + j][cl] = a1[j];
      }
    }
    __syncthreads();
    {
      int r = tid >> 3, c0 = (tid & 7) << 1;
      float rg0 = sigm(red[0][r][c0] + ghb[0][r][c0]);
      float rg1 = sigm(red[0][r][c0 + 1] + ghb[0][r][c0 + 1]);
      float zg0 = sigm(red[1][r][c0] + ghb[1][r][c0]);
      float zg1 = sigm(red[1][r][c0 + 1] + ghb[1][r][c0 + 1]);
      float ng0 = tanhf(red[2][r][c0] + rg0 * ghb[2][r][c0]);
      float ng1 = tanhf(red[2][r][c0 + 1] + rg1 * ghb[2][r][c0 + 1]);
      hold[r][c0]     = (1.f - zg0) * ng0 + zg0 * hold[r][c0];
      hold[r][c0 + 1] = (1.f - zg1) * ng1 + zg1 * hold[r][c0 + 1];
    }
    __syncthreads();   // hold ready
    if (t < TT - 1) {
      if (wave == 0) {  // coalesced h' export: 2x16B per row, wave0 only
        int r = lane;
        const float* hp = &hold[r][0];
        u32x4 w0, w1;
        w0[0] = f2b2(hp[0], hp[1]);   w0[1] = f2b2(hp[2], hp[3]);
        w0[2] = f2b2(hp[4], hp[5]);   w0[3] = f2b2(hp[6], hp[7]);
        w1[0] = f2b2(hp[8], hp[9]);   w1[1] = f2b2(hp[10], hp[11]);
        w1[2] = f2b2(hp[12], hp[13]); w1[3] = f2b2(hp[14], hp[15]);
        u16* dst = hall + ((size_t)(t + 1) * NB + r) * HDI + sl * 16;
        st16B_c(dst, w0);
        st16B_c(dst + 8, w1);
        drain_vm();
      }
      postc(cH, tid);   // tid0 is in wave0: program order after its drain
    } else {
      if (wave == 0) {
        int r = lane;
        float* dst = hg + (size_t)r * 512 + sl * 16;
#pragma unroll
        for (int k = 0; k < 16; k += 4) {
          float4 o = {hold[r][k], hold[r][k + 1], hold[r][k + 2], hold[r][k + 3]};
          *(float4*)(dst + k) = o;
        }
      }
    }
  }
}

// ---------------- phase C: decoder chain + generation loss ----------------
__global__ __launch_bounds__(256, 1) void phaseC(
    char* ws, const float* db1, const float* db2, const float* dmbias,
    const float* genb, const int* ts, float* gpart) {
  __shared__ u16 lA[64 * 640];
  __shared__ u16 lB[64 * 512];
  int rb = blockIdx.x;
  int tid = threadIdx.x, wave = tid >> 6, lane = tid & 63;
  const u16* zall = (const u16*)(ws + OFF_ZALL);
  const u16* hall = (const u16*)(ws + OFF_HALL);
  const u16* wd1 = (const u16*)(ws + OFF_WD1);
  const u16* wd2 = (const u16*)(ws + OFF_WD2);
  const u16* wdm = (const u16*)(ws + OFF_WDM);
  const u16* wgw = (const u16*)(ws + OFF_WGW);

  fill_lds(lA, 640, zall + (size_t)rb * NB * ZDI, 128, hall + (size_t)rb * NB * HDI, 512);
  __syncthreads();
  for (int tile = wave; tile < 32; tile += 4) {
    f32x4 acc[4];
    acc[0] = acc[1] = acc[2] = acc[3] = (f32x4){0.f, 0.f, 0.f, 0.f};
    mm_tile(acc, lA, 640, 0, wd1, 640, tile * 16, 640, lane);
    int col = tile * 16 + (lane & 15);
    float bias = db1[col];
#pragma unroll
    for (int m = 0; m < 4; ++m)
#pragma unroll
      for (int j = 0; j < 4; ++j) {
        int row = (m << 4) + ((lane >> 4) << 2) + j;
        int byte = ((row * 512 + col) << 1) ^ ((row & 7) << 4);
        *(u16*)((char*)lB + byte) = f2b(fmaxf(acc[m][j] + bias, 0.f));
      }
  }
  __syncthreads();
  for (int tile = wave; tile < 32; tile += 4) {
    f32x4 acc[4];
    acc[0] = acc[1] = acc[2] = acc[3] = (f32x4){0.f, 0.f, 0.f, 0.f};
    mm_tile(acc, lB, 512, 0, wd2, 512, tile * 16, 512, lane);
    int col = tile * 16 + (lane & 15);
    float bias = db2[col];
#pragma unroll
    for (int m = 0; m < 4; ++m)
#pragma unroll
      for (int j = 0; j < 4; ++j) {
        int row = (m << 4) + ((lane >> 4) << 2) + j;
        int byte = ((row * 512 + col) << 1) ^ ((row & 7) << 4);
        *(u16*)((char*)lA + byte) = f2b(fmaxf(acc[m][j] + bias, 0.f));
      }
  }
  __syncthreads();
  for (int tile = wave; tile < 16; tile += 4) {
    f32x4 acc[4];
    acc[0] = acc[1] = acc[2] = acc[3] = (f32x4){0.f, 0.f, 0.f, 0.f};
    mm_tile(acc, lA, 512, 0, wdm, 512, tile * 16, 512, lane);
    int col = tile * 16 + (lane & 15);
    float bias = dmbias[col];
#pragma unroll
    for (int m = 0; m < 4; ++m)
#pragma unroll
      for (int j = 0; j < 4; ++j) {
        int row = (m << 4) + ((lane >> 4) << 2) + j;
        float v = 1.f / (1.f + __expf(-(acc[m][j] + bias)));
        int byte = ((row * 256 + col) << 1) ^ ((row & 7) << 4);
        *(u16*)((char*)lB + byte) = f2b(v);
      }
  }
  __syncthreads();
  float mr[16], sr[16], cap[16];
  int tg[16];
#pragma unroll
  for (int q = 0; q < 16; ++q) {
    int r = ((q >> 2) << 4) + ((lane >> 4) << 2) + (q & 3);
    tg[q] = ts[r * TT + rb];
    mr[q] = -1e30f; sr[q] = 0.f; cap[q] = -1e30f;
  }
  for (int ct = wave; ct < 625; ct += 4) {
    f32x4 acc[4];
    acc[0] = acc[1] = acc[2] = acc[3] = (f32x4){0.f, 0.f, 0.f, 0.f};
    mm_tile(acc, lB, 256, 0, wgw, 256, ct * 16, 256, lane);
    int colw = ct * 16 + (lane & 15);
    float gbv = genb[colw];
#pragma unroll
    for (int mi = 0; mi < 4; ++mi)
#pragma unroll
      for (int j = 0; j < 4; ++j) {
        int q = (mi << 2) + j;
        float v = acc[mi][j] + gbv;
        if (colw == tg[q]) cap[q] = v;
        float mn = fmaxf(mr[q], v);
        sr[q] = sr[q] * __expf(mr[q] - mn) + __expf(v - mn);
        mr[q] = mn;
      }
  }
#pragma unroll
  for (int d = 1; d < 16; d <<= 1) {
#pragma unroll
    for (int q = 0; q < 16; ++q) {
      float mo = __shfl_xor(mr[q], d);
      float so = __shfl_xor(sr[q], d);
      float co = __shfl_xor(cap[q], d);
      float mn = fmaxf(mr[q], mo);
      sr[q] = sr[q] * __expf(mr[q] - mn) + so * __expf(mo - mn);
      mr[q] = mn;
      cap[q] = fmaxf(cap[q], co);
    }
  }
  float* sc = (float*)lA;
  if ((lane & 15) == 0) {
    int g = lane >> 4;
#pragma unroll
    for (int q = 0; q < 16; ++q) {
      int r = ((q >> 2) << 4) + (g << 2) + (q & 3);
      sc[wave * 64 + r] = mr[q];
      sc[256 + wave * 64 + r] = sr[q];
      sc[512 + wave * 64 + r] = cap[q];
    }
  }
  __syncthreads();
  if (tid < 64) {
    float M = -1e30f, S = 0.f, C = -1e30f;
#pragma unroll
    for (int w = 0; w < 4; ++w) {
      float m = sc[w * 64 + tid], s = sc[256 + w * 64 + tid], c = sc[512 + w * 64 + tid];
      float mn = fmaxf(M, m);
      S = S * __expf(M - mn) + s * __expf(m - mn);
      M = mn;
      C = fmaxf(C, c);
    }
    float lossr = M + __logf(S) - C;
    for (int d = 1; d < 64; d <<= 1) lossr += __shfl_xor(lossr, d);
    if (tid == 0) gpart[rb] = lossr;
  }
}

// ---------------- final reduce + classifier ----------------
__global__ __launch_bounds__(256) void finalk(char* ws, const int* labels,
                                              const float* cw, const float* cb,
                                              const float* gpart, float* out) {
  __shared__ float sred[256];
  __shared__ float cred[64];
  int tid = threadIdx.x;
  sred[tid] = gpart[tid];
  __syncthreads();
  for (int s2 = 128; s2 > 0; s2 >>= 1) {
    if (tid < s2) sred[tid] += sred[tid + s2];
    __syncthreads();
  }
  const float* h = (const float*)(ws + OFF_H);
  if (tid < 64) {
    const float* hrow = h + tid * 512;
    float a0 = cb[0], a1 = cb[1], a2 = cb[2], a3 = cb[3];
    for (int k = 0; k < 512; k += 4) {
      float4 hv = *(const float4*)(hrow + k);
      float4 w0 = *(const float4*)(cw + 0 * 512 + k);
      float4 w1 = *(const float4*)(cw + 1 * 512 + k);
      float4 w2 = *(const float4*)(cw + 2 * 512 + k);
      float4 w3 = *(const float4*)(cw + 3 * 512 + k);
      a0 += hv.x * w0.x + hv.y * w0.y + hv.z * w0.z + hv.w * w0.w;
      a1 += hv.x * w1.x + hv.y * w1.y + hv.z * w1.z + hv.w * w1.w;
      a2 += hv.x * w2.x + hv.y * w2.y + hv.z * w2.z + hv.w * w2.w;
      a3 += hv.x * w3.x + hv.y * w3.y + hv.z * w3.z + hv.w * w3.w;
    }
    float M = fmaxf(fmaxf(a0, a1), fmaxf(a2, a3));
    float S = __expf(a0 - M) + __expf(a1 - M) + __expf(a2 - M) + __expf(a3 - M);
    int lb = labels[tid];
    float lg = (lb == 0) ? a0 : (lb == 1) ? a1 : (lb == 2) ? a2 : a3;
    cred[tid] = M + __logf(S) - lg;
  }
  __syncthreads();
  if (tid == 0) {
    float cs = 0.f;
    for (int i = 0; i < 64; ++i) cs += cred[i];
    out[0] = sred[0] / 16384.f;
    out[1] = cs / 64.f;
  }
}

extern "C" void kernel_launch(void* const* d_in, const int* in_sizes, int n_in,
                              void* d_out, int out_size, void* d_ws, size_t ws_size,
                              hipStream_t stream) {
  (void)in_sizes; (void)n_in; (void)out_size; (void)ws_size;
  char* ws = (char*)d_ws;
  const int* xs = (const int*)d_in[0];
  const int* ts = (const int*)d_in[1];
  const int* labels = (const int*)d_in[2];
  const int* wflag = (const int*)d_in[3];
  const float* eps = (const float*)d_in[4];
  const float* hnoise = (const float*)d_in[5];
  const float* embed = (const float*)d_in[6];
  const float* e_w1 = (const float*)d_in[7];
  const float* e_b1 = (const float*)d_in[8];
  const float* e_w2 = (const float*)d_in[9];
  const float* e_b2 = (const float*)d_in[10];
  const float* m_w = (const float*)d_in[11];
  const float* m_b = (const float*)d_in[12];
  const float* s_w = (const float*)d_in[13];
  const float* s_b = (const float*)d_in[14];
  const float* d_w1 = (const float*)d_in[15];
  const float* d_b1 = (const float*)d_in[16];
  const float* d_w2 = (const float*)d_in[17];
  const float* d_b2 = (const float*)d_in[18];
  const float* dm_w = (const float*)d_in[19];
  const float* dm_b = (const float*)d_in[20];
  const float* g_ih = (const float*)d_in[21];
  const float* g_hh = (const float*)d_in[22];
  const float* g_bih = (const float*)d_in[23];
  const float* g_bhh = (const float*)d_in[24];
  const float* gw = (const float*)d_in[25];
  const float* gb = (const float*)d_in[26];
  const float* cw = (const float*)d_in[27];
  const float* cb = (const float*)d_in[28];
  const float* hw = (const float*)d_in[29];
  const float* hb0 = (const float*)d_in[30];

  hipMemsetAsync(ws + OFF_FLAG, 0, 1024, stream);

  ConvArgs ca;
  const float* srcs[10] = {e_w1, e_w2, m_w, s_w, d_w1, d_w2, dm_w, g_ih, g_hh, gw};
  unsigned long long doffs[10] = {OFF_WE1, OFF_WE2, OFF_WMW, OFF_WSW, OFF_WD1,
                                  OFF_WD2, OFF_WDM, OFF_WIH, OFF_WHH, OFF_WGW};
  int ns[10] = {393216, 262144, 65536, 65536, 327680, 262144, 131072, 589824, 786432, 2560000};
  for (int i = 0; i < 10; ++i) { ca.s[i] = srcs[i]; ca.doff[i] = doffs[i]; ca.n[i] = ns[i]; }

  wconv<<<dim3(1250, 10), 256, 0, stream>>>(ws, ca);
  gatherx<<<2048, 256, 0, stream>>>(ws, xs, embed);
  h0init<<<128, 256, 0, stream>>>(ws, labels, wflag, hnoise, hw, hb0);
  gixk<<<256, 256, 0, stream>>>(ws, g_bih);
  phaseB<<<32, 512, 0, stream>>>(ws, eps, e_b1, e_b2, m_b, s_b, g_bhh);
  phaseC<<<256, 256, 0, stream>>>(ws, d_b1, d_b2, dm_b, gb, ts, (float*)(ws + OFF_GPART));
  finalk<<<1, 256, 0, stream>>>(ws, labels, cw, cb, (const float*)(ws + OFF_GPART), (float*)d_out);
}

// Round 12
// 4750.654 us; speedup vs baseline: 1.9659x; 1.1254x over previous
//
#include <hip/hip_runtime.h>

typedef unsigned short u16;
typedef unsigned int u32;
typedef unsigned long long u64;
using bf16x8 = __attribute__((ext_vector_type(8))) short;
using f32x4  = __attribute__((ext_vector_type(4))) float;
using u32x4  = __attribute__((ext_vector_type(4))) unsigned int;

#define TT   256
#define NB   64
#define XDI  256
#define HDI  512
#define ZDI  128
#define VV   10000

// ---- workspace byte offsets ----
#define OFF_WE1   512ull        // [512][768] bf16
#define OFF_WE2   786944ull     // [512][512] bf16
#define OFF_WMW   1311232ull    // [128][512] bf16
#define OFF_WSW   1442304ull    // [128][512] bf16
#define OFF_WD1   1573376ull    // [512][640] bf16
#define OFF_WD2   2228736ull    // [512][512] bf16
#define OFF_WDM   2753024ull    // [256][512] bf16
#define OFF_WIH   3015168ull    // [1536][384] bf16
#define OFF_WHH   4194816ull    // [1536][512] bf16
#define OFF_WGW   5767680ull    // [10000][256] bf16
#define OFF_XEMB  10887680ull   // [256][64][256] bf16
#define OFF_H     19276288ull   // [64][512] f32
#define OFF_ZALL  19997184ull   // [256*64][128] bf16 (also the z exchange)
#define OFF_HALL  24191488ull   // [256*64][512] bf16 (h entering step t; also the h exchange)
#define OFF_GPART 40968704ull   // [256] f32
#define OFF_EXC   40969728ull   // [64][512] bf16 c1 exchange
#define OFF_EXE   41035264ull   // [64][512] bf16 e exchange
#define OFF_FLAG  41100800ull   // 4 stage counters, 256B apart
#define OFF_GIX   41102848ull   // [256][1536][64] bf16 (x-part of gi + bih)
#define OFF_C1X   91766784ull   // [256][512][64] bf16 (x-part of c1 + b_e1), 16MB

__device__ __forceinline__ u16 f2b(float f) {
  union { float f; u32 u; } v; v.f = f;
  u32 r = v.u + 0x7fffu + ((v.u >> 16) & 1u);
  return (u16)(r >> 16);
}
__device__ __forceinline__ u32 f2b2(float a, float b) {
  return (u32)f2b(a) | ((u32)f2b(b) << 16);
}
__device__ __forceinline__ float b2f(u16 x) {
  union { u32 u; float f; } v; v.u = ((u32)x) << 16; return v.f;
}

#define MFMA16(a, b, c) __builtin_amdgcn_mfma_f32_16x16x32_bf16(a, b, c, 0, 0, 0)

__device__ __forceinline__ const bf16x8* ldsB(const u16* base, int r, int K, int k) {
  return (const bf16x8*)((const char*)base + (((r * K + k) << 1) ^ ((r & 7) << 4)));
}
__device__ __forceinline__ void ldsW(u16* base, int r, int K, int k, uint4 v) {
  *(uint4*)((char*)base + (((r * K + k) << 1) ^ ((r & 7) << 4))) = v;
}

__device__ __forceinline__ void fill_lds(u16* lds, int Ktot,
                                         const u16* s0, int K0,
                                         const u16* s1, int K1) {
  int kch = Ktot >> 3;
  int nch = 64 * kch;
  for (int i = threadIdx.x; i < nch; i += 256) {
    int row = i / kch;
    int k = (i - row * kch) << 3;
    const u16* src = (k < K0) ? (s0 + row * K0 + k) : (s1 + row * K1 + (k - K0));
    uint4 v = *(const uint4*)src;
    ldsW(lds, row, Ktot, k, v);
  }
}

__device__ __forceinline__ void mm_tile(f32x4 acc[4], const u16* lds, int ldsStride, int ldsK0,
                                        const u16* __restrict__ W, int Kw, int wcol0,
                                        int Klen, int lane) {
  const int kl = (lane >> 4) << 3;
  const int cl = lane & 15;
  const u16* wp = W + (size_t)(wcol0 + cl) * Kw;
  for (int kc = 0; kc < Klen; kc += 32) {
    int k = kc + kl;
    bf16x8 b = *(const bf16x8*)(wp + k);
#pragma unroll
    for (int m = 0; m < 4; ++m)
      acc[m] = MFMA16(*ldsB(lds, (m << 4) + cl, ldsStride, ldsK0 + k), b, acc[m]);
  }
}

// ---- MALL-coherent consumer loads (R4/R7-proven) ----
__device__ __forceinline__ void ld16_c(const void* p, u32x4* f) {
  asm volatile(
      "global_load_dwordx4 %0, %16, off sc0 sc1\n\t"
      "global_load_dwordx4 %1, %16, off offset:64 sc0 sc1\n\t"
      "global_load_dwordx4 %2, %16, off offset:128 sc0 sc1\n\t"
      "global_load_dwordx4 %3, %16, off offset:192 sc0 sc1\n\t"
      "global_load_dwordx4 %4, %16, off offset:256 sc0 sc1\n\t"
      "global_load_dwordx4 %5, %16, off offset:320 sc0 sc1\n\t"
      "global_load_dwordx4 %6, %16, off offset:384 sc0 sc1\n\t"
      "global_load_dwordx4 %7, %16, off offset:448 sc0 sc1\n\t"
      "global_load_dwordx4 %8, %16, off offset:512 sc0 sc1\n\t"
      "global_load_dwordx4 %9, %16, off offset:576 sc0 sc1\n\t"
      "global_load_dwordx4 %10, %16, off offset:640 sc0 sc1\n\t"
      "global_load_dwordx4 %11, %16, off offset:704 sc0 sc1\n\t"
      "global_load_dwordx4 %12, %16, off offset:768 sc0 sc1\n\t"
      "global_load_dwordx4 %13, %16, off offset:832 sc0 sc1\n\t"
      "global_load_dwordx4 %14, %16, off offset:896 sc0 sc1\n\t"
      "global_load_dwordx4 %15, %16, off offset:960 sc0 sc1\n\t"
      "s_waitcnt vmcnt(0)"
      : "=&v"(f[0]), "=&v"(f[1]), "=&v"(f[2]), "=&v"(f[3]),
        "=&v"(f[4]), "=&v"(f[5]), "=&v"(f[6]), "=&v"(f[7]),
        "=&v"(f[8]), "=&v"(f[9]), "=&v"(f[10]), "=&v"(f[11]),
        "=&v"(f[12]), "=&v"(f[13]), "=&v"(f[14]), "=&v"(f[15])
      : "v"(p) : "memory");
}
__device__ __forceinline__ void ld4_c(const void* p, u32x4* f) {
  asm volatile(
      "global_load_dwordx4 %0, %4, off sc0 sc1\n\t"
      "global_load_dwordx4 %1, %4, off offset:64 sc0 sc1\n\t"
      "global_load_dwordx4 %2, %4, off offset:128 sc0 sc1\n\t"
      "global_load_dwordx4 %3, %4, off offset:192 sc0 sc1\n\t"
      "s_waitcnt vmcnt(0)"
      : "=&v"(f[0]), "=&v"(f[1]), "=&v"(f[2]), "=&v"(f[3])
      : "v"(p) : "memory");
}
__device__ __forceinline__ void st16B_c(void* p, u32x4 v) {
  asm volatile("global_store_dwordx4 %0, %1, off sc0 sc1" :: "v"(p), "v"(v) : "memory");
}
__device__ __forceinline__ void st8B_c(void* p, u64 v) {
  asm volatile("global_store_dwordx2 %0, %1, off sc0 sc1" :: "v"(p), "v"(v) : "memory");
}
__device__ __forceinline__ void drain_vm() {
  asm volatile("s_waitcnt vmcnt(0)" ::: "memory");
}
// contention-free sync: one atomicAdd per WG per stage; one poller lane per WG (R7-proven).
__device__ __forceinline__ void postc(u32* cnt, int tid) {
  if (tid == 0)
    __hip_atomic_fetch_add(cnt, 1u, __ATOMIC_RELAXED, __HIP_MEMORY_SCOPE_AGENT);
}
__device__ __forceinline__ void pollc(u32* cnt, int tid, u32 target) {
  if (tid == 0) {
    while (__hip_atomic_load(cnt, __ATOMIC_RELAXED, __HIP_MEMORY_SCOPE_AGENT) < target)
      __builtin_amdgcn_s_sleep(1);
  }
  __syncthreads();
}
__device__ __forceinline__ f32x4 unpk4(u64 g) {
  f32x4 a;
#pragma unroll
  for (int j = 0; j < 4; ++j) a[j] = b2f((u16)(g >> (16 * j)));
  return a;
}
__device__ __forceinline__ float sigm(float x) { return 1.f / (1.f + __expf(-x)); }

// ---------------- prep kernels ----------------
struct ConvArgs { const float* s[10]; unsigned long long doff[10]; int n[10]; };

__global__ __launch_bounds__(256) void wconv(char* ws, ConvArgs a) {
  int seg = blockIdx.y;
  const float* s = a.s[seg];
  u16* d = (u16*)(ws + a.doff[seg]);
  int n = a.n[seg];
  int i = (blockIdx.x * 256 + threadIdx.x) * 8;
  if (i < n) {
    float4 v0 = *(const float4*)(s + i);
    float4 v1 = *(const float4*)(s + i + 4);
    uint4 o;
    o.x = f2b2(v0.x, v0.y); o.y = f2b2(v0.z, v0.w);
    o.z = f2b2(v1.x, v1.y); o.w = f2b2(v1.z, v1.w);
    *(uint4*)(d + i) = o;
  }
}

__global__ __launch_bounds__(256) void gatherx(char* ws, const int* xs, const float* embed) {
  u16* xemb = (u16*)(ws + OFF_XEMB);
  int i = blockIdx.x * 256 + threadIdx.x;
  int t = i >> 11;
  int rr = i & 2047;
  int n = rr >> 5;
  int k = (rr & 31) << 3;
  int idx = xs[n * TT + t];
  const float* src = embed + (size_t)idx * XDI + k;
  float4 v0 = *(const float4*)src;
  float4 v1 = *(const float4*)(src + 4);
  uint4 o;
  o.x = f2b2(v0.x, v0.y); o.y = f2b2(v0.z, v0.w);
  o.z = f2b2(v1.x, v1.y); o.w = f2b2(v1.z, v1.w);
  *(uint4*)(xemb + ((size_t)t * NB + n) * XDI + k) = o;
}

__global__ __launch_bounds__(256) void h0init(char* ws, const int* labels, const int* wflag,
                                              const float* hnoise, const float* hw, const float* hb0) {
  int i = blockIdx.x * 256 + threadIdx.x;  // 32768
  int n = i >> 9, c = i & 511;
  float v = (float)labels[n] * hw[c] + hb0[c];
  if (wflag[0]) v += hnoise[i];
  ((float*)(ws + OFF_H))[i] = v;
  ((u16*)(ws + OFF_HALL))[i] = f2b(v);   // hall[0] = h0 (bf16)
}

// gi_x[t][c][n] (96 tiles) + c1_x[t][c][n] = x@We1[:, :256]^T + b_e1 (32 tiles)
__global__ __launch_bounds__(256) void gixk(char* ws, const float* bih, const float* b_e1) {
  __shared__ u16 lA[64 * 256];
  int t = blockIdx.x;
  int tid = threadIdx.x, wave = tid >> 6, lane = tid & 63;
  const int cl = lane & 15, rb = (lane >> 4) << 2;
  const u16* xemb = (const u16*)(ws + OFF_XEMB);
  const u16* wih = (const u16*)(ws + OFF_WIH);
  const u16* we1 = (const u16*)(ws + OFF_WE1);
  u16* gix = (u16*)(ws + OFF_GIX);
  u16* c1x = (u16*)(ws + OFF_C1X);
  fill_lds(lA, 256, xemb + (size_t)t * NB * XDI, 256, xemb, 256);
  __syncthreads();
  for (int ct = wave; ct < 128; ct += 4) {
    f32x4 acc[4];
    acc[0] = acc[1] = acc[2] = acc[3] = (f32x4){0.f, 0.f, 0.f, 0.f};
    if (ct < 96) {
      mm_tile(acc, lA, 256, 0, wih, 384, ct * 16, 256, lane);
      int col = ct * 16 + cl;
      float bv = bih[col];
      u16* dst = gix + ((size_t)t * 1536 + col) * 64;
#pragma unroll
      for (int m = 0; m < 4; ++m) {
        u64 o = (u64)f2b(acc[m][0] + bv) | ((u64)f2b(acc[m][1] + bv) << 16)
              | ((u64)f2b(acc[m][2] + bv) << 32) | ((u64)f2b(acc[m][3] + bv) << 48);
        *(u64*)(dst + (m << 4) + rb) = o;
      }
    } else {
      int c0 = (ct - 96) * 16;
      mm_tile(acc, lA, 256, 0, we1, 768, c0, 256, lane);
      int col = c0 + cl;
      float bv = b_e1[col];
      u16* dst = c1x + ((size_t)t * 512 + col) * 64;
#pragma unroll
      for (int m = 0; m < 4; ++m) {
        u64 o = (u64)f2b(acc[m][0] + bv) | ((u64)f2b(acc[m][1] + bv) << 16)
              | ((u64)f2b(acc[m][2] + bv) << 32) | ((u64)f2b(acc[m][3] + bv) << 48);
        *(u64*)(dst + (m << 4) + rb) = o;
      }
    }
  }
}

// ---------------- phase B: weight-stationary recurrence, counter handoffs ----------------
// 32 WGs x 512 threads. R7/R11 protocol; x-part of c1 precomputed (c1x) so S1's
// critical path is h-load + 16 MFMAs only; no xemb traffic in the loop.
__global__ __launch_bounds__(512, 1) void phaseB(
    char* ws, const float* __restrict__ eps,
    const float* __restrict__ b_e2,
    const float* __restrict__ b_mw, const float* __restrict__ b_sw,
    const float* __restrict__ bhh) {
  __shared__ u16 wsl[59392];                // 116KB weight slices (swizzled)
  __shared__ float ghb[3][64][16];          // gh tiles
  __shared__ float red[3][64][16];          // gi_z tiles
  __shared__ float musp[64][8];             // mu / pre-softplus std
  __shared__ float hold[64][17];            // own h slice (f32, padded)
  __shared__ __align__(16) u16 stg[64][16]; // store-coalescing stage

  u16* wWe1 = wsl;            // [16][768] (cols 256-767 = h part used)
  u16* wWhh = wsl + 12288;    // [48][512]
  u16* wWe2 = wsl + 36864;    // [16][512]
  u16* wWms = wsl + 45056;    // [16][512] rows 0-3 mu, 4-7 std
  u16* wWihz = wsl + 53248;   // [48][128]

  const u16* we1 = (const u16*)(ws + OFF_WE1);
  const u16* we2 = (const u16*)(ws + OFF_WE2);
  const u16* wmw = (const u16*)(ws + OFF_WMW);
  const u16* wsw = (const u16*)(ws + OFF_WSW);
  const u16* wih = (const u16*)(ws + OFF_WIH);
  const u16* whh = (const u16*)(ws + OFF_WHH);
  const u16* gix = (const u16*)(ws + OFF_GIX);
  const u16* c1x = (const u16*)(ws + OFF_C1X);
  float* hg = (float*)(ws + OFF_H);
  u16* zall = (u16*)(ws + OFF_ZALL);
  u16* hall = (u16*)(ws + OFF_HALL);
  u16* c1ex = (u16*)(ws + OFF_EXC);
  u16* eex  = (u16*)(ws + OFF_EXE);
  u32* cC1 = (u32*)(ws + OFF_FLAG);
  u32* cE  = (u32*)(ws + OFF_FLAG + 256);
  u32* cZ  = (u32*)(ws + OFF_FLAG + 512);
  u32* cH  = (u32*)(ws + OFF_FLAG + 768);

  const int tid = threadIdx.x, wave = tid >> 6, lane = tid & 63;
  const int cl = lane & 15, kl = (lane >> 4) << 3, rb = (lane >> 4) << 2;
  const int sl = blockIdx.x;
  const int mt = wave & 3;
  const int arow = mt * 16 + cl;

  // ---- preload weight slices into LDS ----
  for (int c = tid; c < 1536; c += 512) {
    int r = c / 96, k = (c % 96) << 3;
    ldsW(wWe1, r, 768, k, *(const uint4*)(we1 + (size_t)(sl * 16 + r) * 768 + k));
  }
  for (int c = tid; c < 3072; c += 512) {
    int r = c >> 6, k = (c & 63) << 3;
    int gr = (r >> 4) * 512 + sl * 16 + (r & 15);
    ldsW(wWhh, r, 512, k, *(const uint4*)(whh + (size_t)gr * 512 + k));
  }
  for (int c = tid; c < 1024; c += 512) {
    int r = c >> 6, k = (c & 63) << 3;
    ldsW(wWe2, r, 512, k, *(const uint4*)(we2 + (size_t)(sl * 16 + r) * 512 + k));
  }
  for (int c = tid; c < 1024; c += 512) {
    int r = c >> 6, k = (c & 63) << 3;
    uint4 v = {0, 0, 0, 0};
    if (r < 4)      v = *(const uint4*)(wmw + (size_t)(sl * 4 + r) * 512 + k);
    else if (r < 8) v = *(const uint4*)(wsw + (size_t)(sl * 4 + r - 4) * 512 + k);
    ldsW(wWms, r, 512, k, v);
  }
  for (int c = tid; c < 768; c += 512) {
    int r = c >> 4, k = (c & 15) << 3;
    int gr = (r >> 4) * 512 + sl * 16 + (r & 15);
    ldsW(wWihz, r, 128, k, *(const uint4*)(wih + (size_t)gr * 384 + 256 + k));
  }
  for (int i = tid << 1; i < 1024; i += 1024) {
    int r = i >> 4, c = i & 15;
    float2 hv = *(const float2*)(hg + (size_t)r * 512 + sl * 16 + c);
    hold[r][c] = hv.x;
    hold[r][c + 1] = hv.y;
  }
  // biases
  const float be2 = b_e2[sl * 16 + cl];
  const float bms = (cl < 4) ? b_mw[sl * 4 + cl] : ((cl < 8) ? b_sw[sl * 4 + cl - 4] : 0.f);
  const float bh0 = bhh[sl * 16 + cl];
  const float bh1 = bhh[512 + sl * 16 + cl];
  const float bh2 = bhh[1024 + sl * 16 + cl];
  __syncthreads();

  const f32x4 z4 = {0.f, 0.f, 0.f, 0.f};
  for (int t = 0; t < TT; ++t) {
    // ---- S0: prefetch h-independent operands (plain cached) ----
    u64 gx0 = 0, gx1 = 0, cx0 = 0;
    float4 ev4 = {0.f, 0.f, 0.f, 0.f};
    if (wave < 4) {
      cx0 = *(const u64*)(c1x + ((size_t)t * 512 + sl * 16 + cl) * 64 + mt * 16 + rb);
      gx0 = *(const u64*)(gix + ((size_t)t * 1536 + sl * 16 + cl) * 64 + mt * 16 + rb);
    } else {
      gx0 = *(const u64*)(gix + ((size_t)t * 1536 + 512 + sl * 16 + cl) * 64 + mt * 16 + rb);
      gx1 = *(const u64*)(gix + ((size_t)t * 1536 + 1024 + sl * 16 + cl) * 64 + mt * 16 + rb);
    }
    if (wave == 0)
      ev4 = *(const float4*)(eps + (size_t)lane * (TT * ZDI) + (size_t)t * ZDI + sl * 4);

    // ---- S1: wait h(t); c1 slice (w0-3) / gh tiles (w4-7) ----
    pollc(cH, tid, 32u * (u32)t);
    u32x4 hf[16];
    ld16_c(hall + ((size_t)t * NB + arow) * HDI + kl, hf);
    if (wave < 4) {
      f32x4 a = unpk4(cx0);   // x-part + bias precomputed
#pragma unroll
      for (int c = 0; c < 16; ++c)
        a = MFMA16(*(const bf16x8*)&hf[c], *ldsB(wWe1, cl, 768, 256 + c * 32 + kl), a);
#pragma unroll
      for (int j = 0; j < 4; ++j)
        stg[mt * 16 + rb + j][cl] = f2b(fmaxf(a[j], 0.f));
      if (lane < 32) {
        int row = mt * 16 + (lane >> 1), half = lane & 1;
        u32x4 v = *(const u32x4*)&stg[row][half * 8];
        st16B_c(c1ex + (size_t)row * 512 + sl * 16 + half * 8, v);
      }
    }
    drain_vm();
    __syncthreads();
    postc(cC1, tid);
    if (wave >= 4) {  // gh overlaps other WGs' detect latency
      f32x4 g0 = z4, g1 = z4, g2 = z4;
#pragma unroll
      for (int c = 0; c < 16; ++c) {
        bf16x8 af = *(const bf16x8*)&hf[c];
        g0 = MFMA16(af, *ldsB(wWhh, cl, 512, c * 32 + kl), g0);
        g1 = MFMA16(af, *ldsB(wWhh, 16 + cl, 512, c * 32 + kl), g1);
        g2 = MFMA16(af, *ldsB(wWhh, 32 + cl, 512, c * 32 + kl), g2);
      }
#pragma unroll
      for (int j = 0; j < 4; ++j) {
        ghb[0][mt * 16 + rb + j][cl] = g0[j] + bh0;
        ghb[1][mt * 16 + rb + j][cl] = g1[j] + bh1;
        ghb[2][mt * 16 + rb + j][cl] = g2[j] + bh2;
      }
    }

    // ---- S2: e = relu(c1 @ We2^T + b2) ----
    pollc(cC1, tid, 32u * (u32)(t + 1));
    if (wave < 4) {
      u32x4 cf[16];
      ld16_c(c1ex + (size_t)arow * 512 + kl, cf);
      f32x4 a = z4;
#pragma unroll
      for (int c = 0; c < 16; ++c)
        a = MFMA16(*(const bf16x8*)&cf[c], *ldsB(wWe2, cl, 512, c * 32 + kl), a);
#pragma unroll
      for (int j = 0; j < 4; ++j)
        stg[mt * 16 + rb + j][cl] = f2b(fmaxf(a[j] + be2, 0.f));
      if (lane < 32) {
        int row = mt * 16 + (lane >> 1), half = lane & 1;
        u32x4 v = *(const u32x4*)&stg[row][half * 8];
        st16B_c(eex + (size_t)row * 512 + sl * 16 + half * 8, v);
      }
    }
    drain_vm();
    __syncthreads();
    postc(cE, tid);

    // ---- S3: mu/std -> z ----
    pollc(cE, tid, 32u * (u32)(t + 1));
    if (wave < 4) {
      u32x4 ef[16];
      ld16_c(eex + (size_t)arow * 512 + kl, ef);
      f32x4 a = z4;
#pragma unroll
      for (int c = 0; c < 16; ++c)
        a = MFMA16(*(const bf16x8*)&ef[c], *ldsB(wWms, cl, 512, c * 32 + kl), a);
      if (cl < 8) {
#pragma unroll
        for (int j = 0; j < 4; ++j) musp[mt * 16 + rb + j][cl] = a[j] + bms;
      }
    }
    __syncthreads();
    if (wave == 0) {  // one 8B store per row
      int r = lane;
      float m0 = musp[r][0], m1 = musp[r][1], m2 = musp[r][2], m3 = musp[r][3];
      float s0 = musp[r][4], s1 = musp[r][5], s2 = musp[r][6], s3 = musp[r][7];
      float p0 = fmaxf(s0, 0.f) + log1pf(__expf(-fabsf(s0)));
      float p1 = fmaxf(s1, 0.f) + log1pf(__expf(-fabsf(s1)));
      float p2 = fmaxf(s2, 0.f) + log1pf(__expf(-fabsf(s2)));
      float p3 = fmaxf(s3, 0.f) + log1pf(__expf(-fabsf(s3)));
      float z0 = ev4.x * p0 + m0, z1 = ev4.y * p1 + m1;
      float z2 = ev4.z * p2 + m2, z3 = ev4.w * p3 + m3;
      u64 pk = (u64)f2b2(z0, z1) | ((u64)f2b2(z2, z3) << 32);
      st8B_c(zall + ((size_t)t * NB + r) * ZDI + sl * 4, pk);
    }
    drain_vm();
    __syncthreads();
    postc(cZ, tid);

    // ---- S4: gi_z + gates + h' ----
    pollc(cZ, tid, 32u * (u32)(t + 1));
    u32x4 zf[4];
    ld4_c(zall + ((size_t)t * NB + arow) * ZDI + kl, zf);
    if (wave < 4) {
      f32x4 a = unpk4(gx0);
#pragma unroll
      for (int c = 0; c < 4; ++c)
        a = MFMA16(*(const bf16x8*)&zf[c], *ldsB(wWihz, cl, 128, c * 32 + kl), a);
#pragma unroll
      for (int j = 0; j < 4; ++j) red[0][mt * 16 + rb + j][cl] = a[j];
    } else {
      f32x4 a0 = unpk4(gx0), a1 = unpk4(gx1);
#pragma unroll
      for (int c = 0; c < 4; ++c) {
        bf16x8 af = *(const bf16x8*)&zf[c];
        a0 = MFMA16(af, *ldsB(wWihz, 16 + cl, 128, c * 32 + kl), a0);
        a1 = MFMA16(af, *ldsB(wWihz, 32 + cl, 128, c * 32 + kl), a1);
      }
#pragma unroll
      for (int j = 0; j < 4; ++j) {
        red[1][mt * 16 + rb + j][cl] = a0[j];
        red[2][mt * 16 + rb + j][cl] = a1[j];
      }
    }
    __syncthreads();
    {
      int r = tid >> 3, c0 = (tid & 7) << 1;
      float rg0 = sigm(red[0][r][c0] + ghb[0][r][c0]);
      float rg1 = sigm(red[0][r][c0 + 1] + ghb[0][r][c0 + 1]);
      float zg0 = sigm(red[1][r][c0] + ghb[1][r][c0]);
      float zg1 = sigm(red[1][r][c0 + 1] + ghb[1][r][c0 + 1]);
      float ng0 = tanhf(red[2][r][c0] + rg0 * ghb[2][r][c0]);
      float ng1 = tanhf(red[2][r][c0 + 1] + rg1 * ghb[2][r][c0 + 1]);
      hold[r][c0]     = (1.f - zg0) * ng0 + zg0 * hold[r][c0];
      hold[r][c0 + 1] = (1.f - zg1) * ng1 + zg1 * hold[r][c0 + 1];
    }
    __syncthreads();   // hold ready
    if (t < TT - 1) {
      if (wave == 0) {  // coalesced h' export: 2x16B per row, wave0 only
        int r = lane;
        const float* hp = &hold[r][0];
        u32x4 w0, w1;
        w0[0] = f2b2(hp[0], hp[1]);   w0[1] = f2b2(hp[2], hp[3]);
        w0[2] = f2b2(hp[4], hp[5]);   w0[3] = f2b2(hp[6], hp[7]);
        w1[0] = f2b2(hp[8], hp[9]);   w1[1] = f2b2(hp[10], hp[11]);
        w1[2] = f2b2(hp[12], hp[13]); w1[3] = f2b2(hp[14], hp[15]);
        u16* dst = hall + ((size_t)(t + 1) * NB + r) * HDI + sl * 16;
        st16B_c(dst, w0);
        st16B_c(dst + 8, w1);
        drain_vm();
      }
      postc(cH, tid);   // tid0 is in wave0: program order after its drain
    } else {
      if (wave == 0) {
        int r = lane;
        float* dst = hg + (size_t)r * 512 + sl * 16;
#pragma unroll
        for (int k = 0; k < 16; k += 4) {
          float4 o = {hold[r][k], hold[r][k + 1], hold[r][k + 2], hold[r][k + 3]};
          *(float4*)(dst + k) = o;
        }
      }
    }
  }
}

// ---------------- phase C: decoder chain + generation loss ----------------
__global__ __launch_bounds__(256, 1) void phaseC(
    char* ws, const float* db1, const float* db2, const float* dmbias,
    const float* genb, const int* ts, float* gpart) {
  __shared__ u16 lA[64 * 640];
  __shared__ u16 lB[64 * 512];
  int rb = blockIdx.x;
  int tid = threadIdx.x, wave = tid >> 6, lane = tid & 63;
  const u16* zall = (const u16*)(ws + OFF_ZALL);
  const u16* hall = (const u16*)(ws + OFF_HALL);
  const u16* wd1 = (const u16*)(ws + OFF_WD1);
  const u16* wd2 = (const u16*)(ws + OFF_WD2);
  const u16* wdm = (const u16*)(ws + OFF_WDM);
  const u16* wgw = (const u16*)(ws + OFF_WGW);

  fill_lds(lA, 640, zall + (size_t)rb * NB * ZDI, 128, hall + (size_t)rb * NB * HDI, 512);
  __syncthreads();
  for (int tile = wave; tile < 32; tile += 4) {
    f32x4 acc[4];
    acc[0] = acc[1] = acc[2] = acc[3] = (f32x4){0.f, 0.f, 0.f, 0.f};
    mm_tile(acc, lA, 640, 0, wd1, 640, tile * 16, 640, lane);
    int col = tile * 16 + (lane & 15);
    float bias = db1[col];
#pragma unroll
    for (int m = 0; m < 4; ++m)
#pragma unroll
      for (int j = 0; j < 4; ++j) {
        int row = (m << 4) + ((lane >> 4) << 2) + j;
        int byte = ((row * 512 + col) << 1) ^ ((row & 7) << 4);
        *(u16*)((char*)lB + byte) = f2b(fmaxf(acc[m][j] + bias, 0.f));
      }
  }
  __syncthreads();
  for (int tile = wave; tile < 32; tile += 4) {
    f32x4 acc[4];
    acc[0] = acc[1] = acc[2] = acc[3] = (f32x4){0.f, 0.f, 0.f, 0.f};
    mm_tile(acc, lB, 512, 0, wd2, 512, tile * 16, 512, lane);
    int col = tile * 16 + (lane & 15);
    float bias = db2[col];
#pragma unroll
    for (int m = 0; m < 4; ++m)
#pragma unroll
      for (int j = 0; j < 4; ++j) {
        int row = (m << 4) + ((lane >> 4) << 2) + j;
        int byte = ((row * 512 + col) << 1) ^ ((row & 7) << 4);
        *(u16*)((char*)lA + byte) = f2b(fmaxf(acc[m][j] + bias, 0.f));
      }
  }
  __syncthreads();
  for (int tile = wave; tile < 16; tile += 4) {
    f32x4 acc[4];
    acc[0] = acc[1] = acc[2] = acc[3] = (f32x4){0.f, 0.f, 0.f, 0.f};
    mm_tile(acc, lA, 512, 0, wdm, 512, tile * 16, 512, lane);
    int col = tile * 16 + (lane & 15);
    float bias = dmbias[col];
#pragma unroll
    for (int m = 0; m < 4; ++m)
#pragma unroll
      for (int j = 0; j < 4; ++j) {
        int row = (m << 4) + ((lane >> 4) << 2) + j;
        float v = 1.f / (1.f + __expf(-(acc[m][j] + bias)));
        int byte = ((row * 256 + col) << 1) ^ ((row & 7) << 4);
        *(u16*)((char*)lB + byte) = f2b(v);
      }
  }
  __syncthreads();
  float mr[16], sr[16], cap[16];
  int tg[16];
#pragma unroll
  for (int q = 0; q < 16; ++q) {
    int r = ((q >> 2) << 4) + ((lane >> 4) << 2) + (q & 3);
    tg[q] = ts[r * TT + rb];
    mr[q] = -1e30f; sr[q] = 0.f; cap[q] = -1e30f;
  }
  for (int ct = wave; ct < 625; ct += 4) {
    f32x4 acc[4];
    acc[0] = acc[1] = acc[2] = acc[3] = (f32x4){0.f, 0.f, 0.f, 0.f};
    mm_tile(acc, lB, 256, 0, wgw, 256, ct * 16, 256, lane);
    int colw = ct * 16 + (lane & 15);
    float gbv = genb[colw];
#pragma unroll
    for (int mi = 0; mi < 4; ++mi)
#pragma unroll
      for (int j = 0; j < 4; ++j) {
        int q = (mi << 2) + j;
        float v = acc[mi][j] + gbv;
        if (colw == tg[q]) cap[q] = v;
        float mn = fmaxf(mr[q], v);
        sr[q] = sr[q] * __expf(mr[q] - mn) + __expf(v - mn);
        mr[q] = mn;
      }
  }
#pragma unroll
  for (int d = 1; d < 16; d <<= 1) {
#pragma unroll
    for (int q = 0; q < 16; ++q) {
      float mo = __shfl_xor(mr[q], d);
      float so = __shfl_xor(sr[q], d);
      float co = __shfl_xor(cap[q], d);
      float mn = fmaxf(mr[q], mo);
      sr[q] = sr[q] * __expf(mr[q] - mn) + so * __expf(mo - mn);
      mr[q] = mn;
      cap[q] = fmaxf(cap[q], co);
    }
  }
  float* sc = (float*)lA;
  if ((lane & 15) == 0) {
    int g = lane >> 4;
#pragma unroll
    for (int q = 0; q < 16; ++q) {
      int r = ((q >> 2) << 4) + (g << 2) + (q & 3);
      sc[wave * 64 + r] = mr[q];
      sc[256 + wave * 64 + r] = sr[q];
      sc[512 + wave * 64 + r] = cap[q];
    }
  }
  __syncthreads();
  if (tid < 64) {
    float M = -1e30f, S = 0.f, C = -1e30f;
#pragma unroll
    for (int w = 0; w < 4; ++w) {
      float m = sc[w * 64 + tid], s = sc[256 + w * 64 + tid], c = sc[512 + w * 64 + tid];
      float mn = fmaxf(M, m);
      S = S * __expf(M - mn) + s * __expf(m - mn);
      M = mn;
      C = fmaxf(C, c);
    }
    float lossr = M + __logf(S) - C;
    for (int d = 1; d < 64; d <<= 1) lossr += __shfl_xor(lossr, d);
    if (tid == 0) gpart[rb] = lossr;
  }
}

// ---------------- final reduce + classifier ----------------
__global__ __launch_bounds__(256) void finalk(char* ws, const int* labels,
                                              const float* cw, const float* cb,
                                              const float* gpart, float* out) {
  __shared__ float sred[256];
  __shared__ float cred[64];
  int tid = threadIdx.x;
  sred[tid] = gpart[tid];
  __syncthreads();
  for (int s2 = 128; s2 > 0; s2 >>= 1) {
    if (tid < s2) sred[tid] += sred[tid + s2];
    __syncthreads();
  }
  const float* h = (const float*)(ws + OFF_H);
  if (tid < 64) {
    const float* hrow = h + tid * 512;
    float a0 = cb[0], a1 = cb[1], a2 = cb[2], a3 = cb[3];
    for (int k = 0; k < 512; k += 4) {
      float4 hv = *(const float4*)(hrow + k);
      float4 w0 = *(const float4*)(cw + 0 * 512 + k);
      float4 w1 = *(const float4*)(cw + 1 * 512 + k);
      float4 w2 = *(const float4*)(cw + 2 * 512 + k);
      float4 w3 = *(const float4*)(cw + 3 * 512 + k);
      a0 += hv.x * w0.x + hv.y * w0.y + hv.z * w0.z + hv.w * w0.w;
      a1 += hv.x * w1.x + hv.y * w1.y + hv.z * w1.z + hv.w * w1.w;
      a2 += hv.x * w2.x + hv.y * w2.y + hv.z * w2.z + hv.w * w2.w;
      a3 += hv.x * w3.x + hv.y * w3.y + hv.z * w3.z + hv.w * w3.w;
    }
    float M = fmaxf(fmaxf(a0, a1), fmaxf(a2, a3));
    float S = __expf(a0 - M) + __expf(a1 - M) + __expf(a2 - M) + __expf(a3 - M);
    int lb = labels[tid];
    float lg = (lb == 0) ? a0 : (lb == 1) ? a1 : (lb == 2) ? a2 : a3;
    cred[tid] = M + __logf(S) - lg;
  }
  __syncthreads();
  if (tid == 0) {
    float cs = 0.f;
    for (int i = 0; i < 64; ++i) cs += cred[i];
    out[0] = sred[0] / 16384.f;
    out[1] = cs / 64.f;
  }
}

extern "C" void kernel_launch(void* const* d_in, const int* in_sizes, int n_in,
                              void* d_out, int out_size, void* d_ws, size_t ws_size,
                              hipStream_t stream) {
  (void)in_sizes; (void)n_in; (void)out_size; (void)ws_size;
  char* ws = (char*)d_ws;
  const int* xs = (const int*)d_in[0];
  const int* ts = (const int*)d_in[1];
  const int* labels = (const int*)d_in[2];
  const int* wflag = (const int*)d_in[3];
  const float* eps = (const float*)d_in[4];
  const float* hnoise = (const float*)d_in[5];
  const float* embed = (const float*)d_in[6];
  const float* e_w1 = (const float*)d_in[7];
  const float* e_b1 = (const float*)d_in[8];
  const float* e_w2 = (const float*)d_in[9];
  const float* e_b2 = (const float*)d_in[10];
  const float* m_w = (const float*)d_in[11];
  const float* m_b = (const float*)d_in[12];
  const float* s_w = (const float*)d_in[13];
  const float* s_b = (const float*)d_in[14];
  const float* d_w1 = (const float*)d_in[15];
  const float* d_b1 = (const float*)d_in[16];
  const float* d_w2 = (const float*)d_in[17];
  const float* d_b2 = (const float*)d_in[18];
  const float* dm_w = (const float*)d_in[19];
  const float* dm_b = (const float*)d_in[20];
  const float* g_ih = (const float*)d_in[21];
  const float* g_hh = (const float*)d_in[22];
  const float* g_bih = (const float*)d_in[23];
  const float* g_bhh = (const float*)d_in[24];
  const float* gw = (const float*)d_in[25];
  const float* gb = (const float*)d_in[26];
  const float* cw = (const float*)d_in[27];
  const float* cb = (const float*)d_in[28];
  const float* hw = (const float*)d_in[29];
  const float* hb0 = (const float*)d_in[30];

  hipMemsetAsync(ws + OFF_FLAG, 0, 1024, stream);

  ConvArgs ca;
  const float* srcs[10] = {e_w1, e_w2, m_w, s_w, d_w1, d_w2, dm_w, g_ih, g_hh, gw};
  unsigned long long doffs[10] = {OFF_WE1, OFF_WE2, OFF_WMW, OFF_WSW, OFF_WD1,
                                  OFF_WD2, OFF_WDM, OFF_WIH, OFF_WHH, OFF_WGW};
  int ns[10] = {393216, 262144, 65536, 65536, 327680, 262144, 131072, 589824, 786432, 2560000};
  for (int i = 0; i < 10; ++i) { ca.s[i] = srcs[i]; ca.doff[i] = doffs[i]; ca.n[i] = ns[i]; }

  wconv<<<dim3(1250, 10), 256, 0, stream>>>(ws, ca);
  gatherx<<<2048, 256, 0, stream>>>(ws, xs, embed);
  h0init<<<128, 256, 0, stream>>>(ws, labels, wflag, hnoise, hw, hb0);
  gixk<<<256, 256, 0, stream>>>(ws, g_bih, e_b1);
  phaseB<<<32, 512, 0, stream>>>(ws, eps, e_b2, m_b, s_b, g_bhh);
  phaseC<<<256, 256, 0, stream>>>(ws, d_b1, d_b2, dm_b, gb, ts, (float*)(ws + OFF_GPART));
  finalk<<<1, 256, 0, stream>>>(ws, labels, cw, cb, (const float*)(ws + OFF_GPART), (float*)d_out);
}

// Round 13
// 4686.589 us; speedup vs baseline: 1.9928x; 1.0137x over previous
//
#include <hip/hip_runtime.h>

typedef unsigned short u16;
typedef unsigned int u32;
typedef unsigned long long u64;
using bf16x8 = __attribute__((ext_vector_type(8))) short;
using f32x4  = __attribute__((ext_vector_type(4))) float;
using u32x4  = __attribute__((ext_vector_type(4))) unsigned int;

#define TT   256
#define NB   64
#define XDI  256
#define HDI  512
#define ZDI  128
#define VV   10000
#define RING 64
#define RMSK 63

// ---- workspace byte offsets ----
#define OFF_WE1   512ull        // [512][768] bf16
#define OFF_WE2   786944ull     // [512][512] bf16
#define OFF_WMW   1311232ull    // [128][512] bf16
#define OFF_WSW   1442304ull    // [128][512] bf16
#define OFF_WD1   1573376ull    // [512][640] bf16
#define OFF_WD2   2228736ull    // [512][512] bf16
#define OFF_WDM   2753024ull    // [256][512] bf16
#define OFF_WIH   3015168ull    // [1536][384] bf16
#define OFF_WHH   4194816ull    // [1536][512] bf16
#define OFF_WGW   5767680ull    // [10000][256] bf16
#define OFF_XEMB  10887680ull   // [256][64][256] bf16
#define OFF_H     19276288ull   // [64][512] f32
#define OFF_ZALL  19997184ull   // [256*64][128] bf16 (t-indexed z exchange)
#define OFF_HALL  24191488ull   // [256*64][512] bf16 (t-indexed h exchange)
#define OFF_GPART 40968704ull   // [256] f32
#define OFF_FLAG  41100800ull   // 4 stage counters, 256B apart
#define OFF_GIX   41102848ull   // [256][1536][64] bf16 (x-part of gi + bih)
#define OFF_C1X   91766784ull   // [256][512][64] bf16 (x-part of c1 + b_e1), 16MB
#define OFF_C1A   108544000ull  // [64][64][512] bf16 c1 ring (4MB)
#define OFF_EA    112738304ull  // [64][64][512] bf16 e ring (4MB)

__device__ __forceinline__ u16 f2b(float f) {
  union { float f; u32 u; } v; v.f = f;
  u32 r = v.u + 0x7fffu + ((v.u >> 16) & 1u);
  return (u16)(r >> 16);
}
__device__ __forceinline__ u32 f2b2(float a, float b) {
  return (u32)f2b(a) | ((u32)f2b(b) << 16);
}
__device__ __forceinline__ float b2f(u16 x) {
  union { u32 u; float f; } v; v.u = ((u32)x) << 16; return v.f;
}

#define MFMA16(a, b, c) __builtin_amdgcn_mfma_f32_16x16x32_bf16(a, b, c, 0, 0, 0)

__device__ __forceinline__ const bf16x8* ldsB(const u16* base, int r, int K, int k) {
  return (const bf16x8*)((const char*)base + (((r * K + k) << 1) ^ ((r & 7) << 4)));
}
__device__ __forceinline__ void ldsW(u16* base, int r, int K, int k, uint4 v) {
  *(uint4*)((char*)base + (((r * K + k) << 1) ^ ((r & 7) << 4))) = v;
}

__device__ __forceinline__ void fill_lds(u16* lds, int Ktot,
                                         const u16* s0, int K0,
                                         const u16* s1, int K1) {
  int kch = Ktot >> 3;
  int nch = 64 * kch;
  for (int i = threadIdx.x; i < nch; i += 256) {
    int row = i / kch;
    int k = (i - row * kch) << 3;
    const u16* src = (k < K0) ? (s0 + row * K0 + k) : (s1 + row * K1 + (k - K0));
    uint4 v = *(const uint4*)src;
    ldsW(lds, row, Ktot, k, v);
  }
}

__device__ __forceinline__ void mm_tile(f32x4 acc[4], const u16* lds, int ldsStride, int ldsK0,
                                        const u16* __restrict__ W, int Kw, int wcol0,
                                        int Klen, int lane) {
  const int kl = (lane >> 4) << 3;
  const int cl = lane & 15;
  const u16* wp = W + (size_t)(wcol0 + cl) * Kw;
  for (int kc = 0; kc < Klen; kc += 32) {
    int k = kc + kl;
    bf16x8 b = *(const bf16x8*)(wp + k);
#pragma unroll
    for (int m = 0; m < 4; ++m)
      acc[m] = MFMA16(*ldsB(lds, (m << 4) + cl, ldsStride, ldsK0 + k), b, acc[m]);
  }
}

// ---- exchange loads: sc0 only (L1-bypass, L2-shared across the XCD's 4 WGs).
// Safe because every exchange address is t-unique (never re-read stale).
__device__ __forceinline__ void ld16_l2(const void* p, u32x4* f) {
  asm volatile(
      "global_load_dwordx4 %0, %16, off sc0\n\t"
      "global_load_dwordx4 %1, %16, off offset:64 sc0\n\t"
      "global_load_dwordx4 %2, %16, off offset:128 sc0\n\t"
      "global_load_dwordx4 %3, %16, off offset:192 sc0\n\t"
      "global_load_dwordx4 %4, %16, off offset:256 sc0\n\t"
      "global_load_dwordx4 %5, %16, off offset:320 sc0\n\t"
      "global_load_dwordx4 %6, %16, off offset:384 sc0\n\t"
      "global_load_dwordx4 %7, %16, off offset:448 sc0\n\t"
      "global_load_dwordx4 %8, %16, off offset:512 sc0\n\t"
      "global_load_dwordx4 %9, %16, off offset:576 sc0\n\t"
      "global_load_dwordx4 %10, %16, off offset:640 sc0\n\t"
      "global_load_dwordx4 %11, %16, off offset:704 sc0\n\t"
      "global_load_dwordx4 %12, %16, off offset:768 sc0\n\t"
      "global_load_dwordx4 %13, %16, off offset:832 sc0\n\t"
      "global_load_dwordx4 %14, %16, off offset:896 sc0\n\t"
      "global_load_dwordx4 %15, %16, off offset:960 sc0\n\t"
      "s_waitcnt vmcnt(0)"
      : "=&v"(f[0]), "=&v"(f[1]), "=&v"(f[2]), "=&v"(f[3]),
        "=&v"(f[4]), "=&v"(f[5]), "=&v"(f[6]), "=&v"(f[7]),
        "=&v"(f[8]), "=&v"(f[9]), "=&v"(f[10]), "=&v"(f[11]),
        "=&v"(f[12]), "=&v"(f[13]), "=&v"(f[14]), "=&v"(f[15])
      : "v"(p) : "memory");
}
__device__ __forceinline__ void ld4_l2(const void* p, u32x4* f) {
  asm volatile(
      "global_load_dwordx4 %0, %4, off sc0\n\t"
      "global_load_dwordx4 %1, %4, off offset:64 sc0\n\t"
      "global_load_dwordx4 %2, %4, off offset:128 sc0\n\t"
      "global_load_dwordx4 %3, %4, off offset:192 sc0\n\t"
      "s_waitcnt vmcnt(0)"
      : "=&v"(f[0]), "=&v"(f[1]), "=&v"(f[2]), "=&v"(f[3])
      : "v"(p) : "memory");
}
__device__ __forceinline__ void st16B_c(void* p, u32x4 v) {
  asm volatile("global_store_dwordx4 %0, %1, off sc0 sc1" :: "v"(p), "v"(v) : "memory");
}
__device__ __forceinline__ void st8B_c(void* p, u64 v) {
  asm volatile("global_store_dwordx2 %0, %1, off sc0 sc1" :: "v"(p), "v"(v) : "memory");
}
__device__ __forceinline__ void drain_vm() {
  asm volatile("s_waitcnt vmcnt(0)" ::: "memory");
}
// contention-free sync (R7-proven)
__device__ __forceinline__ void postc(u32* cnt, int tid) {
  if (tid == 0)
    __hip_atomic_fetch_add(cnt, 1u, __ATOMIC_RELAXED, __HIP_MEMORY_SCOPE_AGENT);
}
__device__ __forceinline__ void pollc(u32* cnt, int tid, u32 target) {
  if (tid == 0) {
    while (__hip_atomic_load(cnt, __ATOMIC_RELAXED, __HIP_MEMORY_SCOPE_AGENT) < target)
      __builtin_amdgcn_s_sleep(1);
  }
  __syncthreads();
}
__device__ __forceinline__ f32x4 unpk4(u64 g) {
  f32x4 a;
#pragma unroll
  for (int j = 0; j < 4; ++j) a[j] = b2f((u16)(g >> (16 * j)));
  return a;
}
__device__ __forceinline__ float sigm(float x) { return 1.f / (1.f + __expf(-x)); }

// ---------------- prep kernels ----------------
struct ConvArgs { const float* s[10]; unsigned long long doff[10]; int n[10]; };

__global__ __launch_bounds__(256) void wconv(char* ws, ConvArgs a) {
  int seg = blockIdx.y;
  const float* s = a.s[seg];
  u16* d = (u16*)(ws + a.doff[seg]);
  int n = a.n[seg];
  int i = (blockIdx.x * 256 + threadIdx.x) * 8;
  if (i < n) {
    float4 v0 = *(const float4*)(s + i);
    float4 v1 = *(const float4*)(s + i + 4);
    uint4 o;
    o.x = f2b2(v0.x, v0.y); o.y = f2b2(v0.z, v0.w);
    o.z = f2b2(v1.x, v1.y); o.w = f2b2(v1.z, v1.w);
    *(uint4*)(d + i) = o;
  }
}

__global__ __launch_bounds__(256) void gatherx(char* ws, const int* xs, const float* embed) {
  u16* xemb = (u16*)(ws + OFF_XEMB);
  int i = blockIdx.x * 256 + threadIdx.x;
  int t = i >> 11;
  int rr = i & 2047;
  int n = rr >> 5;
  int k = (rr & 31) << 3;
  int idx = xs[n * TT + t];
  const float* src = embed + (size_t)idx * XDI + k;
  float4 v0 = *(const float4*)src;
  float4 v1 = *(const float4*)(src + 4);
  uint4 o;
  o.x = f2b2(v0.x, v0.y); o.y = f2b2(v0.z, v0.w);
  o.z = f2b2(v1.x, v1.y); o.w = f2b2(v1.z, v1.w);
  *(uint4*)(xemb + ((size_t)t * NB + n) * XDI + k) = o;
}

__global__ __launch_bounds__(256) void h0init(char* ws, const int* labels, const int* wflag,
                                              const float* hnoise, const float* hw, const float* hb0) {
  int i = blockIdx.x * 256 + threadIdx.x;  // 32768
  int n = i >> 9, c = i & 511;
  float v = (float)labels[n] * hw[c] + hb0[c];
  if (wflag[0]) v += hnoise[i];
  ((float*)(ws + OFF_H))[i] = v;
  ((u16*)(ws + OFF_HALL))[i] = f2b(v);   // hall[0] = h0 (kernel boundary flushes L2)
}

// gi_x[t][c][n] (96 tiles) + c1_x[t][c][n] = x@We1[:, :256]^T + b_e1 (32 tiles)
__global__ __launch_bounds__(256) void gixk(char* ws, const float* bih, const float* b_e1) {
  __shared__ u16 lA[64 * 256];
  int t = blockIdx.x;
  int tid = threadIdx.x, wave = tid >> 6, lane = tid & 63;
  const int cl = lane & 15, rb = (lane >> 4) << 2;
  const u16* xemb = (const u16*)(ws + OFF_XEMB);
  const u16* wih = (const u16*)(ws + OFF_WIH);
  const u16* we1 = (const u16*)(ws + OFF_WE1);
  u16* gix = (u16*)(ws + OFF_GIX);
  u16* c1x = (u16*)(ws + OFF_C1X);
  fill_lds(lA, 256, xemb + (size_t)t * NB * XDI, 256, xemb, 256);
  __syncthreads();
  for (int ct = wave; ct < 128; ct += 4) {
    f32x4 acc[4];
    acc[0] = acc[1] = acc[2] = acc[3] = (f32x4){0.f, 0.f, 0.f, 0.f};
    if (ct < 96) {
      mm_tile(acc, lA, 256, 0, wih, 384, ct * 16, 256, lane);
      int col = ct * 16 + cl;
      float bv = bih[col];
      u16* dst = gix + ((size_t)t * 1536 + col) * 64;
#pragma unroll
      for (int m = 0; m < 4; ++m) {
        u64 o = (u64)f2b(acc[m][0] + bv) | ((u64)f2b(acc[m][1] + bv) << 16)
              | ((u64)f2b(acc[m][2] + bv) << 32) | ((u64)f2b(acc[m][3] + bv) << 48);
        *(u64*)(dst + (m << 4) + rb) = o;
      }
    } else {
      int c0 = (ct - 96) * 16;
      mm_tile(acc, lA, 256, 0, we1, 768, c0, 256, lane);
      int col = c0 + cl;
      float bv = b_e1[col];
      u16* dst = c1x + ((size_t)t * 512 + col) * 64;
#pragma unroll
      for (int m = 0; m < 4; ++m) {
        u64 o = (u64)f2b(acc[m][0] + bv) | ((u64)f2b(acc[m][1] + bv) << 16)
              | ((u64)f2b(acc[m][2] + bv) << 32) | ((u64)f2b(acc[m][3] + bv) << 48);
        *(u64*)(dst + (m << 4) + rb) = o;
      }
    }
  }
}

// ---------------- phase B: weight-stationary recurrence, counter handoffs ----------------
// R12 structure; exchange reads sc0-only (XCD-L2 shared), c1/e in 64-deep t-rings.
__global__ __launch_bounds__(512, 1) void phaseB(
    char* ws, const float* __restrict__ eps,
    const float* __restrict__ b_e2,
    const float* __restrict__ b_mw, const float* __restrict__ b_sw,
    const float* __restrict__ bhh) {
  __shared__ u16 wsl[59392];                // 116KB weight slices (swizzled)
  __shared__ float ghb[3][64][16];          // gh tiles
  __shared__ float red[3][64][16];          // gi_z tiles
  __shared__ float musp[64][8];             // mu / pre-softplus std
  __shared__ float hold[64][17];            // own h slice (f32, padded)
  __shared__ __align__(16) u16 stg[64][16]; // store-coalescing stage

  u16* wWe1 = wsl;            // [16][768] (cols 256-767 = h part used)
  u16* wWhh = wsl + 12288;    // [48][512]
  u16* wWe2 = wsl + 36864;    // [16][512]
  u16* wWms = wsl + 45056;    // [16][512] rows 0-3 mu, 4-7 std
  u16* wWihz = wsl + 53248;   // [48][128]

  const u16* we1 = (const u16*)(ws + OFF_WE1);
  const u16* we2 = (const u16*)(ws + OFF_WE2);
  const u16* wmw = (const u16*)(ws + OFF_WMW);
  const u16* wsw = (const u16*)(ws + OFF_WSW);
  const u16* wih = (const u16*)(ws + OFF_WIH);
  const u16* whh = (const u16*)(ws + OFF_WHH);
  const u16* gix = (const u16*)(ws + OFF_GIX);
  const u16* c1x = (const u16*)(ws + OFF_C1X);
  float* hg = (float*)(ws + OFF_H);
  u16* zall = (u16*)(ws + OFF_ZALL);
  u16* hall = (u16*)(ws + OFF_HALL);
  u16* c1a = (u16*)(ws + OFF_C1A);
  u16* ea  = (u16*)(ws + OFF_EA);
  u32* cC1 = (u32*)(ws + OFF_FLAG);
  u32* cE  = (u32*)(ws + OFF_FLAG + 256);
  u32* cZ  = (u32*)(ws + OFF_FLAG + 512);
  u32* cH  = (u32*)(ws + OFF_FLAG + 768);

  const int tid = threadIdx.x, wave = tid >> 6, lane = tid & 63;
  const int cl = lane & 15, kl = (lane >> 4) << 3, rb = (lane >> 4) << 2;
  const int sl = blockIdx.x;
  const int mt = wave & 3;
  const int arow = mt * 16 + cl;

  // ---- preload weight slices into LDS ----
  for (int c = tid; c < 1536; c += 512) {
    int r = c / 96, k = (c % 96) << 3;
    ldsW(wWe1, r, 768, k, *(const uint4*)(we1 + (size_t)(sl * 16 + r) * 768 + k));
  }
  for (int c = tid; c < 3072; c += 512) {
    int r = c >> 6, k = (c & 63) << 3;
    int gr = (r >> 4) * 512 + sl * 16 + (r & 15);
    ldsW(wWhh, r, 512, k, *(const uint4*)(whh + (size_t)gr * 512 + k));
  }
  for (int c = tid; c < 1024; c += 512) {
    int r = c >> 6, k = (c & 63) << 3;
    ldsW(wWe2, r, 512, k, *(const uint4*)(we2 + (size_t)(sl * 16 + r) * 512 + k));
  }
  for (int c = tid; c < 1024; c += 512) {
    int r = c >> 6, k = (c & 63) << 3;
    uint4 v = {0, 0, 0, 0};
    if (r < 4)      v = *(const uint4*)(wmw + (size_t)(sl * 4 + r) * 512 + k);
    else if (r < 8) v = *(const uint4*)(wsw + (size_t)(sl * 4 + r - 4) * 512 + k);
    ldsW(wWms, r, 512, k, v);
  }
  for (int c = tid; c < 768; c += 512) {
    int r = c >> 4, k = (c & 15) << 3;
    int gr = (r >> 4) * 512 + sl * 16 + (r & 15);
    ldsW(wWihz, r, 128, k, *(const uint4*)(wih + (size_t)gr * 384 + 256 + k));
  }
  for (int i = tid << 1; i < 1024; i += 1024) {
    int r = i >> 4, c = i & 15;
    float2 hv = *(const float2*)(hg + (size_t)r * 512 + sl * 16 + c);
    hold[r][c] = hv.x;
    hold[r][c + 1] = hv.y;
  }
  // biases
  const float be2 = b_e2[sl * 16 + cl];
  const float bms = (cl < 4) ? b_mw[sl * 4 + cl] : ((cl < 8) ? b_sw[sl * 4 + cl - 4] : 0.f);
  const float bh0 = bhh[sl * 16 + cl];
  const float bh1 = bhh[512 + sl * 16 + cl];
  const float bh2 = bhh[1024 + sl * 16 + cl];
  __syncthreads();

  const f32x4 z4 = {0.f, 0.f, 0.f, 0.f};
  for (int t = 0; t < TT; ++t) {
    const int rs = t & RMSK;
    // ---- S0: prefetch h-independent operands (plain cached) ----
    u64 gx0 = 0, gx1 = 0, cx0 = 0;
    float4 ev4 = {0.f, 0.f, 0.f, 0.f};
    if (wave < 4) {
      cx0 = *(const u64*)(c1x + ((size_t)t * 512 + sl * 16 + cl) * 64 + mt * 16 + rb);
      gx0 = *(const u64*)(gix + ((size_t)t * 1536 + sl * 16 + cl) * 64 + mt * 16 + rb);
    } else {
      gx0 = *(const u64*)(gix + ((size_t)t * 1536 + 512 + sl * 16 + cl) * 64 + mt * 16 + rb);
      gx1 = *(const u64*)(gix + ((size_t)t * 1536 + 1024 + sl * 16 + cl) * 64 + mt * 16 + rb);
    }
    if (wave == 0)
      ev4 = *(const float4*)(eps + (size_t)lane * (TT * ZDI) + (size_t)t * ZDI + sl * 4);

    // ---- S1: wait h(t); c1 slice (w0-3) / gh tiles (w4-7) ----
    pollc(cH, tid, 32u * (u32)t);
    u32x4 hf[16];
    ld16_l2(hall + ((size_t)t * NB + arow) * HDI + kl, hf);
    if (wave < 4) {
      f32x4 a = unpk4(cx0);   // x-part + bias precomputed
#pragma unroll
      for (int c = 0; c < 16; ++c)
        a = MFMA16(*(const bf16x8*)&hf[c], *ldsB(wWe1, cl, 768, 256 + c * 32 + kl), a);
#pragma unroll
      for (int j = 0; j < 4; ++j)
        stg[mt * 16 + rb + j][cl] = f2b(fmaxf(a[j], 0.f));
      if (lane < 32) {
        int row = mt * 16 + (lane >> 1), half = lane & 1;
        u32x4 v = *(const u32x4*)&stg[row][half * 8];
        st16B_c(c1a + ((size_t)rs * NB + row) * 512 + sl * 16 + half * 8, v);
      }
    }
    drain_vm();
    __syncthreads();
    postc(cC1, tid);
    if (wave >= 4) {  // gh overlaps other WGs' detect latency
      f32x4 g0 = z4, g1 = z4, g2 = z4;
#pragma unroll
      for (int c = 0; c < 16; ++c) {
        bf16x8 af = *(const bf16x8*)&hf[c];
        g0 = MFMA16(af, *ldsB(wWhh, cl, 512, c * 32 + kl), g0);
        g1 = MFMA16(af, *ldsB(wWhh, 16 + cl, 512, c * 32 + kl), g1);
        g2 = MFMA16(af, *ldsB(wWhh, 32 + cl, 512, c * 32 + kl), g2);
      }
#pragma unroll
      for (int j = 0; j < 4; ++j) {
        ghb[0][mt * 16 + rb + j][cl] = g0[j] + bh0;
        ghb[1][mt * 16 + rb + j][cl] = g1[j] + bh1;
        ghb[2][mt * 16 + rb + j][cl] = g2[j] + bh2;
      }
    }

    // ---- S2: e = relu(c1 @ We2^T + b2) ----
    pollc(cC1, tid, 32u * (u32)(t + 1));
    if (wave < 4) {
      u32x4 cf[16];
      ld16_l2(c1a + ((size_t)rs * NB + arow) * 512 + kl, cf);
      f32x4 a = z4;
#pragma unroll
      for (int c = 0; c < 16; ++c)
        a = MFMA16(*(const bf16x8*)&cf[c], *ldsB(wWe2, cl, 512, c * 32 + kl), a);
#pragma unroll
      for (int j = 0; j < 4; ++j)
        stg[mt * 16 + rb + j][cl] = f2b(fmaxf(a[j] + be2, 0.f));
      if (lane < 32) {
        int row = mt * 16 + (lane >> 1), half = lane & 1;
        u32x4 v = *(const u32x4*)&stg[row][half * 8];
        st16B_c(ea + ((size_t)rs * NB + row) * 512 + sl * 16 + half * 8, v);
      }
    }
    drain_vm();
    __syncthreads();
    postc(cE, tid);

    // ---- S3: mu/std -> z ----
    pollc(cE, tid, 32u * (u32)(t + 1));
    if (wave < 4) {
      u32x4 ef[16];
      ld16_l2(ea + ((size_t)rs * NB + arow) * 512 + kl, ef);
      f32x4 a = z4;
#pragma unroll
      for (int c = 0; c < 16; ++c)
        a = MFMA16(*(const bf16x8*)&ef[c], *ldsB(wWms, cl, 512, c * 32 + kl), a);
      if (cl < 8) {
#pragma unroll
        for (int j = 0; j < 4; ++j) musp[mt * 16 + rb + j][cl] = a[j] + bms;
      }
    }
    __syncthreads();
    if (wave == 0) {  // one 8B store per row
      int r = lane;
      float m0 = musp[r][0], m1 = musp[r][1], m2 = musp[r][2], m3 = musp[r][3];
      float s0 = musp[r][4], s1 = musp[r][5], s2 = musp[r][6], s3 = musp[r][7];
      float p0 = fmaxf(s0, 0.f) + log1pf(__expf(-fabsf(s0)));
      float p1 = fmaxf(s1, 0.f) + log1pf(__expf(-fabsf(s1)));
      float p2 = fmaxf(s2, 0.f) + log1pf(__expf(-fabsf(s2)));
      float p3 = fmaxf(s3, 0.f) + log1pf(__expf(-fabsf(s3)));
      float z0 = ev4.x * p0 + m0, z1 = ev4.y * p1 + m1;
      float z2 = ev4.z * p2 + m2, z3 = ev4.w * p3 + m3;
      u64 pk = (u64)f2b2(z0, z1) | ((u64)f2b2(z2, z3) << 32);
      st8B_c(zall + ((size_t)t * NB + r) * ZDI + sl * 4, pk);
    }
    drain_vm();
    __syncthreads();
    postc(cZ, tid);

    // ---- S4: gi_z + gates + h' ----
    pollc(cZ, tid, 32u * (u32)(t + 1));
    u32x4 zf[4];
    ld4_l2(zall + ((size_t)t * NB + arow) * ZDI + kl, zf);
    if (wave < 4) {
      f32x4 a = unpk4(gx0);
#pragma unroll
      for (int c = 0; c < 4; ++c)
        a = MFMA16(*(const bf16x8*)&zf[c], *ldsB(wWihz, cl, 128, c * 32 + kl), a);
#pragma unroll
      for (int j = 0; j < 4; ++j) red[0][mt * 16 + rb + j][cl] = a[j];
    } else {
      f32x4 a0 = unpk4(gx0), a1 = unpk4(gx1);
#pragma unroll
      for (int c = 0; c < 4; ++c) {
        bf16x8 af = *(const bf16x8*)&zf[c];
        a0 = MFMA16(af, *ldsB(wWihz, 16 + cl, 128, c * 32 + kl), a0);
        a1 = MFMA16(af, *ldsB(wWihz, 32 + cl, 128, c * 32 + kl), a1);
      }
#pragma unroll
      for (int j = 0; j < 4; ++j) {
        red[1][mt * 16 + rb + j][cl] = a0[j];
        red[2][mt * 16 + rb + j][cl] = a1[j];
      }
    }
    __syncthreads();
    {
      int r = tid >> 3, c0 = (tid & 7) << 1;
      float rg0 = sigm(red[0][r][c0] + ghb[0][r][c0]);
      float rg1 = sigm(red[0][r][c0 + 1] + ghb[0][r][c0 + 1]);
      float zg0 = sigm(red[1][r][c0] + ghb[1][r][c0]);
      float zg1 = sigm(red[1][r][c0 + 1] + ghb[1][r][c0 + 1]);
      float ng0 = tanhf(red[2][r][c0] + rg0 * ghb[2][r][c0]);
      float ng1 = tanhf(red[2][r][c0 + 1] + rg1 * ghb[2][r][c0 + 1]);
      hold[r][c0]     = (1.f - zg0) * ng0 + zg0 * hold[r][c0];
      hold[r][c0 + 1] = (1.f - zg1) * ng1 + zg1 * hold[r][c0 + 1];
    }
    __syncthreads();   // hold ready
    if (t < TT - 1) {
      if (wave == 0) {  // coalesced h' export: 2x16B per row, wave0 only
        int r = lane;
        const float* hp = &hold[r][0];
        u32x4 w0, w1;
        w0[0] = f2b2(hp[0], hp[1]);   w0[1] = f2b2(hp[2], hp[3]);
        w0[2] = f2b2(hp[4], hp[5]);   w0[3] = f2b2(hp[6], hp[7]);
        w1[0] = f2b2(hp[8], hp[9]);   w1[1] = f2b2(hp[10], hp[11]);
        w1[2] = f2b2(hp[12], hp[13]); w1[3] = f2b2(hp[14], hp[15]);
        u16* dst = hall + ((size_t)(t + 1) * NB + r) * HDI + sl * 16;
        st16B_c(dst, w0);
        st16B_c(dst + 8, w1);
        drain_vm();
      }
      postc(cH, tid);   // tid0 is in wave0: program order after its drain
    } else {
      if (wave == 0) {
        int r = lane;
        float* dst = hg + (size_t)r * 512 + sl * 16;
#pragma unroll
        for (int k = 0; k < 16; k += 4) {
          float4 o = {hold[r][k], hold[r][k + 1], hold[r][k + 2], hold[r][k + 3]};
          *(float4*)(dst + k) = o;
        }
      }
    }
  }
}

// ---------------- phase C: decoder chain + generation loss ----------------
__global__ __launch_bounds__(256, 1) void phaseC(
    char* ws, const float* db1, const float* db2, const float* dmbias,
    const float* genb, const int* ts, float* gpart) {
  __shared__ u16 lA[64 * 640];
  __shared__ u16 lB[64 * 512];
  int rb = blockIdx.x;
  int tid = threadIdx.x, wave = tid >> 6, lane = tid & 63;
  const u16* zall = (const u16*)(ws + OFF_ZALL);
  const u16* hall = (const u16*)(ws + OFF_HALL);
  const u16* wd1 = (const u16*)(ws + OFF_WD1);
  const u16* wd2 = (const u16*)(ws + OFF_WD2);
  const u16* wdm = (const u16*)(ws + OFF_WDM);
  const u16* wgw = (const u16*)(ws + OFF_WGW);

  fill_lds(lA, 640, zall + (size_t)rb * NB * ZDI, 128, hall + (size_t)rb * NB * HDI, 512);
  __syncthreads();
  for (int tile = wave; tile < 32; tile += 4) {
    f32x4 acc[4];
    acc[0] = acc[1] = acc[2] = acc[3] = (f32x4){0.f, 0.f, 0.f, 0.f};
    mm_tile(acc, lA, 640, 0, wd1, 640, tile * 16, 640, lane);
    int col = tile * 16 + (lane & 15);
    float bias = db1[col];
#pragma unroll
    for (int m = 0; m < 4; ++m)
#pragma unroll
      for (int j = 0; j < 4; ++j) {
        int row = (m << 4) + ((lane >> 4) << 2) + j;
        int byte = ((row * 512 + col) << 1) ^ ((row & 7) << 4);
        *(u16*)((char*)lB + byte) = f2b(fmaxf(acc[m][j] + bias, 0.f));
      }
  }
  __syncthreads();
  for (int tile = wave; tile < 32; tile += 4) {
    f32x4 acc[4];
    acc[0] = acc[1] = acc[2] = acc[3] = (f32x4){0.f, 0.f, 0.f, 0.f};
    mm_tile(acc, lB, 512, 0, wd2, 512, tile * 16, 512, lane);
    int col = tile * 16 + (lane & 15);
    float bias = db2[col];
#pragma unroll
    for (int m = 0; m < 4; ++m)
#pragma unroll
      for (int j = 0; j < 4; ++j) {
        int row = (m << 4) + ((lane >> 4) << 2) + j;
        int byte = ((row * 512 + col) << 1) ^ ((row & 7) << 4);
        *(u16*)((char*)lA + byte) = f2b(fmaxf(acc[m][j] + bias, 0.f));
      }
  }
  __syncthreads();
  for (int tile = wave; tile < 16; tile += 4) {
    f32x4 acc[4];
    acc[0] = acc[1] = acc[2] = acc[3] = (f32x4){0.f, 0.f, 0.f, 0.f};
    mm_tile(acc, lA, 512, 0, wdm, 512, tile * 16, 512, lane);
    int col = tile * 16 + (lane & 15);
    float bias = dmbias[col];
#pragma unroll
    for (int m = 0; m < 4; ++m)
#pragma unroll
      for (int j = 0; j < 4; ++j) {
        int row = (m << 4) + ((lane >> 4) << 2) + j;
        float v = 1.f / (1.f + __expf(-(acc[m][j] + bias)));
        int byte = ((row * 256 + col) << 1) ^ ((row & 7) << 4);
        *(u16*)((char*)lB + byte) = f2b(v);
      }
  }
  __syncthreads();
  float mr[16], sr[16], cap[16];
  int tg[16];
#pragma unroll
  for (int q = 0; q < 16; ++q) {
    int r = ((q >> 2) << 4) + ((lane >> 4) << 2) + (q & 3);
    tg[q] = ts[r * TT + rb];
    mr[q] = -1e30f; sr[q] = 0.f; cap[q] = -1e30f;
  }
  for (int ct = wave; ct < 625; ct += 4) {
    f32x4 acc[4];
    acc[0] = acc[1] = acc[2] = acc[3] = (f32x4){0.f, 0.f, 0.f, 0.f};
    mm_tile(acc, lB, 256, 0, wgw, 256, ct * 16, 256, lane);
    int colw = ct * 16 + (lane & 15);
    float gbv = genb[colw];
#pragma unroll
    for (int mi = 0; mi < 4; ++mi)
#pragma unroll
      for (int j = 0; j < 4; ++j) {
        int q = (mi << 2) + j;
        float v = acc[mi][j] + gbv;
        if (colw == tg[q]) cap[q] = v;
        float mn = fmaxf(mr[q], v);
        sr[q] = sr[q] * __expf(mr[q] - mn) + __expf(v - mn);
        mr[q] = mn;
      }
  }
#pragma unroll
  for (int d = 1; d < 16; d <<= 1) {
#pragma unroll
    for (int q = 0; q < 16; ++q) {
      float mo = __shfl_xor(mr[q], d);
      float so = __shfl_xor(sr[q], d);
      float co = __shfl_xor(cap[q], d);
      float mn = fmaxf(mr[q], mo);
      sr[q] = sr[q] * __expf(mr[q] - mn) + so * __expf(mo - mn);
      mr[q] = mn;
      cap[q] = fmaxf(cap[q], co);
    }
  }
  float* sc = (float*)lA;
  if ((lane & 15) == 0) {
    int g = lane >> 4;
#pragma unroll
    for (int q = 0; q < 16; ++q) {
      int r = ((q >> 2) << 4) + (g << 2) + (q & 3);
      sc[wave * 64 + r] = mr[q];
      sc[256 + wave * 64 + r] = sr[q];
      sc[512 + wave * 64 + r] = cap[q];
    }
  }
  __syncthreads();
  if (tid < 64) {
    float M = -1e30f, S = 0.f, C = -1e30f;
#pragma unroll
    for (int w = 0; w < 4; ++w) {
      float m = sc[w * 64 + tid], s = sc[256 + w * 64 + tid], c = sc[512 + w * 64 + tid];
      float mn = fmaxf(M, m);
      S = S * __expf(M - mn) + s * __expf(m - mn);
      M = mn;
      C = fmaxf(C, c);
    }
    float lossr = M + __logf(S) - C;
    for (int d = 1; d < 64; d <<= 1) lossr += __shfl_xor(lossr, d);
    if (tid == 0) gpart[rb] = lossr;
  }
}

// ---------------- final reduce + classifier ----------------
__global__ __launch_bounds__(256) void finalk(char* ws, const int* labels,
                                              const float* cw, const float* cb,
                                              const float* gpart, float* out) {
  __shared__ float sred[256];
  __shared__ float cred[64];
  int tid = threadIdx.x;
  sred[tid] = gpart[tid];
  __syncthreads();
  for (int s2 = 128; s2 > 0; s2 >>= 1) {
    if (tid < s2) sred[tid] += sred[tid + s2];
    __syncthreads();
  }
  const float* h = (const float*)(ws + OFF_H);
  if (tid < 64) {
    const float* hrow = h + tid * 512;
    float a0 = cb[0], a1 = cb[1], a2 = cb[2], a3 = cb[3];
    for (int k = 0; k < 512; k += 4) {
      float4 hv = *(const float4*)(hrow + k);
      float4 w0 = *(const float4*)(cw + 0 * 512 + k);
      float4 w1 = *(const float4*)(cw + 1 * 512 + k);
      float4 w2 = *(const float4*)(cw + 2 * 512 + k);
      float4 w3 = *(const float4*)(cw + 3 * 512 + k);
      a0 += hv.x * w0.x + hv.y * w0.y + hv.z * w0.z + hv.w * w0.w;
      a1 += hv.x * w1.x + hv.y * w1.y + hv.z * w1.z + hv.w * w1.w;
      a2 += hv.x * w2.x + hv.y * w2.y + hv.z * w2.z + hv.w * w2.w;
      a3 += hv.x * w3.x + hv.y * w3.y + hv.z * w3.z + hv.w * w3.w;
    }
    float M = fmaxf(fmaxf(a0, a1), fmaxf(a2, a3));
    float S = __expf(a0 - M) + __expf(a1 - M) + __expf(a2 - M) + __expf(a3 - M);
    int lb = labels[tid];
    float lg = (lb == 0) ? a0 : (lb == 1) ? a1 : (lb == 2) ? a2 : a3;
    cred[tid] = M + __logf(S) - lg;
  }
  __syncthreads();
  if (tid == 0) {
    float cs = 0.f;
    for (int i = 0; i < 64; ++i) cs += cred[i];
    out[0] = sred[0] / 16384.f;
    out[1] = cs / 64.f;
  }
}

extern "C" void kernel_launch(void* const* d_in, const int* in_sizes, int n_in,
                              void* d_out, int out_size, void* d_ws, size_t ws_size,
                              hipStream_t stream) {
  (void)in_sizes; (void)n_in; (void)out_size; (void)ws_size;
  char* ws = (char*)d_ws;
  const int* xs = (const int*)d_in[0];
  const int* ts = (const int*)d_in[1];
  const int* labels = (const int*)d_in[2];
  const int* wflag = (const int*)d_in[3];
  const float* eps = (const float*)d_in[4];
  const float* hnoise = (const float*)d_in[5];
  const float* embed = (const float*)d_in[6];
  const float* e_w1 = (const float*)d_in[7];
  const float* e_b1 = (const float*)d_in[8];
  const float* e_w2 = (const float*)d_in[9];
  const float* e_b2 = (const float*)d_in[10];
  const float* m_w = (const float*)d_in[11];
  const float* m_b = (const float*)d_in[12];
  const float* s_w = (const float*)d_in[13];
  const float* s_b = (const float*)d_in[14];
  const float* d_w1 = (const float*)d_in[15];
  const float* d_b1 = (const float*)d_in[16];
  const float* d_w2 = (const float*)d_in[17];
  const float* d_b2 = (const float*)d_in[18];
  const float* dm_w = (const float*)d_in[19];
  const float* dm_b = (const float*)d_in[20];
  const float* g_ih = (const float*)d_in[21];
  const float* g_hh = (const float*)d_in[22];
  const float* g_bih = (const float*)d_in[23];
  const float* g_bhh = (const float*)d_in[24];
  const float* gw = (const float*)d_in[25];
  const float* gb = (const float*)d_in[26];
  const float* cw = (const float*)d_in[27];
  const float* cb = (const float*)d_in[28];
  const float* hw = (const float*)d_in[29];
  const float* hb0 = (const float*)d_in[30];

  hipMemsetAsync(ws + OFF_FLAG, 0, 1024, stream);

  ConvArgs ca;
  const float* srcs[10] = {e_w1, e_w2, m_w, s_w, d_w1, d_w2, dm_w, g_ih, g_hh, gw};
  unsigned long long doffs[10] = {OFF_WE1, OFF_WE2, OFF_WMW, OFF_WSW, OFF_WD1,
                                  OFF_WD2, OFF_WDM, OFF_WIH, OFF_WHH, OFF_WGW};
  int ns[10] = {393216, 262144, 65536, 65536, 327680, 262144, 131072, 589824, 786432, 2560000};
  for (int i = 0; i < 10; ++i) { ca.s[i] = srcs[i]; ca.doff[i] = doffs[i]; ca.n[i] = ns[i]; }

  wconv<<<dim3(1250, 10), 256, 0, stream>>>(ws, ca);
  gatherx<<<2048, 256, 0, stream>>>(ws, xs, embed);
  h0init<<<128, 256, 0, stream>>>(ws, labels, wflag, hnoise, hw, hb0);
  gixk<<<256, 256, 0, stream>>>(ws, g_bih, e_b1);
  phaseB<<<32, 512, 0, stream>>>(ws, eps, e_b2, m_b, s_b, g_bhh);
  phaseC<<<256, 256, 0, stream>>>(ws, d_b1, d_b2, dm_b, gb, ts, (float*)(ws + OFF_GPART));
  finalk<<<1, 256, 0, stream>>>(ws, labels, cw, cb, (const float*)(ws + OFF_GPART), (float*)d_out);
}

// Round 14
// 3299.496 us; speedup vs baseline: 2.8305x; 1.4204x over previous
//
#include <hip/hip_runtime.h>

typedef unsigned short u16;
typedef unsigned int u32;
typedef unsigned long long u64;
using bf16x8 = __attribute__((ext_vector_type(8))) short;
using f32x4  = __attribute__((ext_vector_type(4))) float;
using u32x4  = __attribute__((ext_vector_type(4))) unsigned int;

#define TT   256
#define NB   64
#define XDI  256
#define HDI  512
#define ZDI  128
#define VV   10000
#define RING 64
#define RMSK 63

// ---- workspace byte offsets ----
#define OFF_WE1   512ull        // [512][768] bf16
#define OFF_WE2   786944ull     // [512][512] bf16
#define OFF_WMW   1311232ull    // [128][512] bf16
#define OFF_WSW   1442304ull    // [128][512] bf16
#define OFF_WD1   1573376ull    // [512][640] bf16
#define OFF_WD2   2228736ull    // [512][512] bf16
#define OFF_WDM   2753024ull    // [256][512] bf16
#define OFF_WIH   3015168ull    // [1536][384] bf16
#define OFF_WHH   4194816ull    // [1536][512] bf16
#define OFF_WGW   5767680ull    // [10000][256] bf16
#define OFF_XEMB  10887680ull   // [256][64][256] bf16
#define OFF_H     19276288ull   // [64][512] f32
#define OFF_ZALL  19997184ull   // [256*64][128] bf16 (t-indexed z exchange)
#define OFF_HALL  24191488ull   // [256*64][512] bf16 (t-indexed h exchange)
#define OFF_GPART 40968704ull   // [256] f32
#define OFF_FLAG  41100800ull   // [4 chains][4 counters], 256B apart
#define OFF_GIX   41102848ull   // [256][1536][64] bf16 (x-part of gi + bih)
#define OFF_C1X   91766784ull   // [256][512][64] bf16 (x-part of c1 + b_e1)
#define OFF_C1A   108544000ull  // [4][RING][16][512] bf16 c1 rings (4x1MB)
#define OFF_EA    112738304ull  // [4][RING][16][512] bf16 e rings (4x1MB)

__device__ __forceinline__ u16 f2b(float f) {
  union { float f; u32 u; } v; v.f = f;
  u32 r = v.u + 0x7fffu + ((v.u >> 16) & 1u);
  return (u16)(r >> 16);
}
__device__ __forceinline__ u32 f2b2(float a, float b) {
  return (u32)f2b(a) | ((u32)f2b(b) << 16);
}
__device__ __forceinline__ float b2f(u16 x) {
  union { u32 u; float f; } v; v.u = ((u32)x) << 16; return v.f;
}

#define MFMA16(a, b, c) __builtin_amdgcn_mfma_f32_16x16x32_bf16(a, b, c, 0, 0, 0)

__device__ __forceinline__ const bf16x8* ldsB(const u16* base, int r, int K, int k) {
  return (const bf16x8*)((const char*)base + (((r * K + k) << 1) ^ ((r & 7) << 4)));
}
__device__ __forceinline__ void ldsW(u16* base, int r, int K, int k, uint4 v) {
  *(uint4*)((char*)base + (((r * K + k) << 1) ^ ((r & 7) << 4))) = v;
}

__device__ __forceinline__ void fill_lds(u16* lds, int Ktot,
                                         const u16* s0, int K0,
                                         const u16* s1, int K1) {
  int kch = Ktot >> 3;
  int nch = 64 * kch;
  for (int i = threadIdx.x; i < nch; i += 256) {
    int row = i / kch;
    int k = (i - row * kch) << 3;
    const u16* src = (k < K0) ? (s0 + row * K0 + k) : (s1 + row * K1 + (k - K0));
    uint4 v = *(const uint4*)src;
    ldsW(lds, row, Ktot, k, v);
  }
}

__device__ __forceinline__ void mm_tile(f32x4 acc[4], const u16* lds, int ldsStride, int ldsK0,
                                        const u16* __restrict__ W, int Kw, int wcol0,
                                        int Klen, int lane) {
  const int kl = (lane >> 4) << 3;
  const int cl = lane & 15;
  const u16* wp = W + (size_t)(wcol0 + cl) * Kw;
  for (int kc = 0; kc < Klen; kc += 32) {
    int k = kc + kl;
    bf16x8 b = *(const bf16x8*)(wp + k);
#pragma unroll
    for (int m = 0; m < 4; ++m)
      acc[m] = MFMA16(*ldsB(lds, (m << 4) + cl, ldsStride, ldsK0 + k), b, acc[m]);
  }
}

// ---- MALL-coherent exchange ops (R4/R7-proven encodings) ----
__device__ __forceinline__ void ld16_c(const void* p, u32x4* f) {
  asm volatile(
      "global_load_dwordx4 %0, %16, off sc0 sc1\n\t"
      "global_load_dwordx4 %1, %16, off offset:64 sc0 sc1\n\t"
      "global_load_dwordx4 %2, %16, off offset:128 sc0 sc1\n\t"
      "global_load_dwordx4 %3, %16, off offset:192 sc0 sc1\n\t"
      "global_load_dwordx4 %4, %16, off offset:256 sc0 sc1\n\t"
      "global_load_dwordx4 %5, %16, off offset:320 sc0 sc1\n\t"
      "global_load_dwordx4 %6, %16, off offset:384 sc0 sc1\n\t"
      "global_load_dwordx4 %7, %16, off offset:448 sc0 sc1\n\t"
      "global_load_dwordx4 %8, %16, off offset:512 sc0 sc1\n\t"
      "global_load_dwordx4 %9, %16, off offset:576 sc0 sc1\n\t"
      "global_load_dwordx4 %10, %16, off offset:640 sc0 sc1\n\t"
      "global_load_dwordx4 %11, %16, off offset:704 sc0 sc1\n\t"
      "global_load_dwordx4 %12, %16, off offset:768 sc0 sc1\n\t"
      "global_load_dwordx4 %13, %16, off offset:832 sc0 sc1\n\t"
      "global_load_dwordx4 %14, %16, off offset:896 sc0 sc1\n\t"
      "global_load_dwordx4 %15, %16, off offset:960 sc0 sc1\n\t"
      "s_waitcnt vmcnt(0)"
      : "=&v"(f[0]), "=&v"(f[1]), "=&v"(f[2]), "=&v"(f[3]),
        "=&v"(f[4]), "=&v"(f[5]), "=&v"(f[6]), "=&v"(f[7]),
        "=&v"(f[8]), "=&v"(f[9]), "=&v"(f[10]), "=&v"(f[11]),
        "=&v"(f[12]), "=&v"(f[13]), "=&v"(f[14]), "=&v"(f[15])
      : "v"(p) : "memory");
}
__device__ __forceinline__ void ld4_c(const void* p, u32x4* f) {
  asm volatile(
      "global_load_dwordx4 %0, %4, off sc0 sc1\n\t"
      "global_load_dwordx4 %1, %4, off offset:64 sc0 sc1\n\t"
      "global_load_dwordx4 %2, %4, off offset:128 sc0 sc1\n\t"
      "global_load_dwordx4 %3, %4, off offset:192 sc0 sc1\n\t"
      "s_waitcnt vmcnt(0)"
      : "=&v"(f[0]), "=&v"(f[1]), "=&v"(f[2]), "=&v"(f[3])
      : "v"(p) : "memory");
}
__device__ __forceinline__ void st16B_c(void* p, u32x4 v) {
  asm volatile("global_store_dwordx4 %0, %1, off sc0 sc1" :: "v"(p), "v"(v) : "memory");
}
__device__ __forceinline__ void st8B_c(void* p, u64 v) {
  asm volatile("global_store_dwordx2 %0, %1, off sc0 sc1" :: "v"(p), "v"(v) : "memory");
}
__device__ __forceinline__ void drain_vm() {
  asm volatile("s_waitcnt vmcnt(0)" ::: "memory");
}
__device__ __forceinline__ void postc(u32* cnt, int tid) {
  if (tid == 0)
    __hip_atomic_fetch_add(cnt, 1u, __ATOMIC_RELAXED, __HIP_MEMORY_SCOPE_AGENT);
}
__device__ __forceinline__ void pollc(u32* cnt, int tid, u32 target) {
  if (tid == 0) {
    while (__hip_atomic_load(cnt, __ATOMIC_RELAXED, __HIP_MEMORY_SCOPE_AGENT) < target)
      __builtin_amdgcn_s_sleep(1);
  }
  __syncthreads();
}
__device__ __forceinline__ f32x4 unpk4(u64 g) {
  f32x4 a;
#pragma unroll
  for (int j = 0; j < 4; ++j) a[j] = b2f((u16)(g >> (16 * j)));
  return a;
}
__device__ __forceinline__ float sigm(float x) { return 1.f / (1.f + __expf(-x)); }

// ---------------- prep kernels ----------------
struct ConvArgs { const float* s[10]; unsigned long long doff[10]; int n[10]; };

__global__ __launch_bounds__(256) void wconv(char* ws, ConvArgs a) {
  int seg = blockIdx.y;
  const float* s = a.s[seg];
  u16* d = (u16*)(ws + a.doff[seg]);
  int n = a.n[seg];
  int i = (blockIdx.x * 256 + threadIdx.x) * 8;
  if (i < n) {
    float4 v0 = *(const float4*)(s + i);
    float4 v1 = *(const float4*)(s + i + 4);
    uint4 o;
    o.x = f2b2(v0.x, v0.y); o.y = f2b2(v0.z, v0.w);
    o.z = f2b2(v1.x, v1.y); o.w = f2b2(v1.z, v1.w);
    *(uint4*)(d + i) = o;
  }
}

__global__ __launch_bounds__(256) void gatherx(char* ws, const int* xs, const float* embed) {
  u16* xemb = (u16*)(ws + OFF_XEMB);
  int i = blockIdx.x * 256 + threadIdx.x;
  int t = i >> 11;
  int rr = i & 2047;
  int n = rr >> 5;
  int k = (rr & 31) << 3;
  int idx = xs[n * TT + t];
  const float* src = embed + (size_t)idx * XDI + k;
  float4 v0 = *(const float4*)src;
  float4 v1 = *(const float4*)(src + 4);
  uint4 o;
  o.x = f2b2(v0.x, v0.y); o.y = f2b2(v0.z, v0.w);
  o.z = f2b2(v1.x, v1.y); o.w = f2b2(v1.z, v1.w);
  *(uint4*)(xemb + ((size_t)t * NB + n) * XDI + k) = o;
}

__global__ __launch_bounds__(256) void h0init(char* ws, const int* labels, const int* wflag,
                                              const float* hnoise, const float* hw, const float* hb0) {
  int i = blockIdx.x * 256 + threadIdx.x;  // 32768
  int n = i >> 9, c = i & 511;
  float v = (float)labels[n] * hw[c] + hb0[c];
  if (wflag[0]) v += hnoise[i];
  ((float*)(ws + OFF_H))[i] = v;
  ((u16*)(ws + OFF_HALL))[i] = f2b(v);   // hall[0] = h0
}

// gi_x[t][c][n] (96 tiles) + c1_x[t][c][n] = x@We1[:, :256]^T + b_e1 (32 tiles)
__global__ __launch_bounds__(256) void gixk(char* ws, const float* bih, const float* b_e1) {
  __shared__ u16 lA[64 * 256];
  int t = blockIdx.x;
  int tid = threadIdx.x, wave = tid >> 6, lane = tid & 63;
  const int cl = lane & 15, rb = (lane >> 4) << 2;
  const u16* xemb = (const u16*)(ws + OFF_XEMB);
  const u16* wih = (const u16*)(ws + OFF_WIH);
  const u16* we1 = (const u16*)(ws + OFF_WE1);
  u16* gix = (u16*)(ws + OFF_GIX);
  u16* c1x = (u16*)(ws + OFF_C1X);
  fill_lds(lA, 256, xemb + (size_t)t * NB * XDI, 256, xemb, 256);
  __syncthreads();
  for (int ct = wave; ct < 128; ct += 4) {
    f32x4 acc[4];
    acc[0] = acc[1] = acc[2] = acc[3] = (f32x4){0.f, 0.f, 0.f, 0.f};
    if (ct < 96) {
      mm_tile(acc, lA, 256, 0, wih, 384, ct * 16, 256, lane);
      int col = ct * 16 + cl;
      float bv = bih[col];
      u16* dst = gix + ((size_t)t * 1536 + col) * 64;
#pragma unroll
      for (int m = 0; m < 4; ++m) {
        u64 o = (u64)f2b(acc[m][0] + bv) | ((u64)f2b(acc[m][1] + bv) << 16)
              | ((u64)f2b(acc[m][2] + bv) << 32) | ((u64)f2b(acc[m][3] + bv) << 48);
        *(u64*)(dst + (m << 4) + rb) = o;
      }
    } else {
      int c0 = (ct - 96) * 16;
      mm_tile(acc, lA, 256, 0, we1, 768, c0, 256, lane);
      int col = c0 + cl;
      float bv = b_e1[col];
      u16* dst = c1x + ((size_t)t * 512 + col) * 64;
#pragma unroll
      for (int m = 0; m < 4; ++m) {
        u64 o = (u64)f2b(acc[m][0] + bv) | ((u64)f2b(acc[m][1] + bv) << 16)
              | ((u64)f2b(acc[m][2] + bv) << 32) | ((u64)f2b(acc[m][3] + bv) << 48);
        *(u64*)(dst + (m << 4) + rb) = o;
      }
    }
  }
}

// ---------------- phase B: 4 independent 16-row chains x 32 slices ----------------
// 128 WGs x 256 threads. Chain g rows g*16..+15. Wave0: c1->e->ms->z chain;
// waves 1-3: gh gates; waves 0-2: gi_z gates. Per-chain counters.
__global__ __launch_bounds__(256, 1) void phaseB(
    char* ws, const float* __restrict__ eps,
    const float* __restrict__ b_e2,
    const float* __restrict__ b_mw, const float* __restrict__ b_sw,
    const float* __restrict__ bhh) {
  __shared__ u16 wsl[59392];                // 116KB weight slices (swizzled)
  __shared__ float ghb[3][16][16];
  __shared__ float red[3][16][16];
  __shared__ float musp[16][8];
  __shared__ float hold[16][17];
  __shared__ __align__(16) u16 stg[16][16];

  u16* wWe1 = wsl;            // [16][768] (h-part cols 256-767 used)
  u16* wWhh = wsl + 12288;    // [48][512]
  u16* wWe2 = wsl + 36864;    // [16][512]
  u16* wWms = wsl + 45056;    // [16][512] rows 0-3 mu, 4-7 std
  u16* wWihz = wsl + 53248;   // [48][128]

  const u16* we1 = (const u16*)(ws + OFF_WE1);
  const u16* we2 = (const u16*)(ws + OFF_WE2);
  const u16* wmw = (const u16*)(ws + OFF_WMW);
  const u16* wsw = (const u16*)(ws + OFF_WSW);
  const u16* wih = (const u16*)(ws + OFF_WIH);
  const u16* whh = (const u16*)(ws + OFF_WHH);
  const u16* gix = (const u16*)(ws + OFF_GIX);
  const u16* c1x = (const u16*)(ws + OFF_C1X);
  float* hg = (float*)(ws + OFF_H);
  u16* zall = (u16*)(ws + OFF_ZALL);
  u16* hall = (u16*)(ws + OFF_HALL);

  const int tid = threadIdx.x, wave = tid >> 6, lane = tid & 63;
  const int cl = lane & 15, kl = (lane >> 4) << 3, rb = (lane >> 4) << 2;
  const int g = blockIdx.x >> 5, sl = blockIdx.x & 31;
  const int r0 = g << 4;

  u16* c1g = (u16*)(ws + OFF_C1A) + (size_t)g * (RING * 16 * 512);
  u16* eg  = (u16*)(ws + OFF_EA)  + (size_t)g * (RING * 16 * 512);
  u32* cC1 = (u32*)(ws + OFF_FLAG + (size_t)g * 1024);
  u32* cE  = (u32*)((char*)cC1 + 256);
  u32* cZ  = (u32*)((char*)cC1 + 512);
  u32* cH  = (u32*)((char*)cC1 + 768);

  // ---- preload weight slices into LDS ----
  for (int c = tid; c < 1536; c += 256) {
    int r = c / 96, k = (c % 96) << 3;
    ldsW(wWe1, r, 768, k, *(const uint4*)(we1 + (size_t)(sl * 16 + r) * 768 + k));
  }
  for (int c = tid; c < 3072; c += 256) {
    int r = c >> 6, k = (c & 63) << 3;
    int gr = (r >> 4) * 512 + sl * 16 + (r & 15);
    ldsW(wWhh, r, 512, k, *(const uint4*)(whh + (size_t)gr * 512 + k));
  }
  for (int c = tid; c < 1024; c += 256) {
    int r = c >> 6, k = (c & 63) << 3;
    ldsW(wWe2, r, 512, k, *(const uint4*)(we2 + (size_t)(sl * 16 + r) * 512 + k));
  }
  for (int c = tid; c < 1024; c += 256) {
    int r = c >> 6, k = (c & 63) << 3;
    uint4 v = {0, 0, 0, 0};
    if (r < 4)      v = *(const uint4*)(wmw + (size_t)(sl * 4 + r) * 512 + k);
    else if (r < 8) v = *(const uint4*)(wsw + (size_t)(sl * 4 + r - 4) * 512 + k);
    ldsW(wWms, r, 512, k, v);
  }
  for (int c = tid; c < 768; c += 256) {
    int r = c >> 4, k = (c & 15) << 3;
    int gr = (r >> 4) * 512 + sl * 16 + (r & 15);
    ldsW(wWihz, r, 128, k, *(const uint4*)(wih + (size_t)gr * 384 + 256 + k));
  }
  {
    int r = tid >> 4, c = tid & 15;
    hold[r][c] = hg[(size_t)(r0 + r) * 512 + sl * 16 + c];
  }
  // biases
  const float be2 = b_e2[sl * 16 + cl];
  const float bms = (cl < 4) ? b_mw[sl * 4 + cl] : ((cl < 8) ? b_sw[sl * 4 + cl - 4] : 0.f);
  const float bhg = (wave >= 1) ? bhh[(wave - 1) * 512 + sl * 16 + cl] : 0.f;
  __syncthreads();

  const f32x4 z4 = {0.f, 0.f, 0.f, 0.f};
  for (int t = 0; t < TT; ++t) {
    const int rs = t & RMSK;
    // ---- S0: prefetch (plain cached) ----
    u64 gx0 = 0, cx0 = 0;
    float4 ev4 = {0.f, 0.f, 0.f, 0.f};
    if (wave == 0)
      cx0 = *(const u64*)(c1x + ((size_t)t * 512 + sl * 16 + cl) * 64 + r0 + rb);
    if (wave < 3)
      gx0 = *(const u64*)(gix + ((size_t)t * 1536 + wave * 512 + sl * 16 + cl) * 64 + r0 + rb);
    if (wave == 0 && lane < 16)
      ev4 = *(const float4*)(eps + (size_t)(r0 + lane) * (TT * ZDI) + (size_t)t * ZDI + sl * 4);

    // ---- S1: wait h(t); c1 (wave0) / gh gates (waves1-3) ----
    pollc(cH, tid, 32u * (u32)t);
    u32x4 hf[16];
    ld16_c(hall + ((size_t)t * NB + r0 + cl) * HDI + kl, hf);
    if (wave == 0) {
      f32x4 a = unpk4(cx0);   // x-part + b_e1 precomputed
#pragma unroll
      for (int c = 0; c < 16; ++c)
        a = MFMA16(*(const bf16x8*)&hf[c], *ldsB(wWe1, cl, 768, 256 + c * 32 + kl), a);
#pragma unroll
      for (int j = 0; j < 4; ++j)
        stg[rb + j][cl] = f2b(fmaxf(a[j], 0.f));
      if (lane < 32) {
        int row = lane >> 1, half = lane & 1;
        u32x4 v = *(const u32x4*)&stg[row][half * 8];
        st16B_c(c1g + ((size_t)rs * 16 + row) * 512 + sl * 16 + half * 8, v);
      }
      drain_vm();
      postc(cC1, tid);
    } else {
      f32x4 a = z4;
#pragma unroll
      for (int c = 0; c < 16; ++c)
        a = MFMA16(*(const bf16x8*)&hf[c], *ldsB(wWhh, (wave - 1) * 16 + cl, 512, c * 32 + kl), a);
#pragma unroll
      for (int j = 0; j < 4; ++j) ghb[wave - 1][rb + j][cl] = a[j] + bhg;
    }

    // ---- S2: e = relu(c1 @ We2^T + b2) (wave0) ----
    pollc(cC1, tid, 32u * (u32)(t + 1));
    if (wave == 0) {
      u32x4 cf[16];
      ld16_c(c1g + ((size_t)rs * 16 + cl) * 512 + kl, cf);
      f32x4 a = z4;
#pragma unroll
      for (int c = 0; c < 16; ++c)
        a = MFMA16(*(const bf16x8*)&cf[c], *ldsB(wWe2, cl, 512, c * 32 + kl), a);
#pragma unroll
      for (int j = 0; j < 4; ++j)
        stg[rb + j][cl] = f2b(fmaxf(a[j] + be2, 0.f));
      if (lane < 32) {
        int row = lane >> 1, half = lane & 1;
        u32x4 v = *(const u32x4*)&stg[row][half * 8];
        st16B_c(eg + ((size_t)rs * 16 + row) * 512 + sl * 16 + half * 8, v);
      }
      drain_vm();
      postc(cE, tid);
    }

    // ---- S3: mu/std -> z (wave0) ----
    pollc(cE, tid, 32u * (u32)(t + 1));
    if (wave == 0) {
      u32x4 ef[16];
      ld16_c(eg + ((size_t)rs * 16 + cl) * 512 + kl, ef);
      f32x4 a = z4;
#pragma unroll
      for (int c = 0; c < 16; ++c)
        a = MFMA16(*(const bf16x8*)&ef[c], *ldsB(wWms, cl, 512, c * 32 + kl), a);
      if (cl < 8) {
#pragma unroll
        for (int j = 0; j < 4; ++j) musp[rb + j][cl] = a[j] + bms;
      }
      if (lane < 16) {
        int r = lane;
        float m0 = musp[r][0], m1 = musp[r][1], m2 = musp[r][2], m3 = musp[r][3];
        float s0 = musp[r][4], s1 = musp[r][5], s2 = musp[r][6], s3 = musp[r][7];
        float p0 = fmaxf(s0, 0.f) + log1pf(__expf(-fabsf(s0)));
        float p1 = fmaxf(s1, 0.f) + log1pf(__expf(-fabsf(s1)));
        float p2 = fmaxf(s2, 0.f) + log1pf(__expf(-fabsf(s2)));
        float p3 = fmaxf(s3, 0.f) + log1pf(__expf(-fabsf(s3)));
        float z0 = ev4.x * p0 + m0, z1 = ev4.y * p1 + m1;
        float z2 = ev4.z * p2 + m2, z3 = ev4.w * p3 + m3;
        u64 pk = (u64)f2b2(z0, z1) | ((u64)f2b2(z2, z3) << 32);
        st8B_c(zall + ((size_t)t * NB + r0 + r) * ZDI + sl * 4, pk);
      }
      drain_vm();
      postc(cZ, tid);
    }

    // ---- S4: gi_z gates (waves0-2) ----
    pollc(cZ, tid, 32u * (u32)(t + 1));
    if (wave < 3) {
      u32x4 zf[4];
      ld4_c(zall + ((size_t)t * NB + r0 + cl) * ZDI + kl, zf);
      f32x4 a = unpk4(gx0);
#pragma unroll
      for (int c = 0; c < 4; ++c)
        a = MFMA16(*(const bf16x8*)&zf[c], *ldsB(wWihz, wave * 16 + cl, 128, c * 32 + kl), a);
#pragma unroll
      for (int j = 0; j < 4; ++j) red[wave][rb + j][cl] = a[j];
    }
    __syncthreads();
    // ---- gates + h' (256 threads, one element each) ----
    {
      int r = tid >> 4, c = tid & 15;
      float rg = sigm(red[0][r][c] + ghb[0][r][c]);
      float zg = sigm(red[1][r][c] + ghb[1][r][c]);
      float ng = tanhf(red[2][r][c] + rg * ghb[2][r][c]);
      hold[r][c] = (1.f - zg) * ng + zg * hold[r][c];
    }
    __syncthreads();
    if (t < TT - 1) {
      if (wave == 0) {
        if (lane < 32) {
          int row = lane >> 1, half = lane & 1;
          const float* hp = &hold[row][half * 8];
          u32x4 w;
          w[0] = f2b2(hp[0], hp[1]); w[1] = f2b2(hp[2], hp[3]);
          w[2] = f2b2(hp[4], hp[5]); w[3] = f2b2(hp[6], hp[7]);
          st16B_c(hall + ((size_t)(t + 1) * NB + r0 + row) * HDI + sl * 16 + half * 8, w);
        }
        drain_vm();
        postc(cH, tid);
      }
    } else {
      int r = tid >> 4, c = tid & 15;
      hg[(size_t)(r0 + r) * 512 + sl * 16 + c] = hold[r][c];
    }
  }
}

// ---------------- phase C: decoder chain + generation loss ----------------
__global__ __launch_bounds__(256, 1) void phaseC(
    char* ws, const float* db1, const float* db2, const float* dmbias,
    const float* genb, const int* ts, float* gpart) {
  __shared__ u16 lA[64 * 640];
  __shared__ u16 lB[64 * 512];
  int rb = blockIdx.x;
  int tid = threadIdx.x, wave = tid >> 6, lane = tid & 63;
  const u16* zall = (const u16*)(ws + OFF_ZALL);
  const u16* hall = (const u16*)(ws + OFF_HALL);
  const u16* wd1 = (const u16*)(ws + OFF_WD1);
  const u16* wd2 = (const u16*)(ws + OFF_WD2);
  const u16* wdm = (const u16*)(ws + OFF_WDM);
  const u16* wgw = (const u16*)(ws + OFF_WGW);

  fill_lds(lA, 640, zall + (size_t)rb * NB * ZDI, 128, hall + (size_t)rb * NB * HDI, 512);
  __syncthreads();
  for (int tile = wave; tile < 32; tile += 4) {
    f32x4 acc[4];
    acc[0] = acc[1] = acc[2] = acc[3] = (f32x4){0.f, 0.f, 0.f, 0.f};
    mm_tile(acc, lA, 640, 0, wd1, 640, tile * 16, 640, lane);
    int col = tile * 16 + (lane & 15);
    float bias = db1[col];
#pragma unroll
    for (int m = 0; m < 4; ++m)
#pragma unroll
      for (int j = 0; j < 4; ++j) {
        int row = (m << 4) + ((lane >> 4) << 2) + j;
        int byte = ((row * 512 + col) << 1) ^ ((row & 7) << 4);
        *(u16*)((char*)lB + byte) = f2b(fmaxf(acc[m][j] + bias, 0.f));
      }
  }
  __syncthreads();
  for (int tile = wave; tile < 32; tile += 4) {
    f32x4 acc[4];
    acc[0] = acc[1] = acc[2] = acc[3] = (f32x4){0.f, 0.f, 0.f, 0.f};
    mm_tile(acc, lB, 512, 0, wd2, 512, tile * 16, 512, lane);
    int col = tile * 16 + (lane & 15);
    float bias = db2[col];
#pragma unroll
    for (int m = 0; m < 4; ++m)
#pragma unroll
      for (int j = 0; j < 4; ++j) {
        int row = (m << 4) + ((lane >> 4) << 2) + j;
        int byte = ((row * 512 + col) << 1) ^ ((row & 7) << 4);
        *(u16*)((char*)lA + byte) = f2b(fmaxf(acc[m][j] + bias, 0.f));
      }
  }
  __syncthreads();
  for (int tile = wave; tile < 16; tile += 4) {
    f32x4 acc[4];
    acc[0] = acc[1] = acc[2] = acc[3] = (f32x4){0.f, 0.f, 0.f, 0.f};
    mm_tile(acc, lA, 512, 0, wdm, 512, tile * 16, 512, lane);
    int col = tile * 16 + (lane & 15);
    float bias = dmbias[col];
#pragma unroll
    for (int m = 0; m < 4; ++m)
#pragma unroll
      for (int j = 0; j < 4; ++j) {
        int row = (m << 4) + ((lane >> 4) << 2) + j;
        float v = 1.f / (1.f + __expf(-(acc[m][j] + bias)));
        int byte = ((row * 256 + col) << 1) ^ ((row & 7) << 4);
        *(u16*)((char*)lB + byte) = f2b(v);
      }
  }
  __syncthreads();
  float mr[16], sr[16], cap[16];
  int tg[16];
#pragma unroll
  for (int q = 0; q < 16; ++q) {
    int r = ((q >> 2) << 4) + ((lane >> 4) << 2) + (q & 3);
    tg[q] = ts[r * TT + rb];
    mr[q] = -1e30f; sr[q] = 0.f; cap[q] = -1e30f;
  }
  for (int ct = wave; ct < 625; ct += 4) {
    f32x4 acc[4];
    acc[0] = acc[1] = acc[2] = acc[3] = (f32x4){0.f, 0.f, 0.f, 0.f};
    mm_tile(acc, lB, 256, 0, wgw, 256, ct * 16, 256, lane);
    int colw = ct * 16 + (lane & 15);
    float gbv = genb[colw];
#pragma unroll
    for (int mi = 0; mi < 4; ++mi)
#pragma unroll
      for (int j = 0; j < 4; ++j) {
        int q = (mi << 2) + j;
        float v = acc[mi][j] + gbv;
        if (colw == tg[q]) cap[q] = v;
        float mn = fmaxf(mr[q], v);
        sr[q] = sr[q] * __expf(mr[q] - mn) + __expf(v - mn);
        mr[q] = mn;
      }
  }
#pragma unroll
  for (int d = 1; d < 16; d <<= 1) {
#pragma unroll
    for (int q = 0; q < 16; ++q) {
      float mo = __shfl_xor(mr[q], d);
      float so = __shfl_xor(sr[q], d);
      float co = __shfl_xor(cap[q], d);
      float mn = fmaxf(mr[q], mo);
      sr[q] = sr[q] * __expf(mr[q] - mn) + so * __expf(mo - mn);
      mr[q] = mn;
      cap[q] = fmaxf(cap[q], co);
    }
  }
  float* sc = (float*)lA;
  if ((lane & 15) == 0) {
    int gq = lane >> 4;
#pragma unroll
    for (int q = 0; q < 16; ++q) {
      int r = ((q >> 2) << 4) + (gq << 2) + (q & 3);
      sc[wave * 64 + r] = mr[q];
      sc[256 + wave * 64 + r] = sr[q];
      sc[512 + wave * 64 + r] = cap[q];
    }
  }
  __syncthreads();
  if (tid < 64) {
    float M = -1e30f, S = 0.f, C = -1e30f;
#pragma unroll
    for (int w = 0; w < 4; ++w) {
      float m = sc[w * 64 + tid], s = sc[256 + w * 64 + tid], c = sc[512 + w * 64 + tid];
      float mn = fmaxf(M, m);
      S = S * __expf(M - mn) + s * __expf(m - mn);
      M = mn;
      C = fmaxf(C, c);
    }
    float lossr = M + __logf(S) - C;
    for (int d = 1; d < 64; d <<= 1) lossr += __shfl_xor(lossr, d);
    if (tid == 0) gpart[rb] = lossr;
  }
}

// ---------------- final reduce + classifier ----------------
__global__ __launch_bounds__(256) void finalk(char* ws, const int* labels,
                                              const float* cw, const float* cb,
                                              const float* gpart, float* out) {
  __shared__ float sred[256];
  __shared__ float cred[64];
  int tid = threadIdx.x;
  sred[tid] = gpart[tid];
  __syncthreads();
  for (int s2 = 128; s2 > 0; s2 >>= 1) {
    if (tid < s2) sred[tid] += sred[tid + s2];
    __syncthreads();
  }
  const float* h = (const float*)(ws + OFF_H);
  if (tid < 64) {
    const float* hrow = h + tid * 512;
    float a0 = cb[0], a1 = cb[1], a2 = cb[2], a3 = cb[3];
    for (int k = 0; k < 512; k += 4) {
      float4 hv = *(const float4*)(hrow + k);
      float4 w0 = *(const float4*)(cw + 0 * 512 + k);
      float4 w1 = *(const float4*)(cw + 1 * 512 + k);
      float4 w2 = *(const float4*)(cw + 2 * 512 + k);
      float4 w3 = *(const float4*)(cw + 3 * 512 + k);
      a0 += hv.x * w0.x + hv.y * w0.y + hv.z * w0.z + hv.w * w0.w;
      a1 += hv.x * w1.x + hv.y * w1.y + hv.z * w1.z + hv.w * w1.w;
      a2 += hv.x * w2.x + hv.y * w2.y + hv.z * w2.z + hv.w * w2.w;
      a3 += hv.x * w3.x + hv.y * w3.y + hv.z * w3.z + hv.w * w3.w;
    }
    float M = fmaxf(fmaxf(a0, a1), fmaxf(a2, a3));
    float S = __expf(a0 - M) + __expf(a1 - M) + __expf(a2 - M) + __expf(a3 - M);
    int lb = labels[tid];
    float lg = (lb == 0) ? a0 : (lb == 1) ? a1 : (lb == 2) ? a2 : a3;
    cred[tid] = M + __logf(S) - lg;
  }
  __syncthreads();
  if (tid == 0) {
    float cs = 0.f;
    for (int i = 0; i < 64; ++i) cs += cred[i];
    out[0] = sred[0] / 16384.f;
    out[1] = cs / 64.f;
  }
}

extern "C" void kernel_launch(void* const* d_in, const int* in_sizes, int n_in,
                              void* d_out, int out_size, void* d_ws, size_t ws_size,
                              hipStream_t stream) {
  (void)in_sizes; (void)n_in; (void)out_size; (void)ws_size;
  char* ws = (char*)d_ws;
  const int* xs = (const int*)d_in[0];
  const int* ts = (const int*)d_in[1];
  const int* labels = (const int*)d_in[2];
  const int* wflag = (const int*)d_in[3];
  const float* eps = (const float*)d_in[4];
  const float* hnoise = (const float*)d_in[5];
  const float* embed = (const float*)d_in[6];
  const float* e_w1 = (const float*)d_in[7];
  const float* e_b1 = (const float*)d_in[8];
  const float* e_w2 = (const float*)d_in[9];
  const float* e_b2 = (const float*)d_in[10];
  const float* m_w = (const float*)d_in[11];
  const float* m_b = (const float*)d_in[12];
  const float* s_w = (const float*)d_in[13];
  const float* s_b = (const float*)d_in[14];
  const float* d_w1 = (const float*)d_in[15];
  const float* d_b1 = (const float*)d_in[16];
  const float* d_w2 = (const float*)d_in[17];
  const float* d_b2 = (const float*)d_in[18];
  const float* dm_w = (const float*)d_in[19];
  const float* dm_b = (const float*)d_in[20];
  const float* g_ih = (const float*)d_in[21];
  const float* g_hh = (const float*)d_in[22];
  const float* g_bih = (const float*)d_in[23];
  const float* g_bhh = (const float*)d_in[24];
  const float* gw = (const float*)d_in[25];
  const float* gb = (const float*)d_in[26];
  const float* cw = (const float*)d_in[27];
  const float* cb = (const float*)d_in[28];
  const float* hw = (const float*)d_in[29];
  const float* hb0 = (const float*)d_in[30];

  hipMemsetAsync(ws + OFF_FLAG, 0, 4096, stream);

  ConvArgs ca;
  const float* srcs[10] = {e_w1, e_w2, m_w, s_w, d_w1, d_w2, dm_w, g_ih, g_hh, gw};
  unsigned long long doffs[10] = {OFF_WE1, OFF_WE2, OFF_WMW, OFF_WSW, OFF_WD1,
                                  OFF_WD2, OFF_WDM, OFF_WIH, OFF_WHH, OFF_WGW};
  int ns[10] = {393216, 262144, 65536, 65536, 327680, 262144, 131072, 589824, 786432, 2560000};
  for (int i = 0; i < 10; ++i) { ca.s[i] = srcs[i]; ca.doff[i] = doffs[i]; ca.n[i] = ns[i]; }

  wconv<<<dim3(1250, 10), 256, 0, stream>>>(ws, ca);
  gatherx<<<2048, 256, 0, stream>>>(ws, xs, embed);
  h0init<<<128, 256, 0, stream>>>(ws, labels, wflag, hnoise, hw, hb0);
  gixk<<<256, 256, 0, stream>>>(ws, g_bih, e_b1);
  phaseB<<<128, 256, 0, stream>>>(ws, eps, e_b2, m_b, s_b, g_bhh);
  phaseC<<<256, 256, 0, stream>>>(ws, d_b1, d_b2, dm_b, gb, ts, (float*)(ws + OFF_GPART));
  finalk<<<1, 256, 0, stream>>>(ws, labels, cw, cb, (const float*)(ws + OFF_GPART), (float*)d_out);
}

// Round 15
// 3162.211 us; speedup vs baseline: 2.9534x; 1.0434x over previous
//
#include <hip/hip_runtime.h>

typedef unsigned short u16;
typedef unsigned int u32;
typedef unsigned long long u64;
using bf16x8 = __attribute__((ext_vector_type(8))) short;
using f32x4  = __attribute__((ext_vector_type(4))) float;
using u32x4  = __attribute__((ext_vector_type(4))) unsigned int;

#define TT   256
#define NB   64
#define XDI  256
#define HDI  512
#define ZDI  128
#define VV   10000
#define RING 64
#define RMSK 63
#define NCH  8      // chains
#define CR   8      // rows per chain

// ---- workspace byte offsets ----
#define OFF_WE1   512ull        // [512][768] bf16
#define OFF_WE2   786944ull     // [512][512] bf16
#define OFF_WMW   1311232ull    // [128][512] bf16
#define OFF_WSW   1442304ull    // [128][512] bf16
#define OFF_WD1   1573376ull    // [512][640] bf16
#define OFF_WD2   2228736ull    // [512][512] bf16
#define OFF_WDM   2753024ull    // [256][512] bf16
#define OFF_WIH   3015168ull    // [1536][384] bf16
#define OFF_WHH   4194816ull    // [1536][512] bf16
#define OFF_WGW   5767680ull    // [10000][256] bf16
#define OFF_XEMB  10887680ull   // [256][64][256] bf16
#define OFF_H     19276288ull   // [64][512] f32
#define OFF_ZALL  19997184ull   // [256*64][128] bf16 (t-indexed z exchange)
#define OFF_HALL  24191488ull   // [256*64][512] bf16 (t-indexed h exchange)
#define OFF_GPART 40968704ull   // [256] f32
#define OFF_FLAG  41100800ull   // [8 chains][4 counters], 256B apart
#define OFF_GIX   41102848ull   // [256][1536][64] bf16 (x-part of gi + bih)
#define OFF_C1X   91766784ull   // [256][512][64] bf16 (x-part of c1 + b_e1)
#define OFF_C1A   108544000ull  // [8][RING][8][512] bf16 c1 rings (4MB)
#define OFF_EA    112738304ull  // [8][RING][8][512] bf16 e rings (4MB)

__device__ __forceinline__ u16 f2b(float f) {
  union { float f; u32 u; } v; v.f = f;
  u32 r = v.u + 0x7fffu + ((v.u >> 16) & 1u);
  return (u16)(r >> 16);
}
__device__ __forceinline__ u32 f2b2(float a, float b) {
  return (u32)f2b(a) | ((u32)f2b(b) << 16);
}
__device__ __forceinline__ float b2f(u16 x) {
  union { u32 u; float f; } v; v.u = ((u32)x) << 16; return v.f;
}

#define MFMA16(a, b, c) __builtin_amdgcn_mfma_f32_16x16x32_bf16(a, b, c, 0, 0, 0)

__device__ __forceinline__ const bf16x8* ldsB(const u16* base, int r, int K, int k) {
  return (const bf16x8*)((const char*)base + (((r * K + k) << 1) ^ ((r & 7) << 4)));
}
__device__ __forceinline__ void ldsW(u16* base, int r, int K, int k, uint4 v) {
  *(uint4*)((char*)base + (((r * K + k) << 1) ^ ((r & 7) << 4))) = v;
}

__device__ __forceinline__ void fill_lds(u16* lds, int Ktot,
                                         const u16* s0, int K0,
                                         const u16* s1, int K1) {
  int kch = Ktot >> 3;
  int nch = 64 * kch;
  for (int i = threadIdx.x; i < nch; i += 256) {
    int row = i / kch;
    int k = (i - row * kch) << 3;
    const u16* src = (k < K0) ? (s0 + row * K0 + k) : (s1 + row * K1 + (k - K0));
    uint4 v = *(const uint4*)src;
    ldsW(lds, row, Ktot, k, v);
  }
}

__device__ __forceinline__ void mm_tile(f32x4 acc[4], const u16* lds, int ldsStride, int ldsK0,
                                        const u16* __restrict__ W, int Kw, int wcol0,
                                        int Klen, int lane) {
  const int kl = (lane >> 4) << 3;
  const int cl = lane & 15;
  const u16* wp = W + (size_t)(wcol0 + cl) * Kw;
  for (int kc = 0; kc < Klen; kc += 32) {
    int k = kc + kl;
    bf16x8 b = *(const bf16x8*)(wp + k);
#pragma unroll
    for (int m = 0; m < 4; ++m)
      acc[m] = MFMA16(*ldsB(lds, (m << 4) + cl, ldsStride, ldsK0 + k), b, acc[m]);
  }
}

// ---- MALL-coherent exchange ops (R4/R7-proven encodings) ----
__device__ __forceinline__ void ld16_c(const void* p, u32x4* f) {
  asm volatile(
      "global_load_dwordx4 %0, %16, off sc0 sc1\n\t"
      "global_load_dwordx4 %1, %16, off offset:64 sc0 sc1\n\t"
      "global_load_dwordx4 %2, %16, off offset:128 sc0 sc1\n\t"
      "global_load_dwordx4 %3, %16, off offset:192 sc0 sc1\n\t"
      "global_load_dwordx4 %4, %16, off offset:256 sc0 sc1\n\t"
      "global_load_dwordx4 %5, %16, off offset:320 sc0 sc1\n\t"
      "global_load_dwordx4 %6, %16, off offset:384 sc0 sc1\n\t"
      "global_load_dwordx4 %7, %16, off offset:448 sc0 sc1\n\t"
      "global_load_dwordx4 %8, %16, off offset:512 sc0 sc1\n\t"
      "global_load_dwordx4 %9, %16, off offset:576 sc0 sc1\n\t"
      "global_load_dwordx4 %10, %16, off offset:640 sc0 sc1\n\t"
      "global_load_dwordx4 %11, %16, off offset:704 sc0 sc1\n\t"
      "global_load_dwordx4 %12, %16, off offset:768 sc0 sc1\n\t"
      "global_load_dwordx4 %13, %16, off offset:832 sc0 sc1\n\t"
      "global_load_dwordx4 %14, %16, off offset:896 sc0 sc1\n\t"
      "global_load_dwordx4 %15, %16, off offset:960 sc0 sc1\n\t"
      "s_waitcnt vmcnt(0)"
      : "=&v"(f[0]), "=&v"(f[1]), "=&v"(f[2]), "=&v"(f[3]),
        "=&v"(f[4]), "=&v"(f[5]), "=&v"(f[6]), "=&v"(f[7]),
        "=&v"(f[8]), "=&v"(f[9]), "=&v"(f[10]), "=&v"(f[11]),
        "=&v"(f[12]), "=&v"(f[13]), "=&v"(f[14]), "=&v"(f[15])
      : "v"(p) : "memory");
}
__device__ __forceinline__ void ld4_c(const void* p, u32x4* f) {
  asm volatile(
      "global_load_dwordx4 %0, %4, off sc0 sc1\n\t"
      "global_load_dwordx4 %1, %4, off offset:64 sc0 sc1\n\t"
      "global_load_dwordx4 %2, %4, off offset:128 sc0 sc1\n\t"
      "global_load_dwordx4 %3, %4, off offset:192 sc0 sc1\n\t"
      "s_waitcnt vmcnt(0)"
      : "=&v"(f[0]), "=&v"(f[1]), "=&v"(f[2]), "=&v"(f[3])
      : "v"(p) : "memory");
}
__device__ __forceinline__ void st16B_c(void* p, u32x4 v) {
  asm volatile("global_store_dwordx4 %0, %1, off sc0 sc1" :: "v"(p), "v"(v) : "memory");
}
__device__ __forceinline__ void st8B_c(void* p, u64 v) {
  asm volatile("global_store_dwordx2 %0, %1, off sc0 sc1" :: "v"(p), "v"(v) : "memory");
}
__device__ __forceinline__ void drain_vm() {
  asm volatile("s_waitcnt vmcnt(0)" ::: "memory");
}
__device__ __forceinline__ void postc(u32* cnt, int tid) {
  if (tid == 0)
    __hip_atomic_fetch_add(cnt, 1u, __ATOMIC_RELAXED, __HIP_MEMORY_SCOPE_AGENT);
}
__device__ __forceinline__ void pollc(u32* cnt, int tid, u32 target) {
  if (tid == 0) {
    while (__hip_atomic_load(cnt, __ATOMIC_RELAXED, __HIP_MEMORY_SCOPE_AGENT) < target)
      __builtin_amdgcn_s_sleep(1);
  }
  __syncthreads();
}
__device__ __forceinline__ f32x4 unpk4(u64 g) {
  f32x4 a;
#pragma unroll
  for (int j = 0; j < 4; ++j) a[j] = b2f((u16)(g >> (16 * j)));
  return a;
}
__device__ __forceinline__ float sigm(float x) { return 1.f / (1.f + __expf(-x)); }

// ---------------- prep kernels ----------------
struct ConvArgs { const float* s[10]; unsigned long long doff[10]; int n[10]; };

__global__ __launch_bounds__(256) void wconv(char* ws, ConvArgs a) {
  int seg = blockIdx.y;
  const float* s = a.s[seg];
  u16* d = (u16*)(ws + a.doff[seg]);
  int n = a.n[seg];
  int i = (blockIdx.x * 256 + threadIdx.x) * 8;
  if (i < n) {
    float4 v0 = *(const float4*)(s + i);
    float4 v1 = *(const float4*)(s + i + 4);
    uint4 o;
    o.x = f2b2(v0.x, v0.y); o.y = f2b2(v0.z, v0.w);
    o.z = f2b2(v1.x, v1.y); o.w = f2b2(v1.z, v1.w);
    *(uint4*)(d + i) = o;
  }
}

__global__ __launch_bounds__(256) void gatherx(char* ws, const int* xs, const float* embed) {
  u16* xemb = (u16*)(ws + OFF_XEMB);
  int i = blockIdx.x * 256 + threadIdx.x;
  int t = i >> 11;
  int rr = i & 2047;
  int n = rr >> 5;
  int k = (rr & 31) << 3;
  int idx = xs[n * TT + t];
  const float* src = embed + (size_t)idx * XDI + k;
  float4 v0 = *(const float4*)src;
  float4 v1 = *(const float4*)(src + 4);
  uint4 o;
  o.x = f2b2(v0.x, v0.y); o.y = f2b2(v0.z, v0.w);
  o.z = f2b2(v1.x, v1.y); o.w = f2b2(v1.z, v1.w);
  *(uint4*)(xemb + ((size_t)t * NB + n) * XDI + k) = o;
}

__global__ __launch_bounds__(256) void h0init(char* ws, const int* labels, const int* wflag,
                                              const float* hnoise, const float* hw, const float* hb0) {
  int i = blockIdx.x * 256 + threadIdx.x;  // 32768
  int n = i >> 9, c = i & 511;
  float v = (float)labels[n] * hw[c] + hb0[c];
  if (wflag[0]) v += hnoise[i];
  ((float*)(ws + OFF_H))[i] = v;
  ((u16*)(ws + OFF_HALL))[i] = f2b(v);   // hall[0] = h0
}

// gi_x[t][c][n] (96 tiles) + c1_x[t][c][n] = x@We1[:, :256]^T + b_e1 (32 tiles)
__global__ __launch_bounds__(256) void gixk(char* ws, const float* bih, const float* b_e1) {
  __shared__ u16 lA[64 * 256];
  int t = blockIdx.x;
  int tid = threadIdx.x, wave = tid >> 6, lane = tid & 63;
  const int cl = lane & 15, rb = (lane >> 4) << 2;
  const u16* xemb = (const u16*)(ws + OFF_XEMB);
  const u16* wih = (const u16*)(ws + OFF_WIH);
  const u16* we1 = (const u16*)(ws + OFF_WE1);
  u16* gix = (u16*)(ws + OFF_GIX);
  u16* c1x = (u16*)(ws + OFF_C1X);
  fill_lds(lA, 256, xemb + (size_t)t * NB * XDI, 256, xemb, 256);
  __syncthreads();
  for (int ct = wave; ct < 128; ct += 4) {
    f32x4 acc[4];
    acc[0] = acc[1] = acc[2] = acc[3] = (f32x4){0.f, 0.f, 0.f, 0.f};
    if (ct < 96) {
      mm_tile(acc, lA, 256, 0, wih, 384, ct * 16, 256, lane);
      int col = ct * 16 + cl;
      float bv = bih[col];
      u16* dst = gix + ((size_t)t * 1536 + col) * 64;
#pragma unroll
      for (int m = 0; m < 4; ++m) {
        u64 o = (u64)f2b(acc[m][0] + bv) | ((u64)f2b(acc[m][1] + bv) << 16)
              | ((u64)f2b(acc[m][2] + bv) << 32) | ((u64)f2b(acc[m][3] + bv) << 48);
        *(u64*)(dst + (m << 4) + rb) = o;
      }
    } else {
      int c0 = (ct - 96) * 16;
      mm_tile(acc, lA, 256, 0, we1, 768, c0, 256, lane);
      int col = c0 + cl;
      float bv = b_e1[col];
      u16* dst = c1x + ((size_t)t * 512 + col) * 64;
#pragma unroll
      for (int m = 0; m < 4; ++m) {
        u64 o = (u64)f2b(acc[m][0] + bv) | ((u64)f2b(acc[m][1] + bv) << 16)
              | ((u64)f2b(acc[m][2] + bv) << 32) | ((u64)f2b(acc[m][3] + bv) << 48);
        *(u64*)(dst + (m << 4) + rb) = o;
      }
    }
  }
}

// ---------------- phase B: 8 independent 8-row chains x 32 slices ----------------
// 256 WGs x 256 threads (1/CU). MFMA tiles half-utilized (rows 8-15 duplicate,
// discarded). Protocol identical to R14: per-chain counters, tid0 poll + barrier.
__global__ __launch_bounds__(256, 1) void phaseB(
    char* ws, const float* __restrict__ eps,
    const float* __restrict__ b_e2,
    const float* __restrict__ b_mw, const float* __restrict__ b_sw,
    const float* __restrict__ bhh) {
  __shared__ u16 wsl[59392];                // 116KB weight slices (swizzled)
  __shared__ float ghb[3][CR][16];
  __shared__ float red[3][CR][16];
  __shared__ float musp[CR][8];
  __shared__ float hold[CR][17];
  __shared__ __align__(16) u16 stg[CR][16];

  u16* wWe1 = wsl;            // [16][768] (h-part cols 256-767 used)
  u16* wWhh = wsl + 12288;    // [48][512]
  u16* wWe2 = wsl + 36864;    // [16][512]
  u16* wWms = wsl + 45056;    // [16][512] rows 0-3 mu, 4-7 std
  u16* wWihz = wsl + 53248;   // [48][128]

  const u16* we1 = (const u16*)(ws + OFF_WE1);
  const u16* we2 = (const u16*)(ws + OFF_WE2);
  const u16* wmw = (const u16*)(ws + OFF_WMW);
  const u16* wsw = (const u16*)(ws + OFF_WSW);
  const u16* wih = (const u16*)(ws + OFF_WIH);
  const u16* whh = (const u16*)(ws + OFF_WHH);
  const u16* gix = (const u16*)(ws + OFF_GIX);
  const u16* c1x = (const u16*)(ws + OFF_C1X);
  float* hg = (float*)(ws + OFF_H);
  u16* zall = (u16*)(ws + OFF_ZALL);
  u16* hall = (u16*)(ws + OFF_HALL);

  const int tid = threadIdx.x, wave = tid >> 6, lane = tid & 63;
  const int cl = lane & 15, kl = (lane >> 4) << 3, rb = (lane >> 4) << 2;
  const int g = blockIdx.x >> 5, sl = blockIdx.x & 31;
  const int r0 = g << 3;
  const int crl = cl & 7;     // chain-row index for operand loads (dup upper half)

  u16* c1g = (u16*)(ws + OFF_C1A) + (size_t)g * (RING * CR * 512);
  u16* eg  = (u16*)(ws + OFF_EA)  + (size_t)g * (RING * CR * 512);
  u32* cC1 = (u32*)(ws + OFF_FLAG + (size_t)g * 1024);
  u32* cE  = (u32*)((char*)cC1 + 256);
  u32* cZ  = (u32*)((char*)cC1 + 512);
  u32* cH  = (u32*)((char*)cC1 + 768);

  // ---- preload weight slices into LDS ----
  for (int c = tid; c < 1536; c += 256) {
    int r = c / 96, k = (c % 96) << 3;
    ldsW(wWe1, r, 768, k, *(const uint4*)(we1 + (size_t)(sl * 16 + r) * 768 + k));
  }
  for (int c = tid; c < 3072; c += 256) {
    int r = c >> 6, k = (c & 63) << 3;
    int gr = (r >> 4) * 512 + sl * 16 + (r & 15);
    ldsW(wWhh, r, 512, k, *(const uint4*)(whh + (size_t)gr * 512 + k));
  }
  for (int c = tid; c < 1024; c += 256) {
    int r = c >> 6, k = (c & 63) << 3;
    ldsW(wWe2, r, 512, k, *(const uint4*)(we2 + (size_t)(sl * 16 + r) * 512 + k));
  }
  for (int c = tid; c < 1024; c += 256) {
    int r = c >> 6, k = (c & 63) << 3;
    uint4 v = {0, 0, 0, 0};
    if (r < 4)      v = *(const uint4*)(wmw + (size_t)(sl * 4 + r) * 512 + k);
    else if (r < 8) v = *(const uint4*)(wsw + (size_t)(sl * 4 + r - 4) * 512 + k);
    ldsW(wWms, r, 512, k, v);
  }
  for (int c = tid; c < 768; c += 256) {
    int r = c >> 4, k = (c & 15) << 3;
    int gr = (r >> 4) * 512 + sl * 16 + (r & 15);
    ldsW(wWihz, r, 128, k, *(const uint4*)(wih + (size_t)gr * 384 + 256 + k));
  }
  if (tid < CR * 16) {
    int r = tid >> 4, c = tid & 15;
    hold[r][c] = hg[(size_t)(r0 + r) * 512 + sl * 16 + c];
  }
  // biases
  const float be2 = b_e2[sl * 16 + cl];
  const float bms = (cl < 4) ? b_mw[sl * 4 + cl] : ((cl < 8) ? b_sw[sl * 4 + cl - 4] : 0.f);
  const float bhg = (wave >= 1) ? bhh[(wave - 1) * 512 + sl * 16 + cl] : 0.f;
  __syncthreads();

  const f32x4 z4 = {0.f, 0.f, 0.f, 0.f};
  for (int t = 0; t < TT; ++t) {
    const int rs = t & RMSK;
    // ---- S0: prefetch (plain cached) ----
    u64 gx0 = 0, cx0 = 0;
    float4 ev4 = {0.f, 0.f, 0.f, 0.f};
    if (wave == 0)
      cx0 = *(const u64*)(c1x + ((size_t)t * 512 + sl * 16 + cl) * 64 + r0 + (rb & 7));
    if (wave < 3)
      gx0 = *(const u64*)(gix + ((size_t)t * 1536 + wave * 512 + sl * 16 + cl) * 64 + r0 + (rb & 7));
    if (wave == 0 && lane < CR)
      ev4 = *(const float4*)(eps + (size_t)(r0 + lane) * (TT * ZDI) + (size_t)t * ZDI + sl * 4);

    // ---- S1: wait h(t); c1 (wave0) / gh gates (waves1-3) ----
    pollc(cH, tid, 32u * (u32)t);
    u32x4 hf[16];
    ld16_c(hall + ((size_t)t * NB + r0 + crl) * HDI + kl, hf);
    if (wave == 0) {
      f32x4 a = unpk4(cx0);   // x-part + b_e1 precomputed
#pragma unroll
      for (int c = 0; c < 16; ++c)
        a = MFMA16(*(const bf16x8*)&hf[c], *ldsB(wWe1, cl, 768, 256 + c * 32 + kl), a);
      if (rb < CR) {
#pragma unroll
        for (int j = 0; j < 4; ++j)
          stg[rb + j][cl] = f2b(fmaxf(a[j], 0.f));
      }
      if (lane < 16) {
        int row = lane >> 1, half = lane & 1;
        u32x4 v = *(const u32x4*)&stg[row][half * 8];
        st16B_c(c1g + ((size_t)rs * CR + row) * 512 + sl * 16 + half * 8, v);
      }
      drain_vm();
      postc(cC1, tid);
    } else {
      f32x4 a = z4;
#pragma unroll
      for (int c = 0; c < 16; ++c)
        a = MFMA16(*(const bf16x8*)&hf[c], *ldsB(wWhh, (wave - 1) * 16 + cl, 512, c * 32 + kl), a);
      if (rb < CR) {
#pragma unroll
        for (int j = 0; j < 4; ++j) ghb[wave - 1][rb + j][cl] = a[j] + bhg;
      }
    }

    // ---- S2: e = relu(c1 @ We2^T + b2) (wave0) ----
    pollc(cC1, tid, 32u * (u32)(t + 1));
    if (wave == 0) {
      u32x4 cf[16];
      ld16_c(c1g + ((size_t)rs * CR + crl) * 512 + kl, cf);
      f32x4 a = z4;
#pragma unroll
      for (int c = 0; c < 16; ++c)
        a = MFMA16(*(const bf16x8*)&cf[c], *ldsB(wWe2, cl, 512, c * 32 + kl), a);
      if (rb < CR) {
#pragma unroll
        for (int j = 0; j < 4; ++j)
          stg[rb + j][cl] = f2b(fmaxf(a[j] + be2, 0.f));
      }
      if (lane < 16) {
        int row = lane >> 1, half = lane & 1;
        u32x4 v = *(const u32x4*)&stg[row][half * 8];
        st16B_c(eg + ((size_t)rs * CR + row) * 512 + sl * 16 + half * 8, v);
      }
      drain_vm();
      postc(cE, tid);
    }

    // ---- S3: mu/std -> z (wave0) ----
    pollc(cE, tid, 32u * (u32)(t + 1));
    if (wave == 0) {
      u32x4 ef[16];
      ld16_c(eg + ((size_t)rs * CR + crl) * 512 + kl, ef);
      f32x4 a = z4;
#pragma unroll
      for (int c = 0; c < 16; ++c)
        a = MFMA16(*(const bf16x8*)&ef[c], *ldsB(wWms, cl, 512, c * 32 + kl), a);
      if (rb < CR && cl < 8) {
#pragma unroll
        for (int j = 0; j < 4; ++j) musp[rb + j][cl] = a[j] + bms;
      }
      if (lane < CR) {
        int r = lane;
        float m0 = musp[r][0], m1 = musp[r][1], m2 = musp[r][2], m3 = musp[r][3];
        float s0 = musp[r][4], s1 = musp[r][5], s2 = musp[r][6], s3 = musp[r][7];
        float p0 = fmaxf(s0, 0.f) + log1pf(__expf(-fabsf(s0)));
        float p1 = fmaxf(s1, 0.f) + log1pf(__expf(-fabsf(s1)));
        float p2 = fmaxf(s2, 0.f) + log1pf(__expf(-fabsf(s2)));
        float p3 = fmaxf(s3, 0.f) + log1pf(__expf(-fabsf(s3)));
        float z0 = ev4.x * p0 + m0, z1 = ev4.y * p1 + m1;
        float z2 = ev4.z * p2 + m2, z3 = ev4.w * p3 + m3;
        u64 pk = (u64)f2b2(z0, z1) | ((u64)f2b2(z2, z3) << 32);
        st8B_c(zall + ((size_t)t * NB + r0 + r) * ZDI + sl * 4, pk);
      }
      drain_vm();
      postc(cZ, tid);
    }

    // ---- S4: gi_z gates (waves0-2) ----
    pollc(cZ, tid, 32u * (u32)(t + 1));
    if (wave < 3) {
      u32x4 zf[4];
      ld4_c(zall + ((size_t)t * NB + r0 + crl) * ZDI + kl, zf);
      f32x4 a = unpk4(gx0);
#pragma unroll
      for (int c = 0; c < 4; ++c)
        a = MFMA16(*(const bf16x8*)&zf[c], *ldsB(wWihz, wave * 16 + cl, 128, c * 32 + kl), a);
      if (rb < CR) {
#pragma unroll
        for (int j = 0; j < 4; ++j) red[wave][rb + j][cl] = a[j];
      }
    }
    __syncthreads();
    // ---- gates + h' (128 threads, one element each) ----
    if (tid < CR * 16) {
      int r = tid >> 4, c = tid & 15;
      float rg = sigm(red[0][r][c] + ghb[0][r][c]);
      float zg = sigm(red[1][r][c] + ghb[1][r][c]);
      float ng = tanhf(red[2][r][c] + rg * ghb[2][r][c]);
      hold[r][c] = (1.f - zg) * ng + zg * hold[r][c];
    }
    __syncthreads();
    if (t < TT - 1) {
      if (wave == 0) {
        if (lane < 16) {
          int row = lane >> 1, half = lane & 1;
          const float* hp = &hold[row][half * 8];
          u32x4 w;
          w[0] = f2b2(hp[0], hp[1]); w[1] = f2b2(hp[2], hp[3]);
          w[2] = f2b2(hp[4], hp[5]); w[3] = f2b2(hp[6], hp[7]);
          st16B_c(hall + ((size_t)(t + 1) * NB + r0 + row) * HDI + sl * 16 + half * 8, w);
        }
        drain_vm();
        postc(cH, tid);
      }
    } else {
      if (tid < CR * 16) {
        int r = tid >> 4, c = tid & 15;
        hg[(size_t)(r0 + r) * 512 + sl * 16 + c] = hold[r][c];
      }
    }
  }
}

// ---------------- phase C: decoder chain + generation loss ----------------
__global__ __launch_bounds__(256, 1) void phaseC(
    char* ws, const float* db1, const float* db2, const float* dmbias,
    const float* genb, const int* ts, float* gpart) {
  __shared__ u16 lA[64 * 640];
  __shared__ u16 lB[64 * 512];
  int rb = blockIdx.x;
  int tid = threadIdx.x, wave = tid >> 6, lane = tid & 63;
  const u16* zall = (const u16*)(ws + OFF_ZALL);
  const u16* hall = (const u16*)(ws + OFF_HALL);
  const u16* wd1 = (const u16*)(ws + OFF_WD1);
  const u16* wd2 = (const u16*)(ws + OFF_WD2);
  const u16* wdm = (const u16*)(ws + OFF_WDM);
  const u16* wgw = (const u16*)(ws + OFF_WGW);

  fill_lds(lA, 640, zall + (size_t)rb * NB * ZDI, 128, hall + (size_t)rb * NB * HDI, 512);
  __syncthreads();
  for (int tile = wave; tile < 32; tile += 4) {
    f32x4 acc[4];
    acc[0] = acc[1] = acc[2] = acc[3] = (f32x4){0.f, 0.f, 0.f, 0.f};
    mm_tile(acc, lA, 640, 0, wd1, 640, tile * 16, 640, lane);
    int col = tile * 16 + (lane & 15);
    float bias = db1[col];
#pragma unroll
    for (int m = 0; m < 4; ++m)
#pragma unroll
      for (int j = 0; j < 4; ++j) {
        int row = (m << 4) + ((lane >> 4) << 2) + j;
        int byte = ((row * 512 + col) << 1) ^ ((row & 7) << 4);
        *(u16*)((char*)lB + byte) = f2b(fmaxf(acc[m][j] + bias, 0.f));
      }
  }
  __syncthreads();
  for (int tile = wave; tile < 32; tile += 4) {
    f32x4 acc[4];
    acc[0] = acc[1] = acc[2] = acc[3] = (f32x4){0.f, 0.f, 0.f, 0.f};
    mm_tile(acc, lB, 512, 0, wd2, 512, tile * 16, 512, lane);
    int col = tile * 16 + (lane & 15);
    float bias = db2[col];
#pragma unroll
    for (int m = 0; m < 4; ++m)
#pragma unroll
      for (int j = 0; j < 4; ++j) {
        int row = (m << 4) + ((lane >> 4) << 2) + j;
        int byte = ((row * 512 + col) << 1) ^ ((row & 7) << 4);
        *(u16*)((char*)lA + byte) = f2b(fmaxf(acc[m][j] + bias, 0.f));
      }
  }
  __syncthreads();
  for (int tile = wave; tile < 16; tile += 4) {
    f32x4 acc[4];
    acc[0] = acc[1] = acc[2] = acc[3] = (f32x4){0.f, 0.f, 0.f, 0.f};
    mm_tile(acc, lA, 512, 0, wdm, 512, tile * 16, 512, lane);
    int col = tile * 16 + (lane & 15);
    float bias = dmbias[col];
#pragma unroll
    for (int m = 0; m < 4; ++m)
#pragma unroll
      for (int j = 0; j < 4; ++j) {
        int row = (m << 4) + ((lane >> 4) << 2) + j;
        float v = 1.f / (1.f + __expf(-(acc[m][j] + bias)));
        int byte = ((row * 256 + col) << 1) ^ ((row & 7) << 4);
        *(u16*)((char*)lB + byte) = f2b(v);
      }
  }
  __syncthreads();
  float mr[16], sr[16], cap[16];
  int tg[16];
#pragma unroll
  for (int q = 0; q < 16; ++q) {
    int r = ((q >> 2) << 4) + ((lane >> 4) << 2) + (q & 3);
    tg[q] = ts[r * TT + rb];
    mr[q] = -1e30f; sr[q] = 0.f; cap[q] = -1e30f;
  }
  for (int ct = wave; ct < 625; ct += 4) {
    f32x4 acc[4];
    acc[0] = acc[1] = acc[2] = acc[3] = (f32x4){0.f, 0.f, 0.f, 0.f};
    mm_tile(acc, lB, 256, 0, wgw, 256, ct * 16, 256, lane);
    int colw = ct * 16 + (lane & 15);
    float gbv = genb[colw];
#pragma unroll
    for (int mi = 0; mi < 4; ++mi)
#pragma unroll
      for (int j = 0; j < 4; ++j) {
        int q = (mi << 2) + j;
        float v = acc[mi][j] + gbv;
        if (colw == tg[q]) cap[q] = v;
        float mn = fmaxf(mr[q], v);
        sr[q] = sr[q] * __expf(mr[q] - mn) + __expf(v - mn);
        mr[q] = mn;
      }
  }
#pragma unroll
  for (int d = 1; d < 16; d <<= 1) {
#pragma unroll
    for (int q = 0; q < 16; ++q) {
      float mo = __shfl_xor(mr[q], d);
      float so = __shfl_xor(sr[q], d);
      float co = __shfl_xor(cap[q], d);
      float mn = fmaxf(mr[q], mo);
      sr[q] = sr[q] * __expf(mr[q] - mn) + so * __expf(mo - mn);
      mr[q] = mn;
      cap[q] = fmaxf(cap[q], co);
    }
  }
  float* sc = (float*)lA;
  if ((lane & 15) == 0) {
    int gq = lane >> 4;
#pragma unroll
    for (int q = 0; q < 16; ++q) {
      int r = ((q >> 2) << 4) + (gq << 2) + (q & 3);
      sc[wave * 64 + r] = mr[q];
      sc[256 + wave * 64 + r] = sr[q];
      sc[512 + wave * 64 + r] = cap[q];
    }
  }
  __syncthreads();
  if (tid < 64) {
    float M = -1e30f, S = 0.f, C = -1e30f;
#pragma unroll
    for (int w = 0; w < 4; ++w) {
      float m = sc[w * 64 + tid], s = sc[256 + w * 64 + tid], c = sc[512 + w * 64 + tid];
      float mn = fmaxf(M, m);
      S = S * __expf(M - mn) + s * __expf(m - mn);
      M = mn;
      C = fmaxf(C, c);
    }
    float lossr = M + __logf(S) - C;
    for (int d = 1; d < 64; d <<= 1) lossr += __shfl_xor(lossr, d);
    if (tid == 0) gpart[rb] = lossr;
  }
}

// ---------------- final reduce + classifier ----------------
__global__ __launch_bounds__(256) void finalk(char* ws, const int* labels,
                                              const float* cw, const float* cb,
                                              const float* gpart, float* out) {
  __shared__ float sred[256];
  __shared__ float cred[64];
  int tid = threadIdx.x;
  sred[tid] = gpart[tid];
  __syncthreads();
  for (int s2 = 128; s2 > 0; s2 >>= 1) {
    if (tid < s2) sred[tid] += sred[tid + s2];
    __syncthreads();
  }
  const float* h = (const float*)(ws + OFF_H);
  if (tid < 64) {
    const float* hrow = h + tid * 512;
    float a0 = cb[0], a1 = cb[1], a2 = cb[2], a3 = cb[3];
    for (int k = 0; k < 512; k += 4) {
      float4 hv = *(const float4*)(hrow + k);
      float4 w0 = *(const float4*)(cw + 0 * 512 + k);
      float4 w1 = *(const float4*)(cw + 1 * 512 + k);
      float4 w2 = *(const float4*)(cw + 2 * 512 + k);
      float4 w3 = *(const float4*)(cw + 3 * 512 + k);
      a0 += hv.x * w0.x + hv.y * w0.y + hv.z * w0.z + hv.w * w0.w;
      a1 += hv.x * w1.x + hv.y * w1.y + hv.z * w1.z + hv.w * w1.w;
      a2 += hv.x * w2.x + hv.y * w2.y + hv.z * w2.z + hv.w * w2.w;
      a3 += hv.x * w3.x + hv.y * w3.y + hv.z * w3.z + hv.w * w3.w;
    }
    float M = fmaxf(fmaxf(a0, a1), fmaxf(a2, a3));
    float S = __expf(a0 - M) + __expf(a1 - M) + __expf(a2 - M) + __expf(a3 - M);
    int lb = labels[tid];
    float lg = (lb == 0) ? a0 : (lb == 1) ? a1 : (lb == 2) ? a2 : a3;
    cred[tid] = M + __logf(S) - lg;
  }
  __syncthreads();
  if (tid == 0) {
    float cs = 0.f;
    for (int i = 0; i < 64; ++i) cs += cred[i];
    out[0] = sred[0] / 16384.f;
    out[1] = cs / 64.f;
  }
}

extern "C" void kernel_launch(void* const* d_in, const int* in_sizes, int n_in,
                              void* d_out, int out_size, void* d_ws, size_t ws_size,
                              hipStream_t stream) {
  (void)in_sizes; (void)n_in; (void)out_size; (void)ws_size;
  char* ws = (char*)d_ws;
  const int* xs = (const int*)d_in[0];
  const int* ts = (const int*)d_in[1];
  const int* labels = (const int*)d_in[2];
  const int* wflag = (const int*)d_in[3];
  const float* eps = (const float*)d_in[4];
  const float* hnoise = (const float*)d_in[5];
  const float* embed = (const float*)d_in[6];
  const float* e_w1 = (const float*)d_in[7];
  const float* e_b1 = (const float*)d_in[8];
  const float* e_w2 = (const float*)d_in[9];
  const float* e_b2 = (const float*)d_in[10];
  const float* m_w = (const float*)d_in[11];
  const float* m_b = (const float*)d_in[12];
  const float* s_w = (const float*)d_in[13];
  const float* s_b = (const float*)d_in[14];
  const float* d_w1 = (const float*)d_in[15];
  const float* d_b1 = (const float*)d_in[16];
  const float* d_w2 = (const float*)d_in[17];
  const float* d_b2 = (const float*)d_in[18];
  const float* dm_w = (const float*)d_in[19];
  const float* dm_b = (const float*)d_in[20];
  const float* g_ih = (const float*)d_in[21];
  const float* g_hh = (const float*)d_in[22];
  const float* g_bih = (const float*)d_in[23];
  const float* g_bhh = (const float*)d_in[24];
  const float* gw = (const float*)d_in[25];
  const float* gb = (const float*)d_in[26];
  const float* cw = (const float*)d_in[27];
  const float* cb = (const float*)d_in[28];
  const float* hw = (const float*)d_in[29];
  const float* hb0 = (const float*)d_in[30];

  hipMemsetAsync(ws + OFF_FLAG, 0, 8192, stream);

  ConvArgs ca;
  const float* srcs[10] = {e_w1, e_w2, m_w, s_w, d_w1, d_w2, dm_w, g_ih, g_hh, gw};
  unsigned long long doffs[10] = {OFF_WE1, OFF_WE2, OFF_WMW, OFF_WSW, OFF_WD1,
                                  OFF_WD2, OFF_WDM, OFF_WIH, OFF_WHH, OFF_WGW};
  int ns[10] = {393216, 262144, 65536, 65536, 327680, 262144, 131072, 589824, 786432, 2560000};
  for (int i = 0; i < 10; ++i) { ca.s[i] = srcs[i]; ca.doff[i] = doffs[i]; ca.n[i] = ns[i]; }

  wconv<<<dim3(1250, 10), 256, 0, stream>>>(ws, ca);
  gatherx<<<2048, 256, 0, stream>>>(ws, xs, embed);
  h0init<<<128, 256, 0, stream>>>(ws, labels, wflag, hnoise, hw, hb0);
  gixk<<<256, 256, 0, stream>>>(ws, g_bih, e_b1);
  phaseB<<<256, 256, 0, stream>>>(ws, eps, e_b2, m_b, s_b, g_bhh);
  phaseC<<<256, 256, 0, stream>>>(ws, d_b1, d_b2, dm_b, gb, ts, (float*)(ws + OFF_GPART));
  finalk<<<1, 256, 0, stream>>>(ws, labels, cw, cb, (const float*)(ws + OFF_GPART), (float*)d_out);
}